// Round 10
// baseline (221.949 us; speedup 1.0000x reference)
//
#include <hip/hip_runtime.h>
#include <hip/hip_bf16.h>

typedef unsigned short ushort_t;
typedef short bf16x8 __attribute__((ext_vector_type(8)));
typedef float f32x4 __attribute__((ext_vector_type(4)));

__device__ __forceinline__ ushort_t f2b(float f) {
    __hip_bfloat16 h = __float2bfloat16(f);
    return *reinterpret_cast<ushort_t*>(&h);
}
__device__ __forceinline__ float b2f(short v) {
    union { unsigned int u; float f; } cv;
    cv.u = ((unsigned int)(ushort_t)v) << 16;
    return cv.f;
}

// ---------------- weight repack: w1 (64,3,3,3) -> B-frag order [nf(4)][lane(64)][8], K order k = tap*3+c
__global__ __launch_bounds__(256) void k_pack1(const float* __restrict__ w1, ushort_t* __restrict__ o) {
    const int slot = threadIdx.x;                         // 256 slots
    const int lane = slot & 63, nf = slot >> 6;
    const int co = nf * 16 + (lane & 15);
    const int kg = lane >> 4;
#pragma unroll
    for (int j = 0; j < 8; ++j) {
        const int k = kg * 8 + j;
        float v = 0.f;
        if (k < 27) {
            const int t = k / 3, c = k - 3 * t;
            v = w1[(co * 3 + c) * 9 + t];
        }
        o[slot * 8 + j] = f2b(v);
    }
}

// ---------------- weight repack: w2 (128,64,3,3) -> B-fragment order, bf16
// K order = tap*64 + s, where storage channel s maps to original ci = 16*(s&3) + (s>>2)
// (matches y1's permuted channel layout written by k_conv1g)
__global__ __launch_bounds__(256) void k_pack2(const float* __restrict__ w2, ushort_t* __restrict__ o) {
    const int slot = blockIdx.x * 256 + threadIdx.x;      // 9216 slots
    const int lane = slot & 63, g = (slot >> 6) & 7, kc = slot >> 9;
    const int k0 = kc * 32 + ((lane >> 4) << 3);
    const int tap = k0 >> 6, sb = k0 & 63;
    const int ky = tap >= 6 ? 2 : (tap >= 3 ? 1 : 0), kx = tap - ky * 3;
    const int co = g * 16 + (lane & 15);
#pragma unroll
    for (int j = 0; j < 8; ++j) {
        const int s = sb + j;
        const int ci = 16 * (s & 3) + (s >> 2);
        o[slot * 8 + j] = f2b(w2[((co * 64 + ci) * 3 + ky) * 3 + kx]);
    }
}

// w3 (256,128,3,3): [kc(36)][g16(16)][lane][8], K order = tap*128+ci
__global__ __launch_bounds__(256) void k_pack3(const float* __restrict__ w3, ushort_t* __restrict__ o) {
    const int slot = blockIdx.x * 256 + threadIdx.x;      // 36864 slots
    const int lane = slot & 63, g = (slot >> 6) & 15, kc = slot >> 10;
    const int k0 = kc * 32 + ((lane >> 4) << 3);
    const int tap = k0 >> 7, cib = k0 & 127;
    const int ky = tap >= 6 ? 2 : (tap >= 3 ? 1 : 0), kx = tap - ky * 3;
    const int co = g * 16 + (lane & 15);
#pragma unroll
    for (int j = 0; j < 8; ++j)
        o[slot * 8 + j] = f2b(w3[((co * 128 + cib + j) * 3 + ky) * 3 + kx]);
}

// w4 (512,256,3,3) -> MFMA B-frag bf16 [kc(72)][g16(32)][lane(64)][8], K order = tap*256+ci
__global__ __launch_bounds__(256) void k_pack4m(const float* __restrict__ w4, ushort_t* __restrict__ o) {
    const int co = blockIdx.x;                            // 512 blocks
    __shared__ float sw[2304];
    for (int i = threadIdx.x; i < 2304; i += 256) sw[i] = w4[(size_t)co * 2304 + i];
    __syncthreads();
    const int g = co >> 4, l15 = co & 15;
    for (int it = threadIdx.x; it < 288; it += 256) {
        const int kc = it >> 2, kg = it & 3;
        const int k0 = kc * 32 + kg * 8;
        const int tap = k0 >> 8, ci0 = k0 & 255;
        const int lane = kg * 16 + l15;
        ushort_t tmp[8];
#pragma unroll
        for (int j = 0; j < 8; ++j)
            tmp[j] = f2b(sw[(ci0 + j) * 9 + tap]);
        *(float4*)(o + ((size_t)(kc * 32 + g) * 64 + lane) * 8) = *(const float4*)tmp;
    }
}

// ---------------- im2col for conv1 (aligned loads, contiguous wave stores)
// x (16,3,512,512) f32 -> A [1048576][32] bf16; row m = ((b*128+py)*128+px)*4 + dy*2 + dx
// thread t: dy = t&1, px = (t>>1)&127, py = (t>>8)&127, b = t>>15; handles dx=0,1
// lane i writes bytes [i*128, i*128+128) of the wave's 8KB region -> fully coalesced
__global__ __launch_bounds__(256) void k_im2col2b(const float* __restrict__ x, ushort_t* __restrict__ A) {
    const int t = blockIdx.x * 256 + threadIdx.x;         // 2048 blocks
    const int dy = t & 1;
    const int px = (t >> 1) & 127;
    const int py = (t >> 8) & 127;
    const int b  = t >> 15;
    const int oy = 2 * py + dy;
    const int iy0 = 2 * oy - 1;
    const float* xb = x + (size_t)b * 3 * 512 * 512;
    const int lane = threadIdx.x & 63;

    ushort_t r0[32], r1[32];
#pragma unroll
    for (int k = 0; k < 32; ++k) { r0[k] = 0; r1[k] = 0; }

#pragma unroll
    for (int c = 0; c < 3; ++c) {
#pragma unroll
        for (int ky = 0; ky < 3; ++ky) {
            const int iy = iy0 + ky;
            const float* rp = xb + ((size_t)c * 512 + iy) * 512;
            float4 q = {0.f, 0.f, 0.f, 0.f};
            if (iy >= 0) q = *(const float4*)(rp + 4 * px);   // 16B-aligned dwordx4
            float vm1 = __shfl_up(q.w, 2, 64);                // col 4px-1: lane-2 = (px-1, same dy)
            if (lane < 2) vm1 = (px > 0 && iy >= 0) ? rp[4 * px - 1] : 0.f;
            const int kb = ky * 9 + c;                        // k = (ky*3+kx)*3 + c
            r0[kb]     = f2b(vm1);  r1[kb]     = f2b(q.y);
            r0[kb + 3] = f2b(q.x);  r1[kb + 3] = f2b(q.z);
            r0[kb + 6] = f2b(q.y);  r1[kb + 6] = f2b(q.w);
        }
    }
    const size_t m0 = (((size_t)(b * 128 + py) * 128 + px) << 2) + (dy << 1);
    float4* dst = (float4*)(A + m0 * 32);
    const float4* s0 = (const float4*)r0;
    const float4* s1 = (const float4*)r1;
    dst[0] = s0[0]; dst[1] = s0[1]; dst[2] = s0[2]; dst[3] = s0[3];
    dst[4] = s1[0]; dst[5] = s1[1]; dst[6] = s1[2]; dst[7] = s1[3];
}

// ---------------- conv1 GEMM: A [1M][32] x w1 [32][64] -> pool+bias+relu -> y1 bf16 NHWC
// y1 channel storage order: s = 4*l15 + nf  (original co = nf*16 + l15) -> 8B store per lane
__global__ __launch_bounds__(256) void k_conv1g(const ushort_t* __restrict__ A,
                                                const ushort_t* __restrict__ wpk1,
                                                const float* __restrict__ b1,
                                                ushort_t* __restrict__ y1) {
    const int tid = threadIdx.x;
    const int wid = tid >> 6, lane = tid & 63;
    const int l15 = lane & 15, kg = lane >> 4;

    bf16x8 bF[4];
    float bias[4];
#pragma unroll
    for (int nf = 0; nf < 4; ++nf) {
        bF[nf] = *reinterpret_cast<const bf16x8*>(wpk1 + (size_t)(nf * 64 + lane) * 8);
        bias[nf] = b1[nf * 16 + l15];
    }
    const f32x4 z4 = {0.f, 0.f, 0.f, 0.f};
    const int f0 = blockIdx.x * 64 + wid * 16;

#pragma unroll 2
    for (int it = 0; it < 16; ++it) {
        const int f = f0 + it;
        const bf16x8 aF = *reinterpret_cast<const bf16x8*>(A + ((size_t)f * 16 + l15) * 32 + kg * 8);
        f32x4 acc[4];
#pragma unroll
        for (int nf = 0; nf < 4; ++nf)
            acc[nf] = __builtin_amdgcn_mfma_f32_16x16x32_bf16(aF, bF[nf], z4, 0, 0, 0);
        const int g = f * 4 + kg;
        const int px = g & 127, py = (g >> 7) & 127, b = g >> 14;
        union { ushort_t u[4]; uint2 v; } pk;
#pragma unroll
        for (int nf = 0; nf < 4; ++nf) {
            float v = fmaxf(fmaxf(acc[nf][0], acc[nf][1]), fmaxf(acc[nf][2], acc[nf][3]));
            pk.u[nf] = f2b(fmaxf(v + bias[nf], 0.f));
        }
        *(uint2*)(y1 + ((size_t)(b * 128 + py) * 128 + px) * 64 + 4 * l15) = pk.v;
    }
}

// ---------------- fallback conv1 (scalar path, used only if ws too small; writes permuted channel order)
__global__ __launch_bounds__(256, 4) void k_conv1(const float* __restrict__ x,
                                                  const float* __restrict__ w1,
                                                  const float* __restrict__ b1,
                                                  ushort_t* __restrict__ y1) {
    const int b = blockIdx.y;
    const int tileY = blockIdx.x >> 4, tileX = blockIdx.x & 15;
    const int tid = threadIdx.x;
    const int cog = __builtin_amdgcn_readfirstlane(tid >> 6);
    const int pix = tid & 63;
    const int ty = pix >> 3, tx = pix & 7;

    __shared__ float sIn[3 * 33 * 36];
    const int iyb = 32 * tileY - 1, ixb = 32 * tileX - 1;
    const float* xb = x + (size_t)b * 3 * 512 * 512;
    for (int idx = tid; idx < 3564; idx += 256) {
        const int col = idx % 36;
        const int rc = idx / 36;
        const int r = rc % 33, c = rc / 33;
        const int iy = iyb + r, ix = ixb + col;
        float v = 0.f;
        if (col < 33 && iy >= 0 && iy < 512 && ix >= 0 && ix < 512)
            v = xb[((size_t)c * 512 + iy) * 512 + ix];
        sIn[rc * 36 + col] = v;
    }
    __syncthreads();

    const float* wS = w1 + cog * (16 * 27);
    float acc[4][16];
#pragma unroll
    for (int p = 0; p < 4; ++p)
#pragma unroll
        for (int co = 0; co < 16; ++co) acc[p][co] = 0.f;

#pragma unroll
    for (int c = 0; c < 3; ++c) {
        float in[5][5];
#pragma unroll
        for (int r = 0; r < 5; ++r) {
            const float* rp = &sIn[(c * 33 + 4 * ty + r) * 36 + 4 * tx];
            const float4 qv = *(const float4*)rp;
            in[r][0] = qv.x; in[r][1] = qv.y; in[r][2] = qv.z; in[r][3] = qv.w;
            in[r][4] = rp[4];
        }
#pragma unroll
        for (int ky = 0; ky < 3; ++ky)
#pragma unroll
        for (int kx = 0; kx < 3; ++kx) {
            const int j = c * 9 + ky * 3 + kx;
#pragma unroll
            for (int co = 0; co < 16; ++co) {
                const float w = wS[co * 27 + j];
                acc[0][co] += in[ky][kx] * w;
                acc[1][co] += in[ky][kx + 2] * w;
                acc[2][co] += in[ky + 2][kx] * w;
                acc[3][co] += in[ky + 2][kx + 2] * w;
            }
        }
    }

    const int py = 8 * tileY + ty, px = 8 * tileX + tx;
    ushort_t* op = y1 + ((size_t)(b * 128 + py) * 128 + px) * 64;
#pragma unroll
    for (int co = 0; co < 16; ++co) {
        float m = fmaxf(fmaxf(acc[0][co], acc[1][co]), fmaxf(acc[2][co], acc[3][co]));
        const int c = cog * 16 + co;                  // original channel
        op[4 * (c & 15) + (c >> 4)] = f2b(fmaxf(m + b1[c], 0.f));
    }
}

// ---------------- conv2 MFMA: y1 bf16 (permuted ch) -> y2 bf16 NHWC (16,32,32,128)
// grid (rp=32, cog2=2, b=16); each wave owns one 16-co N-frag
__global__ __launch_bounds__(256) void k_conv2m(const ushort_t* __restrict__ y1,
                                                const ushort_t* __restrict__ wpk2,
                                                const float* __restrict__ b2,
                                                ushort_t* __restrict__ y2) {
    const int b = blockIdx.z;
    const int cog2 = blockIdx.y;
    const int rp = blockIdx.x;               // pooled row 0..31
    const int oy0 = rp * 2;
    const int tid = threadIdx.x;
    const int wid = tid >> 6, lane = tid & 63;
    const int l15 = lane & 15, kl8 = (lane >> 4) << 3;
    const int g16 = cog2 * 4 + wid;

    const ushort_t* xb = y1 + (size_t)b * 128 * 128 * 64;
    const f32x4 z4 = {0.f, 0.f, 0.f, 0.f};
    f32x4 acc[8];
#pragma unroll
    for (int i = 0; i < 8; ++i) acc[i] = z4;

    const int cb0 = 2 * l15 - 1;

#pragma unroll 1
    for (int tap = 0; tap < 9; ++tap) {
        const int ky = tap >= 6 ? 2 : (tap >= 3 ? 1 : 0), kx = tap - ky * 3;
        const int iyA = 2 * oy0 - 1 + ky;
#pragma unroll
        for (int h = 0; h < 2; ++h) {
            const int ci0 = h * 32;
            const int kc = tap * 2 + h;
            bf16x8 aF[8];
#pragma unroll
            for (int mf = 0; mf < 8; ++mf) {
                const int iy = iyA + 2 * (mf >> 2);
                const int c = cb0 + (mf & 3) * 32 + kx;
                const bool ok = (iy >= 0) && (c >= 0);
                bf16x8 r = {0, 0, 0, 0, 0, 0, 0, 0};
                if (ok) r = *reinterpret_cast<const bf16x8*>(xb + ((size_t)iy * 128 + c) * 64 + ci0 + kl8);
                aF[mf] = r;
            }
            const bf16x8 bF = *reinterpret_cast<const bf16x8*>(wpk2 + ((size_t)(kc * 8 + g16) * 64 + lane) * 8);
#pragma unroll
            for (int mf = 0; mf < 8; ++mf)
                acc[mf] = __builtin_amdgcn_mfma_f32_16x16x32_bf16(aF[mf], bF, acc[mf], 0, 0, 0);
        }
    }
    const int kg = lane >> 4;
    const int co = g16 * 16 + l15;
    const float bias = b2[co];
#pragma unroll
    for (int m4 = 0; m4 < 4; ++m4)
#pragma unroll
        for (int p = 0; p < 2; ++p) {
            float v = fmaxf(fmaxf(acc[m4][2 * p], acc[m4][2 * p + 1]),
                            fmaxf(acc[m4 + 4][2 * p], acc[m4 + 4][2 * p + 1]));
            const int px = m4 * 8 + kg * 2 + p;
            y2[((size_t)(b * 32 + rp) * 32 + px) * 128 + co] = f2b(fmaxf(v + bias, 0.f));
        }
}

// ---------------- conv3 MFMA: y2 bf16 NHWC -> y3 bf16 NHWC (16,8,8,256)
__global__ __launch_bounds__(256) void k_conv3m(const ushort_t* __restrict__ y2,
                                                const ushort_t* __restrict__ wpk3,
                                                const float* __restrict__ b3,
                                                ushort_t* __restrict__ y3) {
    const int gy = blockIdx.x, gn = blockIdx.y, b = blockIdx.z;
    const int oy0 = gy * 4;
    const int tid = threadIdx.x;
    const int wid = tid >> 6, lane = tid & 63;
    const int l15 = lane & 15, kl8 = (lane >> 4) << 3;
    const int g16 = gn * 4 + wid;
    const int co = g16 * 16 + l15;

    const ushort_t* xb = y2 + (size_t)b * 32 * 32 * 128;
    const f32x4 z4 = {0.f, 0.f, 0.f, 0.f};
    f32x4 acc[4] = {z4, z4, z4, z4};

#pragma unroll 1
    for (int tap = 0; tap < 9; ++tap) {
        const int ky = tap >= 6 ? 2 : (tap >= 3 ? 1 : 0), kx = tap - ky * 3;
        const int iyA = 2 * oy0 - 1 + ky;
        const int c = 2 * l15 - 1 + kx;
        const bool cok = (c >= 0);
#pragma unroll
        for (int h = 0; h < 4; ++h) {
            const int ci0 = h * 32;
            const int kc = tap * 4 + h;
            bf16x8 aF[4];
#pragma unroll
            for (int mf = 0; mf < 4; ++mf) {
                const int iy = iyA + 2 * mf;
                bf16x8 r = {0, 0, 0, 0, 0, 0, 0, 0};
                if (cok && iy >= 0) r = *reinterpret_cast<const bf16x8*>(xb + ((size_t)iy * 32 + c) * 128 + ci0 + kl8);
                aF[mf] = r;
            }
            const bf16x8 bF = *reinterpret_cast<const bf16x8*>(wpk3 + ((size_t)(kc * 16 + g16) * 64 + lane) * 8);
#pragma unroll
            for (int mf = 0; mf < 4; ++mf)
                acc[mf] = __builtin_amdgcn_mfma_f32_16x16x32_bf16(aF[mf], bF, acc[mf], 0, 0, 0);
        }
    }
    const int kg = lane >> 4;
    const float bias = b3[co];
#pragma unroll
    for (int mp = 0; mp < 2; ++mp) {
        const int py = gy * 2 + mp;
#pragma unroll
        for (int p = 0; p < 2; ++p) {
            float v = fmaxf(fmaxf(acc[2 * mp][2 * p], acc[2 * mp][2 * p + 1]),
                            fmaxf(acc[2 * mp + 1][2 * p], acc[2 * mp + 1][2 * p + 1]));
            const int px = kg * 2 + p;
            y3[((size_t)(b * 8 + py) * 8 + px) * 256 + co] = f2b(fmaxf(v + bias, 0.f));
        }
    }
}

// ---------------- im2col for conv4: y3 bf16 NHWC -> A4 [256][2304] bf16, k = tap*256+ci
__global__ __launch_bounds__(256) void k_im2col4(const ushort_t* __restrict__ y3, ushort_t* __restrict__ A4) {
    const int m = blockIdx.x;                             // 256 blocks
    const int b = m >> 4, pix = m & 15;
    const int oy = pix >> 2, ox = pix & 3;
    const ushort_t* xb = y3 + (size_t)b * 16384;
    for (int it = threadIdx.x; it < 288; it += 256) {
        const int tap = it >> 5, ci8 = it & 31;
        const int ky = tap / 3, kx = tap - 3 * (tap / 3);
        const int iy = 2 * oy - 1 + ky, ix = 2 * ox - 1 + kx;
        bf16x8 r = {0, 0, 0, 0, 0, 0, 0, 0};
        if (iy >= 0 && ix >= 0)
            r = *reinterpret_cast<const bf16x8*>(xb + ((iy * 8 + ix) << 8) + ci8 * 8);
        *reinterpret_cast<bf16x8*>(A4 + (size_t)m * 2304 + tap * 256 + ci8 * 8) = r;
    }
}

// ---------------- conv4 GEMM + relu + mean (K-split across 4 waves, 512 blocks)
__global__ __launch_bounds__(256) void k_conv4g(const ushort_t* __restrict__ A4,
                                                const ushort_t* __restrict__ wpk4m,
                                                const float* __restrict__ b4,
                                                float* __restrict__ feats) {
    const int g16 = blockIdx.x, b = blockIdx.y;
    const int tid = threadIdx.x, wid = tid >> 6, lane = tid & 63;
    const int l15 = lane & 15, kg = lane >> 4, kl8 = kg << 3;
    const f32x4 z4 = {0.f, 0.f, 0.f, 0.f};
    f32x4 acc = z4;
    const ushort_t* arow = A4 + (size_t)(b * 16 + l15) * 2304 + kl8;
    const int kc0 = wid * 18;

#pragma unroll 3
    for (int i = 0; i < 18; ++i) {
        const int kc = kc0 + i;
        const bf16x8 aF = *reinterpret_cast<const bf16x8*>(arow + kc * 32);
        const bf16x8 bF = *reinterpret_cast<const bf16x8*>(wpk4m + ((size_t)(kc * 32 + g16) * 64 + lane) * 8);
        acc = __builtin_amdgcn_mfma_f32_16x16x32_bf16(aF, bF, acc, 0, 0, 0);
    }

    __shared__ f32x4 red[4][64];
    red[wid][lane] = acc;
    __syncthreads();
    if (wid == 0) {
        f32x4 t = red[0][lane];
        t = t + red[1][lane];
        t = t + red[2][lane];
        t = t + red[3][lane];
        const int co = g16 * 16 + l15;
        const float bias = b4[co];
        float s = fmaxf(t[0] + bias, 0.f) + fmaxf(t[1] + bias, 0.f)
                + fmaxf(t[2] + bias, 0.f) + fmaxf(t[3] + bias, 0.f);
        s += __shfl_xor(s, 16, 64);
        s += __shfl_xor(s, 32, 64);
        if (kg == 0) feats[b * 512 + co] = s * 0.0625f;
    }
}

// ---------------- head: feats -> logits -> softmax -> VLAD residual v (16, 32768)
__global__ __launch_bounds__(256) void k_head(const float* __restrict__ feats,
                                              const float* __restrict__ wv,
                                              const float* __restrict__ bv,
                                              const float* __restrict__ centroids,
                                              float* __restrict__ v) {
    const int b = blockIdx.x;
    __shared__ float sf[512];
    __shared__ float sl[64];
    __shared__ float sa[64];
    for (int i = threadIdx.x; i < 512; i += 256) sf[i] = feats[b * 512 + i];
    __syncthreads();
    if (threadIdx.x < 64) {
        const int k = threadIdx.x;
        float s = bv[k];
        for (int c = 0; c < 512; ++c) s += sf[c] * wv[(size_t)k * 512 + c];
        sl[k] = s;
    }
    __syncthreads();
    if (threadIdx.x < 64) {
        const int k = threadIdx.x;
        float m = -1e30f;
        for (int i = 0; i < 64; ++i) m = fmaxf(m, sl[i]);
        float sum = 0.f;
        for (int i = 0; i < 64; ++i) sum += __expf(sl[i] - m);
        sa[k] = __expf(sl[k] - m) / sum;
    }
    __syncthreads();
    for (int i4 = threadIdx.x * 4; i4 < 32768; i4 += 1024) {
        const int k = i4 >> 9;
        const float a_ = sa[k];
        const float4 c4 = *(const float4*)(centroids + i4);
        const float4 f4 = *(const float4*)(&sf[i4 & 511]);
        float4 o;
        o.x = a_ * (f4.x - c4.x);
        o.y = a_ * (f4.y - c4.y);
        o.z = a_ * (f4.z - c4.z);
        o.w = a_ * (f4.w - c4.w);
        *(float4*)(v + (size_t)b * 32768 + i4) = o;
    }
}

// ---------------- fc1a: K-split partial GEMV; part[ks][b][d]
__global__ __launch_bounds__(256) void k_fc1a(const float* __restrict__ v,
                                              const float* __restrict__ fw1,
                                              float* __restrict__ part) {
    const int d = blockIdx.x, ks = blockIdx.y;
    const int base = ks * 4096;
    float acc[16];
#pragma unroll
    for (int i = 0; i < 16; ++i) acc[i] = 0.f;
    const float* wrow = fw1 + (size_t)d * 32768 + base;
    const float* vb = v + base;
#pragma unroll
    for (int it = 0; it < 4; ++it) {
        const int j4 = it * 1024 + threadIdx.x * 4;
        const float4 w = *(const float4*)(wrow + j4);
#pragma unroll
        for (int b = 0; b < 16; ++b) {
            const float4 vv = *(const float4*)(vb + (size_t)b * 32768 + j4);
            acc[b] += w.x * vv.x + w.y * vv.y + w.z * vv.z + w.w * vv.w;
        }
    }
#pragma unroll
    for (int b = 0; b < 16; ++b) {
        float s = acc[b];
        for (int off = 32; off >= 1; off >>= 1) s += __shfl_down(s, off, 64);
        acc[b] = s;
    }
    __shared__ float red[4][16];
    const int wid = threadIdx.x >> 6, lane = threadIdx.x & 63;
    if (lane == 0) {
#pragma unroll
        for (int b = 0; b < 16; ++b) red[wid][b] = acc[b];
    }
    __syncthreads();
    if (threadIdx.x < 16) {
        const int b = threadIdx.x;
        part[((size_t)ks * 16 + b) * 256 + d] = red[0][b] + red[1][b] + red[2][b] + red[3][b];
    }
}

// ---------------- fc1r: reduce 8 partials + bias + relu -> d1 (16,256)
__global__ __launch_bounds__(256) void k_fc1r(const float* __restrict__ part,
                                              const float* __restrict__ fb1,
                                              float* __restrict__ d1) {
    const int i = blockIdx.x * 256 + threadIdx.x;         // 16 blocks -> 4096
    const int d = i & 255;
    float s = fb1[d];
#pragma unroll
    for (int ks = 0; ks < 8; ++ks) s += part[(size_t)ks * 4096 + i];
    d1[i] = fmaxf(s, 0.f);
}

// ---------------- fc2 + L2 norm
__global__ __launch_bounds__(256) void k_fc2(const float* __restrict__ d1,
                                             const float* __restrict__ fw2,
                                             const float* __restrict__ fb2,
                                             float* __restrict__ out) {
    const int b = blockIdx.x;
    const int dd = threadIdx.x;
    __shared__ float sd[256];
    __shared__ float sq[256];
    sd[dd] = d1[b * 256 + dd];
    __syncthreads();
    float s = fb2[dd];
    for (int j = 0; j < 256; ++j) s += sd[j] * fw2[(size_t)dd * 256 + j];
    sq[dd] = s * s;
    __syncthreads();
    for (int off = 128; off >= 1; off >>= 1) {
        if (dd < off) sq[dd] += sq[dd + off];
        __syncthreads();
    }
    const float inv = rsqrtf(sq[0]);
    out[b * 256 + dd] = s * inv;
}

extern "C" void kernel_launch(void* const* d_in, const int* in_sizes, int n_in,
                              void* d_out, int out_size, void* d_ws, size_t ws_size,
                              hipStream_t stream) {
    const float* x    = (const float*)d_in[0];
    const float* w1   = (const float*)d_in[1];
    const float* b1   = (const float*)d_in[2];
    const float* w2   = (const float*)d_in[3];
    const float* b2   = (const float*)d_in[4];
    const float* w3   = (const float*)d_in[5];
    const float* b3   = (const float*)d_in[6];
    const float* w4   = (const float*)d_in[7];
    const float* b4   = (const float*)d_in[8];
    const float* wv   = (const float*)d_in[9];
    const float* bv   = (const float*)d_in[10];
    const float* cen  = (const float*)d_in[11];
    const float* fw1  = (const float*)d_in[12];
    const float* fb1  = (const float*)d_in[13];
    const float* fw2  = (const float*)d_in[14];
    const float* fb2  = (const float*)d_in[15];
    float* out = (float*)d_out;

    char* p = (char*)d_ws;
    ushort_t* y1    = (ushort_t*)p; p += 33554432;  // 16*128*128*64 bf16
    ushort_t* wpk2  = (ushort_t*)p; p += 147456;    // 73728 bf16
    ushort_t* wpk3  = (ushort_t*)p; p += 589824;    // 294912 bf16
    ushort_t* wpk4m = (ushort_t*)p; p += 2359296;   // 1179648 bf16
    ushort_t* wpk1  = (ushort_t*)p; p += 4096;      // 2048 bf16
    // A region (64 MB) — dead after k_conv1g; later buffers alias into it
    char* aRegion = p;
    ushort_t* A    = (ushort_t*)aRegion;            // 1048576*32 bf16 = 64 MB
    char* q = aRegion;
    ushort_t* y2   = (ushort_t*)q; q += 4194304;    // 16*32*32*128 bf16
    ushort_t* y3   = (ushort_t*)q; q += 524288;     // 16*8*8*256 bf16
    float*    feats= (float*)q;    q += 32768;      // 16*512
    float*    vbuf = (float*)q;    q += 2097152;    // 16*32768
    float*    d1   = (float*)q;    q += 16384;      // 16*256
    ushort_t* A4   = (ushort_t*)q; q += 1179648;    // 256*2304 bf16
    float*    part = (float*)q;    q += 131072;     // 8*16*256 f32

    const size_t need = (size_t)(aRegion - (char*)d_ws) + 67108864;
    const bool useMfmaConv1 = (ws_size >= need);

    k_pack2<<<36, 256, 0, stream>>>(w2, wpk2);
    k_pack3<<<144, 256, 0, stream>>>(w3, wpk3);
    k_pack4m<<<512, 256, 0, stream>>>(w4, wpk4m);
    if (useMfmaConv1) {
        k_pack1<<<1, 256, 0, stream>>>(w1, wpk1);
        k_im2col2b<<<2048, 256, 0, stream>>>(x, A);
        k_conv1g<<<1024, 256, 0, stream>>>(A, wpk1, b1, y1);
    } else {
        k_conv1<<<dim3(256, 16), 256, 0, stream>>>(x, w1, b1, y1);
    }
    k_conv2m<<<dim3(32, 2, 16), 256, 0, stream>>>(y1, wpk2, b2, y2);
    k_conv3m<<<dim3(4, 4, 16), 256, 0, stream>>>(y2, wpk3, b3, y3);
    k_im2col4<<<256, 256, 0, stream>>>(y3, A4);
    k_conv4g<<<dim3(32, 16), 256, 0, stream>>>(A4, wpk4m, b4, feats);
    k_head<<<16, 256, 0, stream>>>(feats, wv, bv, cen, vbuf);
    k_fc1a<<<dim3(256, 8), 256, 0, stream>>>(vbuf, fw1, part);
    k_fc1r<<<16, 256, 0, stream>>>(part, fb1, d1);
    k_fc2<<<16, 256, 0, stream>>>(d1, fw2, fb2, out);
}

// Round 11
// 192.814 us; speedup vs baseline: 1.1511x; 1.1511x over previous
//
#include <hip/hip_runtime.h>
#include <hip/hip_bf16.h>

typedef unsigned short ushort_t;
typedef short bf16x8 __attribute__((ext_vector_type(8)));
typedef float f32x4 __attribute__((ext_vector_type(4)));

__device__ __forceinline__ ushort_t f2b(float f) {
    __hip_bfloat16 h = __float2bfloat16(f);
    return *reinterpret_cast<ushort_t*>(&h);
}
__device__ __forceinline__ float b2f(short v) {
    union { unsigned int u; float f; } cv;
    cv.u = ((unsigned int)(ushort_t)v) << 16;
    return cv.f;
}

// ---------------- weight repack: w1 (64,3,3,3) -> B-frag order [nf(4)][lane(64)][8], K order k = tap*3+c
__global__ __launch_bounds__(256) void k_pack1(const float* __restrict__ w1, ushort_t* __restrict__ o) {
    const int slot = threadIdx.x;                         // 256 slots
    const int lane = slot & 63, nf = slot >> 6;
    const int co = nf * 16 + (lane & 15);
    const int kg = lane >> 4;
#pragma unroll
    for (int j = 0; j < 8; ++j) {
        const int k = kg * 8 + j;
        float v = 0.f;
        if (k < 27) {
            const int t = k / 3, c = k - 3 * t;
            v = w1[(co * 3 + c) * 9 + t];
        }
        o[slot * 8 + j] = f2b(v);
    }
}

// ---------------- weight repack: w2 (128,64,3,3) -> B-fragment order, bf16
// K order = tap*64 + s, where storage channel s maps to original ci = 16*(s&3) + (s>>2)
__global__ __launch_bounds__(256) void k_pack2(const float* __restrict__ w2, ushort_t* __restrict__ o) {
    const int slot = blockIdx.x * 256 + threadIdx.x;      // 9216 slots
    const int lane = slot & 63, g = (slot >> 6) & 7, kc = slot >> 9;
    const int k0 = kc * 32 + ((lane >> 4) << 3);
    const int tap = k0 >> 6, sb = k0 & 63;
    const int ky = tap >= 6 ? 2 : (tap >= 3 ? 1 : 0), kx = tap - ky * 3;
    const int co = g * 16 + (lane & 15);
#pragma unroll
    for (int j = 0; j < 8; ++j) {
        const int s = sb + j;
        const int ci = 16 * (s & 3) + (s >> 2);
        o[slot * 8 + j] = f2b(w2[((co * 64 + ci) * 3 + ky) * 3 + kx]);
    }
}

// w3 (256,128,3,3): [kc(36)][g16(16)][lane][8], K order = tap*128+ci
__global__ __launch_bounds__(256) void k_pack3(const float* __restrict__ w3, ushort_t* __restrict__ o) {
    const int slot = blockIdx.x * 256 + threadIdx.x;      // 36864 slots
    const int lane = slot & 63, g = (slot >> 6) & 15, kc = slot >> 10;
    const int k0 = kc * 32 + ((lane >> 4) << 3);
    const int tap = k0 >> 7, cib = k0 & 127;
    const int ky = tap >= 6 ? 2 : (tap >= 3 ? 1 : 0), kx = tap - ky * 3;
    const int co = g * 16 + (lane & 15);
#pragma unroll
    for (int j = 0; j < 8; ++j)
        o[slot * 8 + j] = f2b(w3[((co * 128 + cib + j) * 3 + ky) * 3 + kx]);
}

// w4 (512,256,3,3) -> MFMA B-frag bf16 [kc(72)][g16(32)][lane(64)][8], K order = tap*256+ci
__global__ __launch_bounds__(256) void k_pack4m(const float* __restrict__ w4, ushort_t* __restrict__ o) {
    const int co = blockIdx.x;                            // 512 blocks
    __shared__ float sw[2304];
    for (int i = threadIdx.x; i < 2304; i += 256) sw[i] = w4[(size_t)co * 2304 + i];
    __syncthreads();
    const int g = co >> 4, l15 = co & 15;
    for (int it = threadIdx.x; it < 288; it += 256) {
        const int kc = it >> 2, kg = it & 3;
        const int k0 = kc * 32 + kg * 8;
        const int tap = k0 >> 8, ci0 = k0 & 255;
        const int lane = kg * 16 + l15;
        ushort_t tmp[8];
#pragma unroll
        for (int j = 0; j < 8; ++j)
            tmp[j] = f2b(sw[(ci0 + j) * 9 + tap]);
        *(float4*)(o + ((size_t)(kc * 32 + g) * 64 + lane) * 8) = *(const float4*)tmp;
    }
}

// ---------------- im2col for conv1 (aligned loads, contiguous wave stores)
__global__ __launch_bounds__(256) void k_im2col2b(const float* __restrict__ x, ushort_t* __restrict__ A) {
    const int t = blockIdx.x * 256 + threadIdx.x;         // 2048 blocks
    const int dy = t & 1;
    const int px = (t >> 1) & 127;
    const int py = (t >> 8) & 127;
    const int b  = t >> 15;
    const int oy = 2 * py + dy;
    const int iy0 = 2 * oy - 1;
    const float* xb = x + (size_t)b * 3 * 512 * 512;
    const int lane = threadIdx.x & 63;

    ushort_t r0[32], r1[32];
#pragma unroll
    for (int k = 0; k < 32; ++k) { r0[k] = 0; r1[k] = 0; }

#pragma unroll
    for (int c = 0; c < 3; ++c) {
#pragma unroll
        for (int ky = 0; ky < 3; ++ky) {
            const int iy = iy0 + ky;
            const float* rp = xb + ((size_t)c * 512 + iy) * 512;
            float4 q = {0.f, 0.f, 0.f, 0.f};
            if (iy >= 0) q = *(const float4*)(rp + 4 * px);   // 16B-aligned dwordx4
            float vm1 = __shfl_up(q.w, 2, 64);                // col 4px-1: lane-2 = (px-1, same dy)
            if (lane < 2) vm1 = (px > 0 && iy >= 0) ? rp[4 * px - 1] : 0.f;
            const int kb = ky * 9 + c;
            r0[kb]     = f2b(vm1);  r1[kb]     = f2b(q.y);
            r0[kb + 3] = f2b(q.x);  r1[kb + 3] = f2b(q.z);
            r0[kb + 6] = f2b(q.y);  r1[kb + 6] = f2b(q.w);
        }
    }
    const size_t m0 = (((size_t)(b * 128 + py) * 128 + px) << 2) + (dy << 1);
    float4* dst = (float4*)(A + m0 * 32);
    const float4* s0 = (const float4*)r0;
    const float4* s1 = (const float4*)r1;
    dst[0] = s0[0]; dst[1] = s0[1]; dst[2] = s0[2]; dst[3] = s0[3];
    dst[4] = s1[0]; dst[5] = s1[1]; dst[6] = s1[2]; dst[7] = s1[3];
}

// ---------------- conv1 GEMM: A [1M][32] x w1 [32][64] -> pool+bias+relu -> y1 bf16 NHWC
// y1 channel storage order: s = 4*l15 + nf  (original co = nf*16 + l15) -> 8B store per lane
__global__ __launch_bounds__(256) void k_conv1g(const ushort_t* __restrict__ A,
                                                const ushort_t* __restrict__ wpk1,
                                                const float* __restrict__ b1,
                                                ushort_t* __restrict__ y1) {
    const int tid = threadIdx.x;
    const int wid = tid >> 6, lane = tid & 63;
    const int l15 = lane & 15, kg = lane >> 4;

    bf16x8 bF[4];
    float bias[4];
#pragma unroll
    for (int nf = 0; nf < 4; ++nf) {
        bF[nf] = *reinterpret_cast<const bf16x8*>(wpk1 + (size_t)(nf * 64 + lane) * 8);
        bias[nf] = b1[nf * 16 + l15];
    }
    const f32x4 z4 = {0.f, 0.f, 0.f, 0.f};
    const int f0 = blockIdx.x * 64 + wid * 16;

#pragma unroll 2
    for (int it = 0; it < 16; ++it) {
        const int f = f0 + it;
        const bf16x8 aF = *reinterpret_cast<const bf16x8*>(A + ((size_t)f * 16 + l15) * 32 + kg * 8);
        f32x4 acc[4];
#pragma unroll
        for (int nf = 0; nf < 4; ++nf)
            acc[nf] = __builtin_amdgcn_mfma_f32_16x16x32_bf16(aF, bF[nf], z4, 0, 0, 0);
        const int g = f * 4 + kg;
        const int px = g & 127, py = (g >> 7) & 127, b = g >> 14;
        union { ushort_t u[4]; uint2 v; } pk;
#pragma unroll
        for (int nf = 0; nf < 4; ++nf) {
            float v = fmaxf(fmaxf(acc[nf][0], acc[nf][1]), fmaxf(acc[nf][2], acc[nf][3]));
            pk.u[nf] = f2b(fmaxf(v + bias[nf], 0.f));
        }
        *(uint2*)(y1 + ((size_t)(b * 128 + py) * 128 + px) * 64 + 4 * l15) = pk.v;
    }
}

// ---------------- fallback conv1 (scalar path; writes permuted channel order)
__global__ __launch_bounds__(256, 4) void k_conv1(const float* __restrict__ x,
                                                  const float* __restrict__ w1,
                                                  const float* __restrict__ b1,
                                                  ushort_t* __restrict__ y1) {
    const int b = blockIdx.y;
    const int tileY = blockIdx.x >> 4, tileX = blockIdx.x & 15;
    const int tid = threadIdx.x;
    const int cog = __builtin_amdgcn_readfirstlane(tid >> 6);
    const int pix = tid & 63;
    const int ty = pix >> 3, tx = pix & 7;

    __shared__ float sIn[3 * 33 * 36];
    const int iyb = 32 * tileY - 1, ixb = 32 * tileX - 1;
    const float* xb = x + (size_t)b * 3 * 512 * 512;
    for (int idx = tid; idx < 3564; idx += 256) {
        const int col = idx % 36;
        const int rc = idx / 36;
        const int r = rc % 33, c = rc / 33;
        const int iy = iyb + r, ix = ixb + col;
        float v = 0.f;
        if (col < 33 && iy >= 0 && iy < 512 && ix >= 0 && ix < 512)
            v = xb[((size_t)c * 512 + iy) * 512 + ix];
        sIn[rc * 36 + col] = v;
    }
    __syncthreads();

    const float* wS = w1 + cog * (16 * 27);
    float acc[4][16];
#pragma unroll
    for (int p = 0; p < 4; ++p)
#pragma unroll
        for (int co = 0; co < 16; ++co) acc[p][co] = 0.f;

#pragma unroll
    for (int c = 0; c < 3; ++c) {
        float in[5][5];
#pragma unroll
        for (int r = 0; r < 5; ++r) {
            const float* rp = &sIn[(c * 33 + 4 * ty + r) * 36 + 4 * tx];
            const float4 qv = *(const float4*)rp;
            in[r][0] = qv.x; in[r][1] = qv.y; in[r][2] = qv.z; in[r][3] = qv.w;
            in[r][4] = rp[4];
        }
#pragma unroll
        for (int ky = 0; ky < 3; ++ky)
#pragma unroll
        for (int kx = 0; kx < 3; ++kx) {
            const int j = c * 9 + ky * 3 + kx;
#pragma unroll
            for (int co = 0; co < 16; ++co) {
                const float w = wS[co * 27 + j];
                acc[0][co] += in[ky][kx] * w;
                acc[1][co] += in[ky][kx + 2] * w;
                acc[2][co] += in[ky + 2][kx] * w;
                acc[3][co] += in[ky + 2][kx + 2] * w;
            }
        }
    }

    const int py = 8 * tileY + ty, px = 8 * tileX + tx;
    ushort_t* op = y1 + ((size_t)(b * 128 + py) * 128 + px) * 64;
#pragma unroll
    for (int co = 0; co < 16; ++co) {
        float m = fmaxf(fmaxf(acc[0][co], acc[1][co]), fmaxf(acc[2][co], acc[3][co]));
        const int c = cog * 16 + co;
        op[4 * (c & 15) + (c >> 4)] = f2b(fmaxf(m + b1[c], 0.f));
    }
}

// ---------------- conv2 MFMA (M-split): y1 bf16 (permuted ch) -> y2 bf16 NHWC (16,32,32,128)
// grid (rp=32, xh=2, b=16) = 1024 blocks; block = oy-pair x 32-ox half x all 128 co
// wave: 2 N-frags x 4 M-frags (2 oy x 2 ox-blocks); A-loads partition cleanly by xh (no duplication)
__global__ __launch_bounds__(256) void k_conv2m(const ushort_t* __restrict__ y1,
                                                const ushort_t* __restrict__ wpk2,
                                                const float* __restrict__ b2,
                                                ushort_t* __restrict__ y2) {
    const int b = blockIdx.z;
    const int xh = blockIdx.y;               // ox half: ox-blocks {2xh, 2xh+1}
    const int rp = blockIdx.x;               // pooled row 0..31
    const int oy0 = rp * 2;
    const int tid = threadIdx.x;
    const int wid = tid >> 6, lane = tid & 63;
    const int l15 = lane & 15, kl8 = (lane >> 4) << 3;

    const ushort_t* xb = y1 + (size_t)b * 128 * 128 * 64;
    const f32x4 z4 = {0.f, 0.f, 0.f, 0.f};
    f32x4 acc[2][2][2];                      // [oyi][m2][nf]
#pragma unroll
    for (int i = 0; i < 2; ++i)
#pragma unroll
        for (int j = 0; j < 2; ++j) { acc[i][j][0] = z4; acc[i][j][1] = z4; }

    const int cb0 = 2 * l15 - 1 + xh * 64;   // input col base for this half

#pragma unroll 1
    for (int tap = 0; tap < 9; ++tap) {
        const int ky = tap >= 6 ? 2 : (tap >= 3 ? 1 : 0), kx = tap - ky * 3;
        const int iyA = 2 * oy0 - 1 + ky;
#pragma unroll
        for (int h = 0; h < 2; ++h) {
            const int ci0 = h * 32;
            const int kc = tap * 2 + h;
            bf16x8 aF[2][2];
#pragma unroll
            for (int oyi = 0; oyi < 2; ++oyi)
#pragma unroll
            for (int m2 = 0; m2 < 2; ++m2) {
                const int iy = iyA + 2 * oyi;
                const int c = cb0 + m2 * 32 + kx;
                const bool ok = (iy >= 0) && (c >= 0);
                bf16x8 r = {0, 0, 0, 0, 0, 0, 0, 0};
                if (ok) r = *reinterpret_cast<const bf16x8*>(xb + ((size_t)iy * 128 + c) * 64 + ci0 + kl8);
                aF[oyi][m2] = r;
            }
            bf16x8 bF[2];
#pragma unroll
            for (int nf = 0; nf < 2; ++nf)
                bF[nf] = *reinterpret_cast<const bf16x8*>(wpk2 + ((size_t)(kc * 8 + wid * 2 + nf) * 64 + lane) * 8);
#pragma unroll
            for (int oyi = 0; oyi < 2; ++oyi)
#pragma unroll
            for (int m2 = 0; m2 < 2; ++m2)
#pragma unroll
            for (int nf = 0; nf < 2; ++nf)
                acc[oyi][m2][nf] = __builtin_amdgcn_mfma_f32_16x16x32_bf16(aF[oyi][m2], bF[nf], acc[oyi][m2][nf], 0, 0, 0);
        }
    }
    const int kg = lane >> 4;
#pragma unroll
    for (int nf = 0; nf < 2; ++nf) {
        const int co = wid * 32 + nf * 16 + l15;
        const float bias = b2[co];
#pragma unroll
        for (int m2 = 0; m2 < 2; ++m2)
#pragma unroll
            for (int p = 0; p < 2; ++p) {
                float v = fmaxf(fmaxf(acc[0][m2][nf][2 * p], acc[0][m2][nf][2 * p + 1]),
                                fmaxf(acc[1][m2][nf][2 * p], acc[1][m2][nf][2 * p + 1]));
                const int px = (xh * 2 + m2) * 8 + kg * 2 + p;
                y2[((size_t)(b * 32 + rp) * 32 + px) * 128 + co] = f2b(fmaxf(v + bias, 0.f));
            }
    }
}

// ---------------- conv3 MFMA: y2 bf16 NHWC -> y3 bf16 NHWC (16,8,8,256)
__global__ __launch_bounds__(256) void k_conv3m(const ushort_t* __restrict__ y2,
                                                const ushort_t* __restrict__ wpk3,
                                                const float* __restrict__ b3,
                                                ushort_t* __restrict__ y3) {
    const int gy = blockIdx.x, gn = blockIdx.y, b = blockIdx.z;
    const int oy0 = gy * 4;
    const int tid = threadIdx.x;
    const int wid = tid >> 6, lane = tid & 63;
    const int l15 = lane & 15, kl8 = (lane >> 4) << 3;
    const int g16 = gn * 4 + wid;
    const int co = g16 * 16 + l15;

    const ushort_t* xb = y2 + (size_t)b * 32 * 32 * 128;
    const f32x4 z4 = {0.f, 0.f, 0.f, 0.f};
    f32x4 acc[4] = {z4, z4, z4, z4};

#pragma unroll 1
    for (int tap = 0; tap < 9; ++tap) {
        const int ky = tap >= 6 ? 2 : (tap >= 3 ? 1 : 0), kx = tap - ky * 3;
        const int iyA = 2 * oy0 - 1 + ky;
        const int c = 2 * l15 - 1 + kx;
        const bool cok = (c >= 0);
#pragma unroll
        for (int h = 0; h < 4; ++h) {
            const int ci0 = h * 32;
            const int kc = tap * 4 + h;
            bf16x8 aF[4];
#pragma unroll
            for (int mf = 0; mf < 4; ++mf) {
                const int iy = iyA + 2 * mf;
                bf16x8 r = {0, 0, 0, 0, 0, 0, 0, 0};
                if (cok && iy >= 0) r = *reinterpret_cast<const bf16x8*>(xb + ((size_t)iy * 32 + c) * 128 + ci0 + kl8);
                aF[mf] = r;
            }
            const bf16x8 bF = *reinterpret_cast<const bf16x8*>(wpk3 + ((size_t)(kc * 16 + g16) * 64 + lane) * 8);
#pragma unroll
            for (int mf = 0; mf < 4; ++mf)
                acc[mf] = __builtin_amdgcn_mfma_f32_16x16x32_bf16(aF[mf], bF, acc[mf], 0, 0, 0);
        }
    }
    const int kg = lane >> 4;
    const float bias = b3[co];
#pragma unroll
    for (int mp = 0; mp < 2; ++mp) {
        const int py = gy * 2 + mp;
#pragma unroll
        for (int p = 0; p < 2; ++p) {
            float v = fmaxf(fmaxf(acc[2 * mp][2 * p], acc[2 * mp][2 * p + 1]),
                            fmaxf(acc[2 * mp + 1][2 * p], acc[2 * mp + 1][2 * p + 1]));
            const int px = kg * 2 + p;
            y3[((size_t)(b * 8 + py) * 8 + px) * 256 + co] = f2b(fmaxf(v + bias, 0.f));
        }
    }
}

// ---------------- im2col for conv4: y3 bf16 NHWC -> A4 [256][2304] bf16, k = tap*256+ci
__global__ __launch_bounds__(256) void k_im2col4(const ushort_t* __restrict__ y3, ushort_t* __restrict__ A4) {
    const int m = blockIdx.x;                             // 256 blocks
    const int b = m >> 4, pix = m & 15;
    const int oy = pix >> 2, ox = pix & 3;
    const ushort_t* xb = y3 + (size_t)b * 16384;
    for (int it = threadIdx.x; it < 288; it += 256) {
        const int tap = it >> 5, ci8 = it & 31;
        const int ky = tap / 3, kx = tap - 3 * (tap / 3);
        const int iy = 2 * oy - 1 + ky, ix = 2 * ox - 1 + kx;
        bf16x8 r = {0, 0, 0, 0, 0, 0, 0, 0};
        if (iy >= 0 && ix >= 0)
            r = *reinterpret_cast<const bf16x8*>(xb + ((iy * 8 + ix) << 8) + ci8 * 8);
        *reinterpret_cast<bf16x8*>(A4 + (size_t)m * 2304 + tap * 256 + ci8 * 8) = r;
    }
}

// ---------------- conv4 GEMM + relu + mean (K-split across 4 waves, 512 blocks)
__global__ __launch_bounds__(256) void k_conv4g(const ushort_t* __restrict__ A4,
                                                const ushort_t* __restrict__ wpk4m,
                                                const float* __restrict__ b4,
                                                float* __restrict__ feats) {
    const int g16 = blockIdx.x, b = blockIdx.y;
    const int tid = threadIdx.x, wid = tid >> 6, lane = tid & 63;
    const int l15 = lane & 15, kg = lane >> 4, kl8 = kg << 3;
    const f32x4 z4 = {0.f, 0.f, 0.f, 0.f};
    f32x4 acc = z4;
    const ushort_t* arow = A4 + (size_t)(b * 16 + l15) * 2304 + kl8;
    const int kc0 = wid * 18;

#pragma unroll 3
    for (int i = 0; i < 18; ++i) {
        const int kc = kc0 + i;
        const bf16x8 aF = *reinterpret_cast<const bf16x8*>(arow + kc * 32);
        const bf16x8 bF = *reinterpret_cast<const bf16x8*>(wpk4m + ((size_t)(kc * 32 + g16) * 64 + lane) * 8);
        acc = __builtin_amdgcn_mfma_f32_16x16x32_bf16(aF, bF, acc, 0, 0, 0);
    }

    __shared__ f32x4 red[4][64];
    red[wid][lane] = acc;
    __syncthreads();
    if (wid == 0) {
        f32x4 t = red[0][lane];
        t = t + red[1][lane];
        t = t + red[2][lane];
        t = t + red[3][lane];
        const int co = g16 * 16 + l15;
        const float bias = b4[co];
        float s = fmaxf(t[0] + bias, 0.f) + fmaxf(t[1] + bias, 0.f)
                + fmaxf(t[2] + bias, 0.f) + fmaxf(t[3] + bias, 0.f);
        s += __shfl_xor(s, 16, 64);
        s += __shfl_xor(s, 32, 64);
        if (kg == 0) feats[b * 512 + co] = s * 0.0625f;
    }
}

// ---------------- head: feats -> logits -> softmax -> VLAD residual v (16, 32768)
__global__ __launch_bounds__(256) void k_head(const float* __restrict__ feats,
                                              const float* __restrict__ wv,
                                              const float* __restrict__ bv,
                                              const float* __restrict__ centroids,
                                              float* __restrict__ v) {
    const int b = blockIdx.x;
    __shared__ float sf[512];
    __shared__ float sl[64];
    __shared__ float sa[64];
    for (int i = threadIdx.x; i < 512; i += 256) sf[i] = feats[b * 512 + i];
    __syncthreads();
    if (threadIdx.x < 64) {
        const int k = threadIdx.x;
        float s = bv[k];
        for (int c = 0; c < 512; ++c) s += sf[c] * wv[(size_t)k * 512 + c];
        sl[k] = s;
    }
    __syncthreads();
    if (threadIdx.x < 64) {
        const int k = threadIdx.x;
        float m = -1e30f;
        for (int i = 0; i < 64; ++i) m = fmaxf(m, sl[i]);
        float sum = 0.f;
        for (int i = 0; i < 64; ++i) sum += __expf(sl[i] - m);
        sa[k] = __expf(sl[k] - m) / sum;
    }
    __syncthreads();
    for (int i4 = threadIdx.x * 4; i4 < 32768; i4 += 1024) {
        const int k = i4 >> 9;
        const float a_ = sa[k];
        const float4 c4 = *(const float4*)(centroids + i4);
        const float4 f4 = *(const float4*)(&sf[i4 & 511]);
        float4 o;
        o.x = a_ * (f4.x - c4.x);
        o.y = a_ * (f4.y - c4.y);
        o.z = a_ * (f4.z - c4.z);
        o.w = a_ * (f4.w - c4.w);
        *(float4*)(v + (size_t)b * 32768 + i4) = o;
    }
}

// ---------------- fc1a: K-split partial GEMV; part[ks][b][d]
__global__ __launch_bounds__(256) void k_fc1a(const float* __restrict__ v,
                                              const float* __restrict__ fw1,
                                              float* __restrict__ part) {
    const int d = blockIdx.x, ks = blockIdx.y;
    const int base = ks * 4096;
    float acc[16];
#pragma unroll
    for (int i = 0; i < 16; ++i) acc[i] = 0.f;
    const float* wrow = fw1 + (size_t)d * 32768 + base;
    const float* vb = v + base;
#pragma unroll
    for (int it = 0; it < 4; ++it) {
        const int j4 = it * 1024 + threadIdx.x * 4;
        const float4 w = *(const float4*)(wrow + j4);
#pragma unroll
        for (int b = 0; b < 16; ++b) {
            const float4 vv = *(const float4*)(vb + (size_t)b * 32768 + j4);
            acc[b] += w.x * vv.x + w.y * vv.y + w.z * vv.z + w.w * vv.w;
        }
    }
#pragma unroll
    for (int b = 0; b < 16; ++b) {
        float s = acc[b];
        for (int off = 32; off >= 1; off >>= 1) s += __shfl_down(s, off, 64);
        acc[b] = s;
    }
    __shared__ float red[4][16];
    const int wid = threadIdx.x >> 6, lane = threadIdx.x & 63;
    if (lane == 0) {
#pragma unroll
        for (int b = 0; b < 16; ++b) red[wid][b] = acc[b];
    }
    __syncthreads();
    if (threadIdx.x < 16) {
        const int b = threadIdx.x;
        part[((size_t)ks * 16 + b) * 256 + d] = red[0][b] + red[1][b] + red[2][b] + red[3][b];
    }
}

// ---------------- fc1r: reduce 8 partials + bias + relu -> d1 (16,256)
__global__ __launch_bounds__(256) void k_fc1r(const float* __restrict__ part,
                                              const float* __restrict__ fb1,
                                              float* __restrict__ d1) {
    const int i = blockIdx.x * 256 + threadIdx.x;         // 16 blocks -> 4096
    const int d = i & 255;
    float s = fb1[d];
#pragma unroll
    for (int ks = 0; ks < 8; ++ks) s += part[(size_t)ks * 4096 + i];
    d1[i] = fmaxf(s, 0.f);
}

// ---------------- fc2 + L2 norm
__global__ __launch_bounds__(256) void k_fc2(const float* __restrict__ d1,
                                             const float* __restrict__ fw2,
                                             const float* __restrict__ fb2,
                                             float* __restrict__ out) {
    const int b = blockIdx.x;
    const int dd = threadIdx.x;
    __shared__ float sd[256];
    __shared__ float sq[256];
    sd[dd] = d1[b * 256 + dd];
    __syncthreads();
    float s = fb2[dd];
    for (int j = 0; j < 256; ++j) s += sd[j] * fw2[(size_t)dd * 256 + j];
    sq[dd] = s * s;
    __syncthreads();
    for (int off = 128; off >= 1; off >>= 1) {
        if (dd < off) sq[dd] += sq[dd + off];
        __syncthreads();
    }
    const float inv = rsqrtf(sq[0]);
    out[b * 256 + dd] = s * inv;
}

extern "C" void kernel_launch(void* const* d_in, const int* in_sizes, int n_in,
                              void* d_out, int out_size, void* d_ws, size_t ws_size,
                              hipStream_t stream) {
    const float* x    = (const float*)d_in[0];
    const float* w1   = (const float*)d_in[1];
    const float* b1   = (const float*)d_in[2];
    const float* w2   = (const float*)d_in[3];
    const float* b2   = (const float*)d_in[4];
    const float* w3   = (const float*)d_in[5];
    const float* b3   = (const float*)d_in[6];
    const float* w4   = (const float*)d_in[7];
    const float* b4   = (const float*)d_in[8];
    const float* wv   = (const float*)d_in[9];
    const float* bv   = (const float*)d_in[10];
    const float* cen  = (const float*)d_in[11];
    const float* fw1  = (const float*)d_in[12];
    const float* fb1  = (const float*)d_in[13];
    const float* fw2  = (const float*)d_in[14];
    const float* fb2  = (const float*)d_in[15];
    float* out = (float*)d_out;

    char* p = (char*)d_ws;
    ushort_t* y1    = (ushort_t*)p; p += 33554432;  // 16*128*128*64 bf16
    ushort_t* wpk2  = (ushort_t*)p; p += 147456;    // 73728 bf16
    ushort_t* wpk3  = (ushort_t*)p; p += 589824;    // 294912 bf16
    ushort_t* wpk4m = (ushort_t*)p; p += 2359296;   // 1179648 bf16
    ushort_t* wpk1  = (ushort_t*)p; p += 4096;      // 2048 bf16
    // A region (64 MB) — dead after k_conv1g; later buffers alias into it
    char* aRegion = p;
    ushort_t* A    = (ushort_t*)aRegion;            // 1048576*32 bf16 = 64 MB
    char* q = aRegion;
    ushort_t* y2   = (ushort_t*)q; q += 4194304;    // 16*32*32*128 bf16
    ushort_t* y3   = (ushort_t*)q; q += 524288;     // 16*8*8*256 bf16
    float*    feats= (float*)q;    q += 32768;      // 16*512
    float*    vbuf = (float*)q;    q += 2097152;    // 16*32768
    float*    d1   = (float*)q;    q += 16384;      // 16*256
    ushort_t* A4   = (ushort_t*)q; q += 1179648;    // 256*2304 bf16
    float*    part = (float*)q;    q += 131072;     // 8*16*256 f32

    const size_t need = (size_t)(aRegion - (char*)d_ws) + 67108864;
    const bool useMfmaConv1 = (ws_size >= need);

    k_pack2<<<36, 256, 0, stream>>>(w2, wpk2);
    k_pack3<<<144, 256, 0, stream>>>(w3, wpk3);
    k_pack4m<<<512, 256, 0, stream>>>(w4, wpk4m);
    if (useMfmaConv1) {
        k_pack1<<<1, 256, 0, stream>>>(w1, wpk1);
        k_im2col2b<<<2048, 256, 0, stream>>>(x, A);
        k_conv1g<<<1024, 256, 0, stream>>>(A, wpk1, b1, y1);
    } else {
        k_conv1<<<dim3(256, 16), 256, 0, stream>>>(x, w1, b1, y1);
    }
    k_conv2m<<<dim3(32, 2, 16), 256, 0, stream>>>(y1, wpk2, b2, y2);
    k_conv3m<<<dim3(4, 4, 16), 256, 0, stream>>>(y2, wpk3, b3, y3);
    k_im2col4<<<256, 256, 0, stream>>>(y3, A4);
    k_conv4g<<<dim3(32, 16), 256, 0, stream>>>(A4, wpk4m, b4, feats);
    k_head<<<16, 256, 0, stream>>>(feats, wv, bv, cen, vbuf);
    k_fc1a<<<dim3(256, 8), 256, 0, stream>>>(vbuf, fw1, part);
    k_fc1r<<<16, 256, 0, stream>>>(part, fb1, d1);
    k_fc2<<<16, 256, 0, stream>>>(d1, fw2, fb2, out);
}

// Round 12
// 192.692 us; speedup vs baseline: 1.1518x; 1.0006x over previous
//
#include <hip/hip_runtime.h>
#include <hip/hip_bf16.h>

typedef unsigned short ushort_t;
typedef short bf16x8 __attribute__((ext_vector_type(8)));
typedef float f32x4 __attribute__((ext_vector_type(4)));

__device__ __forceinline__ ushort_t f2b(float f) {
    __hip_bfloat16 h = __float2bfloat16(f);
    return *reinterpret_cast<ushort_t*>(&h);
}
__device__ __forceinline__ float b2f(short v) {
    union { unsigned int u; float f; } cv;
    cv.u = ((unsigned int)(ushort_t)v) << 16;
    return cv.f;
}

// ---------------- weight repack: w1 (64,3,3,3) -> B-frag order [nf(4)][lane(64)][8], K order k = tap*3+c
__global__ __launch_bounds__(256) void k_pack1(const float* __restrict__ w1, ushort_t* __restrict__ o) {
    const int slot = threadIdx.x;                         // 256 slots
    const int lane = slot & 63, nf = slot >> 6;
    const int co = nf * 16 + (lane & 15);
    const int kg = lane >> 4;
#pragma unroll
    for (int j = 0; j < 8; ++j) {
        const int k = kg * 8 + j;
        float v = 0.f;
        if (k < 27) {
            const int t = k / 3, c = k - 3 * t;
            v = w1[(co * 3 + c) * 9 + t];
        }
        o[slot * 8 + j] = f2b(v);
    }
}

// ---------------- weight repack: w2 (128,64,3,3) -> B-fragment order, bf16
// K order = tap*64 + s, where storage channel s maps to original ci = 16*(s&3) + (s>>2)
__global__ __launch_bounds__(256) void k_pack2(const float* __restrict__ w2, ushort_t* __restrict__ o) {
    const int slot = blockIdx.x * 256 + threadIdx.x;      // 9216 slots
    const int lane = slot & 63, g = (slot >> 6) & 7, kc = slot >> 9;
    const int k0 = kc * 32 + ((lane >> 4) << 3);
    const int tap = k0 >> 6, sb = k0 & 63;
    const int ky = tap >= 6 ? 2 : (tap >= 3 ? 1 : 0), kx = tap - ky * 3;
    const int co = g * 16 + (lane & 15);
#pragma unroll
    for (int j = 0; j < 8; ++j) {
        const int s = sb + j;
        const int ci = 16 * (s & 3) + (s >> 2);
        o[slot * 8 + j] = f2b(w2[((co * 64 + ci) * 3 + ky) * 3 + kx]);
    }
}

// w3 (256,128,3,3): [kc(36)][g16(16)][lane][8], K order = tap*128+ci
__global__ __launch_bounds__(256) void k_pack3(const float* __restrict__ w3, ushort_t* __restrict__ o) {
    const int slot = blockIdx.x * 256 + threadIdx.x;      // 36864 slots
    const int lane = slot & 63, g = (slot >> 6) & 15, kc = slot >> 10;
    const int k0 = kc * 32 + ((lane >> 4) << 3);
    const int tap = k0 >> 7, cib = k0 & 127;
    const int ky = tap >= 6 ? 2 : (tap >= 3 ? 1 : 0), kx = tap - ky * 3;
    const int co = g * 16 + (lane & 15);
#pragma unroll
    for (int j = 0; j < 8; ++j)
        o[slot * 8 + j] = f2b(w3[((co * 128 + cib + j) * 3 + ky) * 3 + kx]);
}

// w4 (512,256,3,3) -> MFMA B-frag bf16 [kc(72)][g16(32)][lane(64)][8], K order = tap*256+ci
__global__ __launch_bounds__(256) void k_pack4m(const float* __restrict__ w4, ushort_t* __restrict__ o) {
    const int co = blockIdx.x;                            // 512 blocks
    __shared__ float sw[2304];
    for (int i = threadIdx.x; i < 2304; i += 256) sw[i] = w4[(size_t)co * 2304 + i];
    __syncthreads();
    const int g = co >> 4, l15 = co & 15;
    for (int it = threadIdx.x; it < 288; it += 256) {
        const int kc = it >> 2, kg = it & 3;
        const int k0 = kc * 32 + kg * 8;
        const int tap = k0 >> 8, ci0 = k0 & 255;
        const int lane = kg * 16 + l15;
        ushort_t tmp[8];
#pragma unroll
        for (int j = 0; j < 8; ++j)
            tmp[j] = f2b(sw[(ci0 + j) * 9 + tap]);
        *(float4*)(o + ((size_t)(kc * 32 + g) * 64 + lane) * 8) = *(const float4*)tmp;
    }
}

// ---------------- im2col for conv1 (aligned loads, contiguous wave stores)
__global__ __launch_bounds__(256) void k_im2col2b(const float* __restrict__ x, ushort_t* __restrict__ A) {
    const int t = blockIdx.x * 256 + threadIdx.x;         // 2048 blocks
    const int dy = t & 1;
    const int px = (t >> 1) & 127;
    const int py = (t >> 8) & 127;
    const int b  = t >> 15;
    const int oy = 2 * py + dy;
    const int iy0 = 2 * oy - 1;
    const float* xb = x + (size_t)b * 3 * 512 * 512;
    const int lane = threadIdx.x & 63;

    ushort_t r0[32], r1[32];
#pragma unroll
    for (int k = 0; k < 32; ++k) { r0[k] = 0; r1[k] = 0; }

#pragma unroll
    for (int c = 0; c < 3; ++c) {
#pragma unroll
        for (int ky = 0; ky < 3; ++ky) {
            const int iy = iy0 + ky;
            const float* rp = xb + ((size_t)c * 512 + iy) * 512;
            float4 q = {0.f, 0.f, 0.f, 0.f};
            if (iy >= 0) q = *(const float4*)(rp + 4 * px);   // 16B-aligned dwordx4
            float vm1 = __shfl_up(q.w, 2, 64);                // col 4px-1: lane-2 = (px-1, same dy)
            if (lane < 2) vm1 = (px > 0 && iy >= 0) ? rp[4 * px - 1] : 0.f;
            const int kb = ky * 9 + c;
            r0[kb]     = f2b(vm1);  r1[kb]     = f2b(q.y);
            r0[kb + 3] = f2b(q.x);  r1[kb + 3] = f2b(q.z);
            r0[kb + 6] = f2b(q.y);  r1[kb + 6] = f2b(q.w);
        }
    }
    const size_t m0 = (((size_t)(b * 128 + py) * 128 + px) << 2) + (dy << 1);
    float4* dst = (float4*)(A + m0 * 32);
    const float4* s0 = (const float4*)r0;
    const float4* s1 = (const float4*)r1;
    dst[0] = s0[0]; dst[1] = s0[1]; dst[2] = s0[2]; dst[3] = s0[3];
    dst[4] = s1[0]; dst[5] = s1[1]; dst[6] = s1[2]; dst[7] = s1[3];
}

// ---------------- conv1 GEMM: A [1M][32] x w1 [32][64] -> pool+bias+relu -> y1 bf16 NHWC
// y1 channel storage order: s = 4*l15 + nf  (original co = nf*16 + l15) -> 8B store per lane
__global__ __launch_bounds__(256) void k_conv1g(const ushort_t* __restrict__ A,
                                                const ushort_t* __restrict__ wpk1,
                                                const float* __restrict__ b1,
                                                ushort_t* __restrict__ y1) {
    const int tid = threadIdx.x;
    const int wid = tid >> 6, lane = tid & 63;
    const int l15 = lane & 15, kg = lane >> 4;

    bf16x8 bF[4];
    float bias[4];
#pragma unroll
    for (int nf = 0; nf < 4; ++nf) {
        bF[nf] = *reinterpret_cast<const bf16x8*>(wpk1 + (size_t)(nf * 64 + lane) * 8);
        bias[nf] = b1[nf * 16 + l15];
    }
    const f32x4 z4 = {0.f, 0.f, 0.f, 0.f};
    const int f0 = blockIdx.x * 64 + wid * 16;

#pragma unroll 2
    for (int it = 0; it < 16; ++it) {
        const int f = f0 + it;
        const bf16x8 aF = *reinterpret_cast<const bf16x8*>(A + ((size_t)f * 16 + l15) * 32 + kg * 8);
        f32x4 acc[4];
#pragma unroll
        for (int nf = 0; nf < 4; ++nf)
            acc[nf] = __builtin_amdgcn_mfma_f32_16x16x32_bf16(aF, bF[nf], z4, 0, 0, 0);
        const int g = f * 4 + kg;
        const int px = g & 127, py = (g >> 7) & 127, b = g >> 14;
        union { ushort_t u[4]; uint2 v; } pk;
#pragma unroll
        for (int nf = 0; nf < 4; ++nf) {
            float v = fmaxf(fmaxf(acc[nf][0], acc[nf][1]), fmaxf(acc[nf][2], acc[nf][3]));
            pk.u[nf] = f2b(fmaxf(v + bias[nf], 0.f));
        }
        *(uint2*)(y1 + ((size_t)(b * 128 + py) * 128 + px) * 64 + 4 * l15) = pk.v;
    }
}

// ---------------- fallback conv1 (scalar path; writes permuted channel order)
__global__ __launch_bounds__(256, 4) void k_conv1(const float* __restrict__ x,
                                                  const float* __restrict__ w1,
                                                  const float* __restrict__ b1,
                                                  ushort_t* __restrict__ y1) {
    const int b = blockIdx.y;
    const int tileY = blockIdx.x >> 4, tileX = blockIdx.x & 15;
    const int tid = threadIdx.x;
    const int cog = __builtin_amdgcn_readfirstlane(tid >> 6);
    const int pix = tid & 63;
    const int ty = pix >> 3, tx = pix & 7;

    __shared__ float sIn[3 * 33 * 36];
    const int iyb = 32 * tileY - 1, ixb = 32 * tileX - 1;
    const float* xb = x + (size_t)b * 3 * 512 * 512;
    for (int idx = tid; idx < 3564; idx += 256) {
        const int col = idx % 36;
        const int rc = idx / 36;
        const int r = rc % 33, c = rc / 33;
        const int iy = iyb + r, ix = ixb + col;
        float v = 0.f;
        if (col < 33 && iy >= 0 && iy < 512 && ix >= 0 && ix < 512)
            v = xb[((size_t)c * 512 + iy) * 512 + ix];
        sIn[rc * 36 + col] = v;
    }
    __syncthreads();

    const float* wS = w1 + cog * (16 * 27);
    float acc[4][16];
#pragma unroll
    for (int p = 0; p < 4; ++p)
#pragma unroll
        for (int co = 0; co < 16; ++co) acc[p][co] = 0.f;

#pragma unroll
    for (int c = 0; c < 3; ++c) {
        float in[5][5];
#pragma unroll
        for (int r = 0; r < 5; ++r) {
            const float* rp = &sIn[(c * 33 + 4 * ty + r) * 36 + 4 * tx];
            const float4 qv = *(const float4*)rp;
            in[r][0] = qv.x; in[r][1] = qv.y; in[r][2] = qv.z; in[r][3] = qv.w;
            in[r][4] = rp[4];
        }
#pragma unroll
        for (int ky = 0; ky < 3; ++ky)
#pragma unroll
        for (int kx = 0; kx < 3; ++kx) {
            const int j = c * 9 + ky * 3 + kx;
#pragma unroll
            for (int co = 0; co < 16; ++co) {
                const float w = wS[co * 27 + j];
                acc[0][co] += in[ky][kx] * w;
                acc[1][co] += in[ky][kx + 2] * w;
                acc[2][co] += in[ky + 2][kx] * w;
                acc[3][co] += in[ky + 2][kx + 2] * w;
            }
        }
    }

    const int py = 8 * tileY + ty, px = 8 * tileX + tx;
    ushort_t* op = y1 + ((size_t)(b * 128 + py) * 128 + px) * 64;
#pragma unroll
    for (int co = 0; co < 16; ++co) {
        float m = fmaxf(fmaxf(acc[0][co], acc[1][co]), fmaxf(acc[2][co], acc[3][co]));
        const int c = cog * 16 + co;
        op[4 * (c & 15) + (c >> 4)] = f2b(fmaxf(m + b1[c], 0.f));
    }
}

// ---------------- conv2 MFMA (M-split, 1-wave blocks): y1 bf16 (permuted ch) -> y2 bf16 NHWC
// grid (rp=32, xh*4+wg=8, b=16) = 4096 one-wave blocks; per-wave work identical to R10 wid-wave
__global__ __launch_bounds__(64) void k_conv2m(const ushort_t* __restrict__ y1,
                                               const ushort_t* __restrict__ wpk2,
                                               const float* __restrict__ b2,
                                               ushort_t* __restrict__ y2) {
    const int b = blockIdx.z;
    const int xh = blockIdx.y >> 2;          // ox half: ox-blocks {2xh, 2xh+1}
    const int wg = blockIdx.y & 3;           // co quarter (was wid)
    const int rp = blockIdx.x;               // pooled row 0..31
    const int oy0 = rp * 2;
    const int lane = threadIdx.x;
    const int l15 = lane & 15, kl8 = (lane >> 4) << 3;

    const ushort_t* xb = y1 + (size_t)b * 128 * 128 * 64;
    const f32x4 z4 = {0.f, 0.f, 0.f, 0.f};
    f32x4 acc[2][2][2];                      // [oyi][m2][nf]
#pragma unroll
    for (int i = 0; i < 2; ++i)
#pragma unroll
        for (int j = 0; j < 2; ++j) { acc[i][j][0] = z4; acc[i][j][1] = z4; }

    const int cb0 = 2 * l15 - 1 + xh * 64;   // input col base for this half

#pragma unroll 1
    for (int tap = 0; tap < 9; ++tap) {
        const int ky = tap >= 6 ? 2 : (tap >= 3 ? 1 : 0), kx = tap - ky * 3;
        const int iyA = 2 * oy0 - 1 + ky;
#pragma unroll
        for (int h = 0; h < 2; ++h) {
            const int ci0 = h * 32;
            const int kc = tap * 2 + h;
            bf16x8 aF[2][2];
#pragma unroll
            for (int oyi = 0; oyi < 2; ++oyi)
#pragma unroll
            for (int m2 = 0; m2 < 2; ++m2) {
                const int iy = iyA + 2 * oyi;
                const int c = cb0 + m2 * 32 + kx;
                const bool ok = (iy >= 0) && (c >= 0);
                bf16x8 r = {0, 0, 0, 0, 0, 0, 0, 0};
                if (ok) r = *reinterpret_cast<const bf16x8*>(xb + ((size_t)iy * 128 + c) * 64 + ci0 + kl8);
                aF[oyi][m2] = r;
            }
            bf16x8 bF[2];
#pragma unroll
            for (int nf = 0; nf < 2; ++nf)
                bF[nf] = *reinterpret_cast<const bf16x8*>(wpk2 + ((size_t)(kc * 8 + wg * 2 + nf) * 64 + lane) * 8);
#pragma unroll
            for (int oyi = 0; oyi < 2; ++oyi)
#pragma unroll
            for (int m2 = 0; m2 < 2; ++m2)
#pragma unroll
            for (int nf = 0; nf < 2; ++nf)
                acc[oyi][m2][nf] = __builtin_amdgcn_mfma_f32_16x16x32_bf16(aF[oyi][m2], bF[nf], acc[oyi][m2][nf], 0, 0, 0);
        }
    }
    const int kg = lane >> 4;
#pragma unroll
    for (int nf = 0; nf < 2; ++nf) {
        const int co = wg * 32 + nf * 16 + l15;
        const float bias = b2[co];
#pragma unroll
        for (int m2 = 0; m2 < 2; ++m2)
#pragma unroll
            for (int p = 0; p < 2; ++p) {
                float v = fmaxf(fmaxf(acc[0][m2][nf][2 * p], acc[0][m2][nf][2 * p + 1]),
                                fmaxf(acc[1][m2][nf][2 * p], acc[1][m2][nf][2 * p + 1]));
                const int px = (xh * 2 + m2) * 8 + kg * 2 + p;
                y2[((size_t)(b * 32 + rp) * 32 + px) * 128 + co] = f2b(fmaxf(v + bias, 0.f));
            }
    }
}

// ---------------- conv3 MFMA: y2 bf16 NHWC -> y3 bf16 NHWC (16,8,8,256)
__global__ __launch_bounds__(256) void k_conv3m(const ushort_t* __restrict__ y2,
                                                const ushort_t* __restrict__ wpk3,
                                                const float* __restrict__ b3,
                                                ushort_t* __restrict__ y3) {
    const int gy = blockIdx.x, gn = blockIdx.y, b = blockIdx.z;
    const int oy0 = gy * 4;
    const int tid = threadIdx.x;
    const int wid = tid >> 6, lane = tid & 63;
    const int l15 = lane & 15, kl8 = (lane >> 4) << 3;
    const int g16 = gn * 4 + wid;
    const int co = g16 * 16 + l15;

    const ushort_t* xb = y2 + (size_t)b * 32 * 32 * 128;
    const f32x4 z4 = {0.f, 0.f, 0.f, 0.f};
    f32x4 acc[4] = {z4, z4, z4, z4};

#pragma unroll 1
    for (int tap = 0; tap < 9; ++tap) {
        const int ky = tap >= 6 ? 2 : (tap >= 3 ? 1 : 0), kx = tap - ky * 3;
        const int iyA = 2 * oy0 - 1 + ky;
        const int c = 2 * l15 - 1 + kx;
        const bool cok = (c >= 0);
#pragma unroll
        for (int h = 0; h < 4; ++h) {
            const int ci0 = h * 32;
            const int kc = tap * 4 + h;
            bf16x8 aF[4];
#pragma unroll
            for (int mf = 0; mf < 4; ++mf) {
                const int iy = iyA + 2 * mf;
                bf16x8 r = {0, 0, 0, 0, 0, 0, 0, 0};
                if (cok && iy >= 0) r = *reinterpret_cast<const bf16x8*>(xb + ((size_t)iy * 32 + c) * 128 + ci0 + kl8);
                aF[mf] = r;
            }
            const bf16x8 bF = *reinterpret_cast<const bf16x8*>(wpk3 + ((size_t)(kc * 16 + g16) * 64 + lane) * 8);
#pragma unroll
            for (int mf = 0; mf < 4; ++mf)
                acc[mf] = __builtin_amdgcn_mfma_f32_16x16x32_bf16(aF[mf], bF, acc[mf], 0, 0, 0);
        }
    }
    const int kg = lane >> 4;
    const float bias = b3[co];
#pragma unroll
    for (int mp = 0; mp < 2; ++mp) {
        const int py = gy * 2 + mp;
#pragma unroll
        for (int p = 0; p < 2; ++p) {
            float v = fmaxf(fmaxf(acc[2 * mp][2 * p], acc[2 * mp][2 * p + 1]),
                            fmaxf(acc[2 * mp + 1][2 * p], acc[2 * mp + 1][2 * p + 1]));
            const int px = kg * 2 + p;
            y3[((size_t)(b * 8 + py) * 8 + px) * 256 + co] = f2b(fmaxf(v + bias, 0.f));
        }
    }
}

// ---------------- im2col for conv4: y3 bf16 NHWC -> A4 [256][2304] bf16, k = tap*256+ci
__global__ __launch_bounds__(256) void k_im2col4(const ushort_t* __restrict__ y3, ushort_t* __restrict__ A4) {
    const int m = blockIdx.x;                             // 256 blocks
    const int b = m >> 4, pix = m & 15;
    const int oy = pix >> 2, ox = pix & 3;
    const ushort_t* xb = y3 + (size_t)b * 16384;
    for (int it = threadIdx.x; it < 288; it += 256) {
        const int tap = it >> 5, ci8 = it & 31;
        const int ky = tap / 3, kx = tap - 3 * (tap / 3);
        const int iy = 2 * oy - 1 + ky, ix = 2 * ox - 1 + kx;
        bf16x8 r = {0, 0, 0, 0, 0, 0, 0, 0};
        if (iy >= 0 && ix >= 0)
            r = *reinterpret_cast<const bf16x8*>(xb + ((iy * 8 + ix) << 8) + ci8 * 8);
        *reinterpret_cast<bf16x8*>(A4 + (size_t)m * 2304 + tap * 256 + ci8 * 8) = r;
    }
}

// ---------------- conv4 GEMM + relu + mean (K-split across 4 waves, 512 blocks)
__global__ __launch_bounds__(256) void k_conv4g(const ushort_t* __restrict__ A4,
                                                const ushort_t* __restrict__ wpk4m,
                                                const float* __restrict__ b4,
                                                float* __restrict__ feats) {
    const int g16 = blockIdx.x, b = blockIdx.y;
    const int tid = threadIdx.x, wid = tid >> 6, lane = tid & 63;
    const int l15 = lane & 15, kg = lane >> 4, kl8 = kg << 3;
    const f32x4 z4 = {0.f, 0.f, 0.f, 0.f};
    f32x4 acc = z4;
    const ushort_t* arow = A4 + (size_t)(b * 16 + l15) * 2304 + kl8;
    const int kc0 = wid * 18;

#pragma unroll 3
    for (int i = 0; i < 18; ++i) {
        const int kc = kc0 + i;
        const bf16x8 aF = *reinterpret_cast<const bf16x8*>(arow + kc * 32);
        const bf16x8 bF = *reinterpret_cast<const bf16x8*>(wpk4m + ((size_t)(kc * 32 + g16) * 64 + lane) * 8);
        acc = __builtin_amdgcn_mfma_f32_16x16x32_bf16(aF, bF, acc, 0, 0, 0);
    }

    __shared__ f32x4 red[4][64];
    red[wid][lane] = acc;
    __syncthreads();
    if (wid == 0) {
        f32x4 t = red[0][lane];
        t = t + red[1][lane];
        t = t + red[2][lane];
        t = t + red[3][lane];
        const int co = g16 * 16 + l15;
        const float bias = b4[co];
        float s = fmaxf(t[0] + bias, 0.f) + fmaxf(t[1] + bias, 0.f)
                + fmaxf(t[2] + bias, 0.f) + fmaxf(t[3] + bias, 0.f);
        s += __shfl_xor(s, 16, 64);
        s += __shfl_xor(s, 32, 64);
        if (kg == 0) feats[b * 512 + co] = s * 0.0625f;
    }
}

// ---------------- head: feats -> logits -> softmax -> VLAD residual v (16, 32768)
__global__ __launch_bounds__(256) void k_head(const float* __restrict__ feats,
                                              const float* __restrict__ wv,
                                              const float* __restrict__ bv,
                                              const float* __restrict__ centroids,
                                              float* __restrict__ v) {
    const int b = blockIdx.x;
    __shared__ float sf[512];
    __shared__ float sl[64];
    __shared__ float sa[64];
    for (int i = threadIdx.x; i < 512; i += 256) sf[i] = feats[b * 512 + i];
    __syncthreads();
    if (threadIdx.x < 64) {
        const int k = threadIdx.x;
        float s = bv[k];
        for (int c = 0; c < 512; ++c) s += sf[c] * wv[(size_t)k * 512 + c];
        sl[k] = s;
    }
    __syncthreads();
    if (threadIdx.x < 64) {
        const int k = threadIdx.x;
        float m = -1e30f;
        for (int i = 0; i < 64; ++i) m = fmaxf(m, sl[i]);
        float sum = 0.f;
        for (int i = 0; i < 64; ++i) sum += __expf(sl[i] - m);
        sa[k] = __expf(sl[k] - m) / sum;
    }
    __syncthreads();
    for (int i4 = threadIdx.x * 4; i4 < 32768; i4 += 1024) {
        const int k = i4 >> 9;
        const float a_ = sa[k];
        const float4 c4 = *(const float4*)(centroids + i4);
        const float4 f4 = *(const float4*)(&sf[i4 & 511]);
        float4 o;
        o.x = a_ * (f4.x - c4.x);
        o.y = a_ * (f4.y - c4.y);
        o.z = a_ * (f4.z - c4.z);
        o.w = a_ * (f4.w - c4.w);
        *(float4*)(v + (size_t)b * 32768 + i4) = o;
    }
}

// ---------------- fc1a: K-split partial GEMV; part[ks][b][d]
__global__ __launch_bounds__(256) void k_fc1a(const float* __restrict__ v,
                                              const float* __restrict__ fw1,
                                              float* __restrict__ part) {
    const int d = blockIdx.x, ks = blockIdx.y;
    const int base = ks * 4096;
    float acc[16];
#pragma unroll
    for (int i = 0; i < 16; ++i) acc[i] = 0.f;
    const float* wrow = fw1 + (size_t)d * 32768 + base;
    const float* vb = v + base;
#pragma unroll
    for (int it = 0; it < 4; ++it) {
        const int j4 = it * 1024 + threadIdx.x * 4;
        const float4 w = *(const float4*)(wrow + j4);
#pragma unroll
        for (int b = 0; b < 16; ++b) {
            const float4 vv = *(const float4*)(vb + (size_t)b * 32768 + j4);
            acc[b] += w.x * vv.x + w.y * vv.y + w.z * vv.z + w.w * vv.w;
        }
    }
#pragma unroll
    for (int b = 0; b < 16; ++b) {
        float s = acc[b];
        for (int off = 32; off >= 1; off >>= 1) s += __shfl_down(s, off, 64);
        acc[b] = s;
    }
    __shared__ float red[4][16];
    const int wid = threadIdx.x >> 6, lane = threadIdx.x & 63;
    if (lane == 0) {
#pragma unroll
        for (int b = 0; b < 16; ++b) red[wid][b] = acc[b];
    }
    __syncthreads();
    if (threadIdx.x < 16) {
        const int b = threadIdx.x;
        part[((size_t)ks * 16 + b) * 256 + d] = red[0][b] + red[1][b] + red[2][b] + red[3][b];
    }
}

// ---------------- fc1r: reduce 8 partials + bias + relu -> d1 (16,256)
__global__ __launch_bounds__(256) void k_fc1r(const float* __restrict__ part,
                                              const float* __restrict__ fb1,
                                              float* __restrict__ d1) {
    const int i = blockIdx.x * 256 + threadIdx.x;         // 16 blocks -> 4096
    const int d = i & 255;
    float s = fb1[d];
#pragma unroll
    for (int ks = 0; ks < 8; ++ks) s += part[(size_t)ks * 4096 + i];
    d1[i] = fmaxf(s, 0.f);
}

// ---------------- fc2 + L2 norm
__global__ __launch_bounds__(256) void k_fc2(const float* __restrict__ d1,
                                             const float* __restrict__ fw2,
                                             const float* __restrict__ fb2,
                                             float* __restrict__ out) {
    const int b = blockIdx.x;
    const int dd = threadIdx.x;
    __shared__ float sd[256];
    __shared__ float sq[256];
    sd[dd] = d1[b * 256 + dd];
    __syncthreads();
    float s = fb2[dd];
    for (int j = 0; j < 256; ++j) s += sd[j] * fw2[(size_t)dd * 256 + j];
    sq[dd] = s * s;
    __syncthreads();
    for (int off = 128; off >= 1; off >>= 1) {
        if (dd < off) sq[dd] += sq[dd + off];
        __syncthreads();
    }
    const float inv = rsqrtf(sq[0]);
    out[b * 256 + dd] = s * inv;
}

extern "C" void kernel_launch(void* const* d_in, const int* in_sizes, int n_in,
                              void* d_out, int out_size, void* d_ws, size_t ws_size,
                              hipStream_t stream) {
    const float* x    = (const float*)d_in[0];
    const float* w1   = (const float*)d_in[1];
    const float* b1   = (const float*)d_in[2];
    const float* w2   = (const float*)d_in[3];
    const float* b2   = (const float*)d_in[4];
    const float* w3   = (const float*)d_in[5];
    const float* b3   = (const float*)d_in[6];
    const float* w4   = (const float*)d_in[7];
    const float* b4   = (const float*)d_in[8];
    const float* wv   = (const float*)d_in[9];
    const float* bv   = (const float*)d_in[10];
    const float* cen  = (const float*)d_in[11];
    const float* fw1  = (const float*)d_in[12];
    const float* fb1  = (const float*)d_in[13];
    const float* fw2  = (const float*)d_in[14];
    const float* fb2  = (const float*)d_in[15];
    float* out = (float*)d_out;

    char* p = (char*)d_ws;
    ushort_t* y1    = (ushort_t*)p; p += 33554432;  // 16*128*128*64 bf16
    ushort_t* wpk2  = (ushort_t*)p; p += 147456;    // 73728 bf16
    ushort_t* wpk3  = (ushort_t*)p; p += 589824;    // 294912 bf16
    ushort_t* wpk4m = (ushort_t*)p; p += 2359296;   // 1179648 bf16
    ushort_t* wpk1  = (ushort_t*)p; p += 4096;      // 2048 bf16
    // A region (64 MB) — dead after k_conv1g; later buffers alias into it
    char* aRegion = p;
    ushort_t* A    = (ushort_t*)aRegion;            // 1048576*32 bf16 = 64 MB
    char* q = aRegion;
    ushort_t* y2   = (ushort_t*)q; q += 4194304;    // 16*32*32*128 bf16
    ushort_t* y3   = (ushort_t*)q; q += 524288;     // 16*8*8*256 bf16
    float*    feats= (float*)q;    q += 32768;      // 16*512
    float*    vbuf = (float*)q;    q += 2097152;    // 16*32768
    float*    d1   = (float*)q;    q += 16384;      // 16*256
    ushort_t* A4   = (ushort_t*)q; q += 1179648;    // 256*2304 bf16
    float*    part = (float*)q;    q += 131072;     // 8*16*256 f32

    const size_t need = (size_t)(aRegion - (char*)d_ws) + 67108864;
    const bool useMfmaConv1 = (ws_size >= need);

    k_pack2<<<36, 256, 0, stream>>>(w2, wpk2);
    k_pack3<<<144, 256, 0, stream>>>(w3, wpk3);
    k_pack4m<<<512, 256, 0, stream>>>(w4, wpk4m);
    if (useMfmaConv1) {
        k_pack1<<<1, 256, 0, stream>>>(w1, wpk1);
        k_im2col2b<<<2048, 256, 0, stream>>>(x, A);
        k_conv1g<<<1024, 256, 0, stream>>>(A, wpk1, b1, y1);
    } else {
        k_conv1<<<dim3(256, 16), 256, 0, stream>>>(x, w1, b1, y1);
    }
    k_conv2m<<<dim3(32, 8, 16), 64, 0, stream>>>(y1, wpk2, b2, y2);
    k_conv3m<<<dim3(4, 4, 16), 256, 0, stream>>>(y2, wpk3, b3, y3);
    k_im2col4<<<256, 256, 0, stream>>>(y3, A4);
    k_conv4g<<<dim3(32, 16), 256, 0, stream>>>(A4, wpk4m, b4, feats);
    k_head<<<16, 256, 0, stream>>>(feats, wv, bv, cen, vbuf);
    k_fc1a<<<dim3(256, 8), 256, 0, stream>>>(vbuf, fw1, part);
    k_fc1r<<<16, 256, 0, stream>>>(part, fb1, d1);
    k_fc2<<<16, 256, 0, stream>>>(d1, fw2, fb2, out);
}

// Round 13
// 175.244 us; speedup vs baseline: 1.2665x; 1.0996x over previous
//
#include <hip/hip_runtime.h>
#include <hip/hip_bf16.h>

typedef unsigned short ushort_t;
typedef short bf16x8 __attribute__((ext_vector_type(8)));
typedef float f32x4 __attribute__((ext_vector_type(4)));

__device__ __forceinline__ ushort_t f2b(float f) {
    __hip_bfloat16 h = __float2bfloat16(f);
    return *reinterpret_cast<ushort_t*>(&h);
}
__device__ __forceinline__ float b2f(short v) {
    union { unsigned int u; float f; } cv;
    cv.u = ((unsigned int)(ushort_t)v) << 16;
    return cv.f;
}

// ---------------- weight repack: w1 (64,3,3,3) -> B-frag order [nf(4)][lane(64)][8], K order k = tap*3+c
__global__ __launch_bounds__(256) void k_pack1(const float* __restrict__ w1, ushort_t* __restrict__ o) {
    const int slot = threadIdx.x;                         // 256 slots
    const int lane = slot & 63, nf = slot >> 6;
    const int co = nf * 16 + (lane & 15);
    const int kg = lane >> 4;
#pragma unroll
    for (int j = 0; j < 8; ++j) {
        const int k = kg * 8 + j;
        float v = 0.f;
        if (k < 27) {
            const int t = k / 3, c = k - 3 * t;
            v = w1[(co * 3 + c) * 9 + t];
        }
        o[slot * 8 + j] = f2b(v);
    }
}

// ---------------- weight repack: w2 (128,64,3,3) -> B-fragment order, bf16
// K order = tap*64 + s, where storage channel s maps to original ci = 16*(s&3) + (s>>2)
__global__ __launch_bounds__(256) void k_pack2(const float* __restrict__ w2, ushort_t* __restrict__ o) {
    const int slot = blockIdx.x * 256 + threadIdx.x;      // 9216 slots
    const int lane = slot & 63, g = (slot >> 6) & 7, kc = slot >> 9;
    const int k0 = kc * 32 + ((lane >> 4) << 3);
    const int tap = k0 >> 6, sb = k0 & 63;
    const int ky = tap >= 6 ? 2 : (tap >= 3 ? 1 : 0), kx = tap - ky * 3;
    const int co = g * 16 + (lane & 15);
#pragma unroll
    for (int j = 0; j < 8; ++j) {
        const int s = sb + j;
        const int ci = 16 * (s & 3) + (s >> 2);
        o[slot * 8 + j] = f2b(w2[((co * 64 + ci) * 3 + ky) * 3 + kx]);
    }
}

// w3 (256,128,3,3): [kc(36)][g16(16)][lane][8], K order = tap*128+ci
__global__ __launch_bounds__(256) void k_pack3(const float* __restrict__ w3, ushort_t* __restrict__ o) {
    const int slot = blockIdx.x * 256 + threadIdx.x;      // 36864 slots
    const int lane = slot & 63, g = (slot >> 6) & 15, kc = slot >> 10;
    const int k0 = kc * 32 + ((lane >> 4) << 3);
    const int tap = k0 >> 7, cib = k0 & 127;
    const int ky = tap >= 6 ? 2 : (tap >= 3 ? 1 : 0), kx = tap - ky * 3;
    const int co = g * 16 + (lane & 15);
#pragma unroll
    for (int j = 0; j < 8; ++j)
        o[slot * 8 + j] = f2b(w3[((co * 128 + cib + j) * 3 + ky) * 3 + kx]);
}

// w4 (512,256,3,3) -> MFMA B-frag bf16 [kc(72)][g16(32)][lane(64)][8], K order = tap*256+ci
__global__ __launch_bounds__(256) void k_pack4m(const float* __restrict__ w4, ushort_t* __restrict__ o) {
    const int co = blockIdx.x;                            // 512 blocks
    __shared__ float sw[2304];
    for (int i = threadIdx.x; i < 2304; i += 256) sw[i] = w4[(size_t)co * 2304 + i];
    __syncthreads();
    const int g = co >> 4, l15 = co & 15;
    for (int it = threadIdx.x; it < 288; it += 256) {
        const int kc = it >> 2, kg = it & 3;
        const int k0 = kc * 32 + kg * 8;
        const int tap = k0 >> 8, ci0 = k0 & 255;
        const int lane = kg * 16 + l15;
        ushort_t tmp[8];
#pragma unroll
        for (int j = 0; j < 8; ++j)
            tmp[j] = f2b(sw[(ci0 + j) * 9 + tap]);
        *(float4*)(o + ((size_t)(kc * 32 + g) * 64 + lane) * 8) = *(const float4*)tmp;
    }
}

// ---------------- im2col for conv1 (aligned loads, contiguous wave stores)
__global__ __launch_bounds__(256) void k_im2col2b(const float* __restrict__ x, ushort_t* __restrict__ A) {
    const int t = blockIdx.x * 256 + threadIdx.x;         // 2048 blocks
    const int dy = t & 1;
    const int px = (t >> 1) & 127;
    const int py = (t >> 8) & 127;
    const int b  = t >> 15;
    const int oy = 2 * py + dy;
    const int iy0 = 2 * oy - 1;
    const float* xb = x + (size_t)b * 3 * 512 * 512;
    const int lane = threadIdx.x & 63;

    ushort_t r0[32], r1[32];
#pragma unroll
    for (int k = 0; k < 32; ++k) { r0[k] = 0; r1[k] = 0; }

#pragma unroll
    for (int c = 0; c < 3; ++c) {
#pragma unroll
        for (int ky = 0; ky < 3; ++ky) {
            const int iy = iy0 + ky;
            const float* rp = xb + ((size_t)c * 512 + iy) * 512;
            float4 q = {0.f, 0.f, 0.f, 0.f};
            if (iy >= 0) q = *(const float4*)(rp + 4 * px);   // 16B-aligned dwordx4
            float vm1 = __shfl_up(q.w, 2, 64);                // col 4px-1: lane-2 = (px-1, same dy)
            if (lane < 2) vm1 = (px > 0 && iy >= 0) ? rp[4 * px - 1] : 0.f;
            const int kb = ky * 9 + c;
            r0[kb]     = f2b(vm1);  r1[kb]     = f2b(q.y);
            r0[kb + 3] = f2b(q.x);  r1[kb + 3] = f2b(q.z);
            r0[kb + 6] = f2b(q.y);  r1[kb + 6] = f2b(q.w);
        }
    }
    const size_t m0 = (((size_t)(b * 128 + py) * 128 + px) << 2) + (dy << 1);
    float4* dst = (float4*)(A + m0 * 32);
    const float4* s0 = (const float4*)r0;
    const float4* s1 = (const float4*)r1;
    dst[0] = s0[0]; dst[1] = s0[1]; dst[2] = s0[2]; dst[3] = s0[3];
    dst[4] = s1[0]; dst[5] = s1[1]; dst[6] = s1[2]; dst[7] = s1[3];
}

// ---------------- conv1 GEMM: A [1M][32] x w1 [32][64] -> pool+bias+relu -> y1 bf16 NHWC
// y1 channel storage order: s = 4*l15 + nf  (original co = nf*16 + l15) -> 8B store per lane
__global__ __launch_bounds__(256) void k_conv1g(const ushort_t* __restrict__ A,
                                                const ushort_t* __restrict__ wpk1,
                                                const float* __restrict__ b1,
                                                ushort_t* __restrict__ y1) {
    const int tid = threadIdx.x;
    const int wid = tid >> 6, lane = tid & 63;
    const int l15 = lane & 15, kg = lane >> 4;

    bf16x8 bF[4];
    float bias[4];
#pragma unroll
    for (int nf = 0; nf < 4; ++nf) {
        bF[nf] = *reinterpret_cast<const bf16x8*>(wpk1 + (size_t)(nf * 64 + lane) * 8);
        bias[nf] = b1[nf * 16 + l15];
    }
    const f32x4 z4 = {0.f, 0.f, 0.f, 0.f};
    const int f0 = blockIdx.x * 64 + wid * 16;

#pragma unroll 2
    for (int it = 0; it < 16; ++it) {
        const int f = f0 + it;
        const bf16x8 aF = *reinterpret_cast<const bf16x8*>(A + ((size_t)f * 16 + l15) * 32 + kg * 8);
        f32x4 acc[4];
#pragma unroll
        for (int nf = 0; nf < 4; ++nf)
            acc[nf] = __builtin_amdgcn_mfma_f32_16x16x32_bf16(aF, bF[nf], z4, 0, 0, 0);
        const int g = f * 4 + kg;
        const int px = g & 127, py = (g >> 7) & 127, b = g >> 14;
        union { ushort_t u[4]; uint2 v; } pk;
#pragma unroll
        for (int nf = 0; nf < 4; ++nf) {
            float v = fmaxf(fmaxf(acc[nf][0], acc[nf][1]), fmaxf(acc[nf][2], acc[nf][3]));
            pk.u[nf] = f2b(fmaxf(v + bias[nf], 0.f));
        }
        *(uint2*)(y1 + ((size_t)(b * 128 + py) * 128 + px) * 64 + 4 * l15) = pk.v;
    }
}

// ---------------- fallback conv1 (scalar path; writes permuted channel order)
__global__ __launch_bounds__(256, 4) void k_conv1(const float* __restrict__ x,
                                                  const float* __restrict__ w1,
                                                  const float* __restrict__ b1,
                                                  ushort_t* __restrict__ y1) {
    const int b = blockIdx.y;
    const int tileY = blockIdx.x >> 4, tileX = blockIdx.x & 15;
    const int tid = threadIdx.x;
    const int cog = __builtin_amdgcn_readfirstlane(tid >> 6);
    const int pix = tid & 63;
    const int ty = pix >> 3, tx = pix & 7;

    __shared__ float sIn[3 * 33 * 36];
    const int iyb = 32 * tileY - 1, ixb = 32 * tileX - 1;
    const float* xb = x + (size_t)b * 3 * 512 * 512;
    for (int idx = tid; idx < 3564; idx += 256) {
        const int col = idx % 36;
        const int rc = idx / 36;
        const int r = rc % 33, c = rc / 33;
        const int iy = iyb + r, ix = ixb + col;
        float v = 0.f;
        if (col < 33 && iy >= 0 && iy < 512 && ix >= 0 && ix < 512)
            v = xb[((size_t)c * 512 + iy) * 512 + ix];
        sIn[rc * 36 + col] = v;
    }
    __syncthreads();

    const float* wS = w1 + cog * (16 * 27);
    float acc[4][16];
#pragma unroll
    for (int p = 0; p < 4; ++p)
#pragma unroll
        for (int co = 0; co < 16; ++co) acc[p][co] = 0.f;

#pragma unroll
    for (int c = 0; c < 3; ++c) {
        float in[5][5];
#pragma unroll
        for (int r = 0; r < 5; ++r) {
            const float* rp = &sIn[(c * 33 + 4 * ty + r) * 36 + 4 * tx];
            const float4 qv = *(const float4*)rp;
            in[r][0] = qv.x; in[r][1] = qv.y; in[r][2] = qv.z; in[r][3] = qv.w;
            in[r][4] = rp[4];
        }
#pragma unroll
        for (int ky = 0; ky < 3; ++ky)
#pragma unroll
        for (int kx = 0; kx < 3; ++kx) {
            const int j = c * 9 + ky * 3 + kx;
#pragma unroll
            for (int co = 0; co < 16; ++co) {
                const float w = wS[co * 27 + j];
                acc[0][co] += in[ky][kx] * w;
                acc[1][co] += in[ky][kx + 2] * w;
                acc[2][co] += in[ky + 2][kx] * w;
                acc[3][co] += in[ky + 2][kx + 2] * w;
            }
        }
    }

    const int py = 8 * tileY + ty, px = 8 * tileX + tx;
    ushort_t* op = y1 + ((size_t)(b * 128 + py) * 128 + px) * 64;
#pragma unroll
    for (int co = 0; co < 16; ++co) {
        float m = fmaxf(fmaxf(acc[0][co], acc[1][co]), fmaxf(acc[2][co], acc[3][co]));
        const int c = cog * 16 + co;
        op[4 * (c & 15) + (c >> 4)] = f2b(fmaxf(m + b1[c], 0.f));
    }
}

// ---------------- conv2 LDS-staged MFMA: y1 bf16 (permuted ch) -> y2 bf16 NHWC (16,32,32,128)
// grid (rp=32, xh=2, b=16), 256 thr. Block stages 5 rows x 66 cols x 64ch into LDS (46KB,
// swizzled), then 18-iter tap loop reads LDS. Wave wid owns co quarter (2 N-frags).
__global__ __launch_bounds__(256) void k_conv2s(const ushort_t* __restrict__ y1,
                                                const ushort_t* __restrict__ wpk2,
                                                const float* __restrict__ b2,
                                                ushort_t* __restrict__ y2) {
    const int b = blockIdx.z;
    const int xh = blockIdx.y;               // ox half
    const int rp = blockIdx.x;               // pooled row 0..31
    const int tid = threadIdx.x;
    const int wid = tid >> 6, lane = tid & 63;
    const int l15 = lane & 15, kg = lane >> 4;

    __shared__ __align__(16) ushort_t sY[330 * 72];       // [pc=r*66+cc][ch pad 72], 46.4KB
    bf16x8* sYv = (bf16x8*)sY;                            // pc stride = 9 chunks

    const ushort_t* xb = y1 + (size_t)b * 128 * 128 * 64;
    const int iyb = 4 * rp - 1, ixb = 64 * xh - 1;
    // stage 330 pixels x 8 chunks of 16B; chunk slot swizzled by (pc>>1)&7
    for (int j = tid; j < 2640; j += 256) {
        const int q = j & 7;
        const int pc = j >> 3;
        const int cc = pc % 66, r = pc / 66;
        const int iy = iyb + r, ix = ixb + cc;
        bf16x8 v = {0, 0, 0, 0, 0, 0, 0, 0};
        if (iy >= 0 && ix >= 0 && ix < 128)
            v = *reinterpret_cast<const bf16x8*>(xb + ((size_t)iy * 128 + ix) * 64 + q * 8);
        sYv[pc * 9 + (q ^ ((pc >> 1) & 7))] = v;
    }
    __syncthreads();

    const f32x4 z4 = {0.f, 0.f, 0.f, 0.f};
    f32x4 acc[2][2][2];                      // [oyi][m2][nf]
#pragma unroll
    for (int i = 0; i < 2; ++i)
#pragma unroll
        for (int j = 0; j < 2; ++j) { acc[i][j][0] = z4; acc[i][j][1] = z4; }

#pragma unroll 1
    for (int tap = 0; tap < 9; ++tap) {
        const int ky = tap >= 6 ? 2 : (tap >= 3 ? 1 : 0), kx = tap - ky * 3;
#pragma unroll
        for (int h = 0; h < 2; ++h) {
            const int kc = tap * 2 + h;
            const int c8 = h * 4 + kg;       // channel chunk 0..7
            bf16x8 aF[2][2];
#pragma unroll
            for (int oyi = 0; oyi < 2; ++oyi)
#pragma unroll
            for (int m2 = 0; m2 < 2; ++m2) {
                const int r = 2 * oyi + ky;                  // 0..4
                const int cc = 2 * l15 + m2 * 32 + kx;       // 0..64
                const int pc = r * 66 + cc;
                aF[oyi][m2] = sYv[pc * 9 + (c8 ^ ((pc >> 1) & 7))];
            }
            bf16x8 bF[2];
#pragma unroll
            for (int nf = 0; nf < 2; ++nf)
                bF[nf] = *reinterpret_cast<const bf16x8*>(wpk2 + ((size_t)(kc * 8 + wid * 2 + nf) * 64 + lane) * 8);
#pragma unroll
            for (int oyi = 0; oyi < 2; ++oyi)
#pragma unroll
            for (int m2 = 0; m2 < 2; ++m2)
#pragma unroll
            for (int nf = 0; nf < 2; ++nf)
                acc[oyi][m2][nf] = __builtin_amdgcn_mfma_f32_16x16x32_bf16(aF[oyi][m2], bF[nf], acc[oyi][m2][nf], 0, 0, 0);
        }
    }
    const int kgx = lane >> 4;
#pragma unroll
    for (int nf = 0; nf < 2; ++nf) {
        const int co = wid * 32 + nf * 16 + l15;
        const float bias = b2[co];
#pragma unroll
        for (int m2 = 0; m2 < 2; ++m2)
#pragma unroll
            for (int p = 0; p < 2; ++p) {
                float v = fmaxf(fmaxf(acc[0][m2][nf][2 * p], acc[0][m2][nf][2 * p + 1]),
                                fmaxf(acc[1][m2][nf][2 * p], acc[1][m2][nf][2 * p + 1]));
                const int px = (xh * 2 + m2) * 8 + kgx * 2 + p;
                y2[((size_t)(b * 32 + rp) * 32 + px) * 128 + co] = f2b(fmaxf(v + bias, 0.f));
            }
    }
}

// ---------------- conv3 MFMA: y2 bf16 NHWC -> y3 bf16 NHWC (16,8,8,256)
__global__ __launch_bounds__(256) void k_conv3m(const ushort_t* __restrict__ y2,
                                                const ushort_t* __restrict__ wpk3,
                                                const float* __restrict__ b3,
                                                ushort_t* __restrict__ y3) {
    const int gy = blockIdx.x, gn = blockIdx.y, b = blockIdx.z;
    const int oy0 = gy * 4;
    const int tid = threadIdx.x;
    const int wid = tid >> 6, lane = tid & 63;
    const int l15 = lane & 15, kl8 = (lane >> 4) << 3;
    const int g16 = gn * 4 + wid;
    const int co = g16 * 16 + l15;

    const ushort_t* xb = y2 + (size_t)b * 32 * 32 * 128;
    const f32x4 z4 = {0.f, 0.f, 0.f, 0.f};
    f32x4 acc[4] = {z4, z4, z4, z4};

#pragma unroll 1
    for (int tap = 0; tap < 9; ++tap) {
        const int ky = tap >= 6 ? 2 : (tap >= 3 ? 1 : 0), kx = tap - ky * 3;
        const int iyA = 2 * oy0 - 1 + ky;
        const int c = 2 * l15 - 1 + kx;
        const bool cok = (c >= 0);
#pragma unroll
        for (int h = 0; h < 4; ++h) {
            const int ci0 = h * 32;
            const int kc = tap * 4 + h;
            bf16x8 aF[4];
#pragma unroll
            for (int mf = 0; mf < 4; ++mf) {
                const int iy = iyA + 2 * mf;
                bf16x8 r = {0, 0, 0, 0, 0, 0, 0, 0};
                if (cok && iy >= 0) r = *reinterpret_cast<const bf16x8*>(xb + ((size_t)iy * 32 + c) * 128 + ci0 + kl8);
                aF[mf] = r;
            }
            const bf16x8 bF = *reinterpret_cast<const bf16x8*>(wpk3 + ((size_t)(kc * 16 + g16) * 64 + lane) * 8);
#pragma unroll
            for (int mf = 0; mf < 4; ++mf)
                acc[mf] = __builtin_amdgcn_mfma_f32_16x16x32_bf16(aF[mf], bF, acc[mf], 0, 0, 0);
        }
    }
    const int kg = lane >> 4;
    const float bias = b3[co];
#pragma unroll
    for (int mp = 0; mp < 2; ++mp) {
        const int py = gy * 2 + mp;
#pragma unroll
        for (int p = 0; p < 2; ++p) {
            float v = fmaxf(fmaxf(acc[2 * mp][2 * p], acc[2 * mp][2 * p + 1]),
                            fmaxf(acc[2 * mp + 1][2 * p], acc[2 * mp + 1][2 * p + 1]));
            const int px = kg * 2 + p;
            y3[((size_t)(b * 8 + py) * 8 + px) * 256 + co] = f2b(fmaxf(v + bias, 0.f));
        }
    }
}

// ---------------- im2col for conv4: y3 bf16 NHWC -> A4 [256][2304] bf16, k = tap*256+ci
__global__ __launch_bounds__(256) void k_im2col4(const ushort_t* __restrict__ y3, ushort_t* __restrict__ A4) {
    const int m = blockIdx.x;                             // 256 blocks
    const int b = m >> 4, pix = m & 15;
    const int oy = pix >> 2, ox = pix & 3;
    const ushort_t* xb = y3 + (size_t)b * 16384;
    for (int it = threadIdx.x; it < 288; it += 256) {
        const int tap = it >> 5, ci8 = it & 31;
        const int ky = tap / 3, kx = tap - 3 * (tap / 3);
        const int iy = 2 * oy - 1 + ky, ix = 2 * ox - 1 + kx;
        bf16x8 r = {0, 0, 0, 0, 0, 0, 0, 0};
        if (iy >= 0 && ix >= 0)
            r = *reinterpret_cast<const bf16x8*>(xb + ((iy * 8 + ix) << 8) + ci8 * 8);
        *reinterpret_cast<bf16x8*>(A4 + (size_t)m * 2304 + tap * 256 + ci8 * 8) = r;
    }
}

// ---------------- conv4 GEMM + relu + mean (K-split across 4 waves, 512 blocks)
__global__ __launch_bounds__(256) void k_conv4g(const ushort_t* __restrict__ A4,
                                                const ushort_t* __restrict__ wpk4m,
                                                const float* __restrict__ b4,
                                                float* __restrict__ feats) {
    const int g16 = blockIdx.x, b = blockIdx.y;
    const int tid = threadIdx.x, wid = tid >> 6, lane = tid & 63;
    const int l15 = lane & 15, kg = lane >> 4, kl8 = kg << 3;
    const f32x4 z4 = {0.f, 0.f, 0.f, 0.f};
    f32x4 acc = z4;
    const ushort_t* arow = A4 + (size_t)(b * 16 + l15) * 2304 + kl8;
    const int kc0 = wid * 18;

#pragma unroll 3
    for (int i = 0; i < 18; ++i) {
        const int kc = kc0 + i;
        const bf16x8 aF = *reinterpret_cast<const bf16x8*>(arow + kc * 32);
        const bf16x8 bF = *reinterpret_cast<const bf16x8*>(wpk4m + ((size_t)(kc * 32 + g16) * 64 + lane) * 8);
        acc = __builtin_amdgcn_mfma_f32_16x16x32_bf16(aF, bF, acc, 0, 0, 0);
    }

    __shared__ f32x4 red[4][64];
    red[wid][lane] = acc;
    __syncthreads();
    if (wid == 0) {
        f32x4 t = red[0][lane];
        t = t + red[1][lane];
        t = t + red[2][lane];
        t = t + red[3][lane];
        const int co = g16 * 16 + l15;
        const float bias = b4[co];
        float s = fmaxf(t[0] + bias, 0.f) + fmaxf(t[1] + bias, 0.f)
                + fmaxf(t[2] + bias, 0.f) + fmaxf(t[3] + bias, 0.f);
        s += __shfl_xor(s, 16, 64);
        s += __shfl_xor(s, 32, 64);
        if (kg == 0) feats[b * 512 + co] = s * 0.0625f;
    }
}

// ---------------- head: feats -> logits -> softmax -> VLAD residual v (16, 32768)
__global__ __launch_bounds__(256) void k_head(const float* __restrict__ feats,
                                              const float* __restrict__ wv,
                                              const float* __restrict__ bv,
                                              const float* __restrict__ centroids,
                                              float* __restrict__ v) {
    const int b = blockIdx.x;
    __shared__ float sf[512];
    __shared__ float sl[64];
    __shared__ float sa[64];
    for (int i = threadIdx.x; i < 512; i += 256) sf[i] = feats[b * 512 + i];
    __syncthreads();
    if (threadIdx.x < 64) {
        const int k = threadIdx.x;
        float s = bv[k];
        for (int c = 0; c < 512; ++c) s += sf[c] * wv[(size_t)k * 512 + c];
        sl[k] = s;
    }
    __syncthreads();
    if (threadIdx.x < 64) {
        const int k = threadIdx.x;
        float m = -1e30f;
        for (int i = 0; i < 64; ++i) m = fmaxf(m, sl[i]);
        float sum = 0.f;
        for (int i = 0; i < 64; ++i) sum += __expf(sl[i] - m);
        sa[k] = __expf(sl[k] - m) / sum;
    }
    __syncthreads();
    for (int i4 = threadIdx.x * 4; i4 < 32768; i4 += 1024) {
        const int k = i4 >> 9;
        const float a_ = sa[k];
        const float4 c4 = *(const float4*)(centroids + i4);
        const float4 f4 = *(const float4*)(&sf[i4 & 511]);
        float4 o;
        o.x = a_ * (f4.x - c4.x);
        o.y = a_ * (f4.y - c4.y);
        o.z = a_ * (f4.z - c4.z);
        o.w = a_ * (f4.w - c4.w);
        *(float4*)(v + (size_t)b * 32768 + i4) = o;
    }
}

// ---------------- fc1a: K-split partial GEMV; part[ks][b][d]
__global__ __launch_bounds__(256) void k_fc1a(const float* __restrict__ v,
                                              const float* __restrict__ fw1,
                                              float* __restrict__ part) {
    const int d = blockIdx.x, ks = blockIdx.y;
    const int base = ks * 4096;
    float acc[16];
#pragma unroll
    for (int i = 0; i < 16; ++i) acc[i] = 0.f;
    const float* wrow = fw1 + (size_t)d * 32768 + base;
    const float* vb = v + base;
#pragma unroll
    for (int it = 0; it < 4; ++it) {
        const int j4 = it * 1024 + threadIdx.x * 4;
        const float4 w = *(const float4*)(wrow + j4);
#pragma unroll
        for (int b = 0; b < 16; ++b) {
            const float4 vv = *(const float4*)(vb + (size_t)b * 32768 + j4);
            acc[b] += w.x * vv.x + w.y * vv.y + w.z * vv.z + w.w * vv.w;
        }
    }
#pragma unroll
    for (int b = 0; b < 16; ++b) {
        float s = acc[b];
        for (int off = 32; off >= 1; off >>= 1) s += __shfl_down(s, off, 64);
        acc[b] = s;
    }
    __shared__ float red[4][16];
    const int wid = threadIdx.x >> 6, lane = threadIdx.x & 63;
    if (lane == 0) {
#pragma unroll
        for (int b = 0; b < 16; ++b) red[wid][b] = acc[b];
    }
    __syncthreads();
    if (threadIdx.x < 16) {
        const int b = threadIdx.x;
        part[((size_t)ks * 16 + b) * 256 + d] = red[0][b] + red[1][b] + red[2][b] + red[3][b];
    }
}

// ---------------- fc1r: reduce 8 partials + bias + relu -> d1 (16,256)
__global__ __launch_bounds__(256) void k_fc1r(const float* __restrict__ part,
                                              const float* __restrict__ fb1,
                                              float* __restrict__ d1) {
    const int i = blockIdx.x * 256 + threadIdx.x;         // 16 blocks -> 4096
    const int d = i & 255;
    float s = fb1[d];
#pragma unroll
    for (int ks = 0; ks < 8; ++ks) s += part[(size_t)ks * 4096 + i];
    d1[i] = fmaxf(s, 0.f);
}

// ---------------- fc2 + L2 norm
__global__ __launch_bounds__(256) void k_fc2(const float* __restrict__ d1,
                                             const float* __restrict__ fw2,
                                             const float* __restrict__ fb2,
                                             float* __restrict__ out) {
    const int b = blockIdx.x;
    const int dd = threadIdx.x;
    __shared__ float sd[256];
    __shared__ float sq[256];
    sd[dd] = d1[b * 256 + dd];
    __syncthreads();
    float s = fb2[dd];
    for (int j = 0; j < 256; ++j) s += sd[j] * fw2[(size_t)dd * 256 + j];
    sq[dd] = s * s;
    __syncthreads();
    for (int off = 128; off >= 1; off >>= 1) {
        if (dd < off) sq[dd] += sq[dd + off];
        __syncthreads();
    }
    const float inv = rsqrtf(sq[0]);
    out[b * 256 + dd] = s * inv;
}

extern "C" void kernel_launch(void* const* d_in, const int* in_sizes, int n_in,
                              void* d_out, int out_size, void* d_ws, size_t ws_size,
                              hipStream_t stream) {
    const float* x    = (const float*)d_in[0];
    const float* w1   = (const float*)d_in[1];
    const float* b1   = (const float*)d_in[2];
    const float* w2   = (const float*)d_in[3];
    const float* b2   = (const float*)d_in[4];
    const float* w3   = (const float*)d_in[5];
    const float* b3   = (const float*)d_in[6];
    const float* w4   = (const float*)d_in[7];
    const float* b4   = (const float*)d_in[8];
    const float* wv   = (const float*)d_in[9];
    const float* bv   = (const float*)d_in[10];
    const float* cen  = (const float*)d_in[11];
    const float* fw1  = (const float*)d_in[12];
    const float* fb1  = (const float*)d_in[13];
    const float* fw2  = (const float*)d_in[14];
    const float* fb2  = (const float*)d_in[15];
    float* out = (float*)d_out;

    char* p = (char*)d_ws;
    ushort_t* y1    = (ushort_t*)p; p += 33554432;  // 16*128*128*64 bf16
    ushort_t* wpk2  = (ushort_t*)p; p += 147456;    // 73728 bf16
    ushort_t* wpk3  = (ushort_t*)p; p += 589824;    // 294912 bf16
    ushort_t* wpk4m = (ushort_t*)p; p += 2359296;   // 1179648 bf16
    ushort_t* wpk1  = (ushort_t*)p; p += 4096;      // 2048 bf16
    // A region (64 MB) — dead after k_conv1g; later buffers alias into it
    char* aRegion = p;
    ushort_t* A    = (ushort_t*)aRegion;            // 1048576*32 bf16 = 64 MB
    char* q = aRegion;
    ushort_t* y2   = (ushort_t*)q; q += 4194304;    // 16*32*32*128 bf16
    ushort_t* y3   = (ushort_t*)q; q += 524288;     // 16*8*8*256 bf16
    float*    feats= (float*)q;    q += 32768;      // 16*512
    float*    vbuf = (float*)q;    q += 2097152;    // 16*32768
    float*    d1   = (float*)q;    q += 16384;      // 16*256
    ushort_t* A4   = (ushort_t*)q; q += 1179648;    // 256*2304 bf16
    float*    part = (float*)q;    q += 131072;     // 8*16*256 f32

    const size_t need = (size_t)(aRegion - (char*)d_ws) + 67108864;
    const bool useMfmaConv1 = (ws_size >= need);

    k_pack2<<<36, 256, 0, stream>>>(w2, wpk2);
    k_pack3<<<144, 256, 0, stream>>>(w3, wpk3);
    k_pack4m<<<512, 256, 0, stream>>>(w4, wpk4m);
    if (useMfmaConv1) {
        k_pack1<<<1, 256, 0, stream>>>(w1, wpk1);
        k_im2col2b<<<2048, 256, 0, stream>>>(x, A);
        k_conv1g<<<1024, 256, 0, stream>>>(A, wpk1, b1, y1);
    } else {
        k_conv1<<<dim3(256, 16), 256, 0, stream>>>(x, w1, b1, y1);
    }
    k_conv2s<<<dim3(32, 2, 16), 256, 0, stream>>>(y1, wpk2, b2, y2);
    k_conv3m<<<dim3(4, 4, 16), 256, 0, stream>>>(y2, wpk3, b3, y3);
    k_im2col4<<<256, 256, 0, stream>>>(y3, A4);
    k_conv4g<<<dim3(32, 16), 256, 0, stream>>>(A4, wpk4m, b4, feats);
    k_head<<<16, 256, 0, stream>>>(feats, wv, bv, cen, vbuf);
    k_fc1a<<<dim3(256, 8), 256, 0, stream>>>(vbuf, fw1, part);
    k_fc1r<<<16, 256, 0, stream>>>(part, fb1, d1);
    k_fc2<<<16, 256, 0, stream>>>(d1, fw2, fb2, out);
}

// Round 14
// 159.900 us; speedup vs baseline: 1.3880x; 1.0960x over previous
//
#include <hip/hip_runtime.h>
#include <hip/hip_bf16.h>

typedef unsigned short ushort_t;
typedef short bf16x8 __attribute__((ext_vector_type(8)));
typedef float f32x4 __attribute__((ext_vector_type(4)));

__device__ __forceinline__ ushort_t f2b(float f) {
    __hip_bfloat16 h = __float2bfloat16(f);
    return *reinterpret_cast<ushort_t*>(&h);
}
__device__ __forceinline__ float b2f(short v) {
    union { unsigned int u; float f; } cv;
    cv.u = ((unsigned int)(ushort_t)v) << 16;
    return cv.f;
}

// ---------------- weight repack: w1 (64,3,3,3) -> B-frag order [nf(4)][lane(64)][8], K order k = tap*3+c
__global__ __launch_bounds__(256) void k_pack1(const float* __restrict__ w1, ushort_t* __restrict__ o) {
    const int slot = threadIdx.x;                         // 256 slots
    const int lane = slot & 63, nf = slot >> 6;
    const int co = nf * 16 + (lane & 15);
    const int kg = lane >> 4;
#pragma unroll
    for (int j = 0; j < 8; ++j) {
        const int k = kg * 8 + j;
        float v = 0.f;
        if (k < 27) {
            const int t = k / 3, c = k - 3 * t;
            v = w1[(co * 3 + c) * 9 + t];
        }
        o[slot * 8 + j] = f2b(v);
    }
}

// ---------------- weight repack: w2 (128,64,3,3) -> B-fragment order, bf16
// K order = tap*64 + s, storage channel s -> original ci = 16*(s&3) + (s>>2)
__global__ __launch_bounds__(256) void k_pack2(const float* __restrict__ w2, ushort_t* __restrict__ o) {
    const int slot = blockIdx.x * 256 + threadIdx.x;      // 9216 slots
    const int lane = slot & 63, g = (slot >> 6) & 7, kc = slot >> 9;
    const int k0 = kc * 32 + ((lane >> 4) << 3);
    const int tap = k0 >> 6, sb = k0 & 63;
    const int ky = tap >= 6 ? 2 : (tap >= 3 ? 1 : 0), kx = tap - ky * 3;
    const int co = g * 16 + (lane & 15);
#pragma unroll
    for (int j = 0; j < 8; ++j) {
        const int s = sb + j;
        const int ci = 16 * (s & 3) + (s >> 2);
        o[slot * 8 + j] = f2b(w2[((co * 64 + ci) * 3 + ky) * 3 + kx]);
    }
}

// w3 (256,128,3,3): [kc(36)][g16(16)][lane][8], K order = tap*128+ci
__global__ __launch_bounds__(256) void k_pack3(const float* __restrict__ w3, ushort_t* __restrict__ o) {
    const int slot = blockIdx.x * 256 + threadIdx.x;      // 36864 slots
    const int lane = slot & 63, g = (slot >> 6) & 15, kc = slot >> 10;
    const int k0 = kc * 32 + ((lane >> 4) << 3);
    const int tap = k0 >> 7, cib = k0 & 127;
    const int ky = tap >= 6 ? 2 : (tap >= 3 ? 1 : 0), kx = tap - ky * 3;
    const int co = g * 16 + (lane & 15);
#pragma unroll
    for (int j = 0; j < 8; ++j)
        o[slot * 8 + j] = f2b(w3[((co * 128 + cib + j) * 3 + ky) * 3 + kx]);
}

// w4 (512,256,3,3) -> MFMA B-frag bf16 [kc(72)][g16(32)][lane(64)][8], K order = tap*256+ci
__global__ __launch_bounds__(256) void k_pack4m(const float* __restrict__ w4, ushort_t* __restrict__ o) {
    const int co = blockIdx.x;                            // 512 blocks
    __shared__ float sw[2304];
    for (int i = threadIdx.x; i < 2304; i += 256) sw[i] = w4[(size_t)co * 2304 + i];
    __syncthreads();
    const int g = co >> 4, l15 = co & 15;
    for (int it = threadIdx.x; it < 288; it += 256) {
        const int kc = it >> 2, kg = it & 3;
        const int k0 = kc * 32 + kg * 8;
        const int tap = k0 >> 8, ci0 = k0 & 255;
        const int lane = kg * 16 + l15;
        ushort_t tmp[8];
#pragma unroll
        for (int j = 0; j < 8; ++j)
            tmp[j] = f2b(sw[(ci0 + j) * 9 + tap]);
        *(float4*)(o + ((size_t)(kc * 32 + g) * 64 + lane) * 8) = *(const float4*)tmp;
    }
}

// ---------------- fused conv1: x f32 -> (LDS stage + in-LDS im2col gather) -> MFMA
// -> pool+bias+relu -> y1 bf16 (permuted ch s=4*l15+nf). Block = 2 pooled rows x 128 px.
// grid (rp=64, b=16). LDS tile: [c(3)][r(9)][colx(513 pad 520)] bf16 = 28KB.
__global__ __launch_bounds__(256) void k_conv1f(const float* __restrict__ x,
                                                const ushort_t* __restrict__ wpk1,
                                                const float* __restrict__ b1,
                                                ushort_t* __restrict__ y1) {
    const int rp = blockIdx.x, b = blockIdx.y;
    const int tid = threadIdx.x;
    const int wid = tid >> 6, lane = tid & 63;
    const int l15 = lane & 15, kg = lane >> 4;

    __shared__ __align__(16) ushort_t sX[3 * 9 * 520];    // 28080 B
    const float* xb = x + (size_t)b * 3 * 512 * 512;
    const int iy0 = 8 * rp - 1;
    for (int idx = tid; idx < 13851; idx += 256) {        // 3*9*513
        const int c = idx / 4617;
        const int rem = idx - c * 4617;
        const int r = rem / 513;
        const int colx = rem - r * 513;
        const int iy = iy0 + r, ix = colx - 1;
        float v = 0.f;
        if (iy >= 0 && ix >= 0) v = xb[((size_t)c * 512 + iy) * 512 + ix];
        sX[(c * 9 + r) * 520 + colx] = f2b(v);
    }
    __syncthreads();

    // per-lane gather offsets for the 8 k-values of this lane's A-chunk (k = kg*8+j)
    // idx = c*4680 + ky*520 + kx  (+ base = cr*1040 + 2*ox per fragment)
    const int kbase = kg * 8;
#define OFFJ(J) __extension__ ({ int k_ = kbase + (J); if (k_ > 26) k_ = 26; \
        const int tap_ = k_ / 3; const int c_ = k_ - 3 * tap_; \
        const int ky_ = tap_ / 3; const int kx_ = tap_ - 3 * ky_; \
        c_ * 4680 + ky_ * 520 + kx_; })
    const int o0 = OFFJ(0), o1 = OFFJ(1), o2 = OFFJ(2), o3 = OFFJ(3);
    const int o4 = OFFJ(4), o5 = OFFJ(5), o6 = OFFJ(6), o7 = OFFJ(7);
#undef OFFJ
    // A-gather coords from mA = fl*16 + l15
    const int gq = l15 >> 2;                              // pool-group offset within f
    const int dy = (l15 >> 1) & 1, dx = l15 & 1;

    bf16x8 bF[4];
    float bias[4];
#pragma unroll
    for (int nf = 0; nf < 4; ++nf) {
        bF[nf] = *reinterpret_cast<const bf16x8*>(wpk1 + (size_t)(nf * 64 + lane) * 8);
        bias[nf] = b1[nf * 16 + l15];
    }
    const f32x4 z4 = {0.f, 0.f, 0.f, 0.f};

#pragma unroll 2
    for (int it = 0; it < 16; ++it) {
        const int fl = wid * 16 + it;                     // f_local 0..63
        const int g2 = fl * 4 + gq;                       // A-row pool group 0..255
        const int pyl = g2 >> 7, pxl = g2 & 127;
        const int cr = 2 * pyl + dy;                      // block-local conv row 0..3
        const int ox = 2 * pxl + dx;                      // conv col 0..255
        const int base = cr * 1040 + 2 * ox;
        bf16x8 aF;
        aF[0] = (short)sX[base + o0];
        aF[1] = (short)sX[base + o1];
        aF[2] = (short)sX[base + o2];
        aF[3] = (short)sX[base + o3];
        aF[4] = (short)sX[base + o4];
        aF[5] = (short)sX[base + o5];
        aF[6] = (short)sX[base + o6];
        aF[7] = (short)sX[base + o7];
        f32x4 acc[4];
#pragma unroll
        for (int nf = 0; nf < 4; ++nf)
            acc[nf] = __builtin_amdgcn_mfma_f32_16x16x32_bf16(aF, bF[nf], z4, 0, 0, 0);
        // C layout: lane holds pool group g_out = fl*4 + kg, channel l15 (4 nf)
        const int g_out = fl * 4 + kg;
        const int pyo = g_out >> 7, pxo = g_out & 127;
        union { ushort_t u[4]; uint2 v; } pk;
#pragma unroll
        for (int nf = 0; nf < 4; ++nf) {
            float v = fmaxf(fmaxf(acc[nf][0], acc[nf][1]), fmaxf(acc[nf][2], acc[nf][3]));
            pk.u[nf] = f2b(fmaxf(v + bias[nf], 0.f));
        }
        *(uint2*)(y1 + ((size_t)(b * 128 + 2 * rp + pyo) * 128 + pxo) * 64 + 4 * l15) = pk.v;
    }
}

// ---------------- conv2 LDS-staged MFMA: y1 bf16 (permuted ch) -> y2 bf16 NHWC (16,32,32,128)
__global__ __launch_bounds__(256) void k_conv2s(const ushort_t* __restrict__ y1,
                                                const ushort_t* __restrict__ wpk2,
                                                const float* __restrict__ b2,
                                                ushort_t* __restrict__ y2) {
    const int b = blockIdx.z;
    const int xh = blockIdx.y;               // ox half
    const int rp = blockIdx.x;               // pooled row 0..31
    const int tid = threadIdx.x;
    const int wid = tid >> 6, lane = tid & 63;
    const int l15 = lane & 15, kg = lane >> 4;

    __shared__ __align__(16) ushort_t sY[330 * 72];       // [pc=r*66+cc][ch pad 72], 46.4KB
    bf16x8* sYv = (bf16x8*)sY;                            // pc stride = 9 chunks

    const ushort_t* xb = y1 + (size_t)b * 128 * 128 * 64;
    const int iyb = 4 * rp - 1, ixb = 64 * xh - 1;
    for (int j = tid; j < 2640; j += 256) {
        const int q = j & 7;
        const int pc = j >> 3;
        const int cc = pc % 66, r = pc / 66;
        const int iy = iyb + r, ix = ixb + cc;
        bf16x8 v = {0, 0, 0, 0, 0, 0, 0, 0};
        if (iy >= 0 && ix >= 0 && ix < 128)
            v = *reinterpret_cast<const bf16x8*>(xb + ((size_t)iy * 128 + ix) * 64 + q * 8);
        sYv[pc * 9 + (q ^ ((pc >> 1) & 7))] = v;
    }
    __syncthreads();

    const f32x4 z4 = {0.f, 0.f, 0.f, 0.f};
    f32x4 acc[2][2][2];                      // [oyi][m2][nf]
#pragma unroll
    for (int i = 0; i < 2; ++i)
#pragma unroll
        for (int j = 0; j < 2; ++j) { acc[i][j][0] = z4; acc[i][j][1] = z4; }

#pragma unroll 1
    for (int tap = 0; tap < 9; ++tap) {
        const int ky = tap >= 6 ? 2 : (tap >= 3 ? 1 : 0), kx = tap - ky * 3;
#pragma unroll
        for (int h = 0; h < 2; ++h) {
            const int kc = tap * 2 + h;
            const int c8 = h * 4 + kg;       // channel chunk 0..7
            bf16x8 aF[2][2];
#pragma unroll
            for (int oyi = 0; oyi < 2; ++oyi)
#pragma unroll
            for (int m2 = 0; m2 < 2; ++m2) {
                const int r = 2 * oyi + ky;
                const int cc = 2 * l15 + m2 * 32 + kx;
                const int pc = r * 66 + cc;
                aF[oyi][m2] = sYv[pc * 9 + (c8 ^ ((pc >> 1) & 7))];
            }
            bf16x8 bF[2];
#pragma unroll
            for (int nf = 0; nf < 2; ++nf)
                bF[nf] = *reinterpret_cast<const bf16x8*>(wpk2 + ((size_t)(kc * 8 + wid * 2 + nf) * 64 + lane) * 8);
#pragma unroll
            for (int oyi = 0; oyi < 2; ++oyi)
#pragma unroll
            for (int m2 = 0; m2 < 2; ++m2)
#pragma unroll
            for (int nf = 0; nf < 2; ++nf)
                acc[oyi][m2][nf] = __builtin_amdgcn_mfma_f32_16x16x32_bf16(aF[oyi][m2], bF[nf], acc[oyi][m2][nf], 0, 0, 0);
        }
    }
    const int kgx = lane >> 4;
#pragma unroll
    for (int nf = 0; nf < 2; ++nf) {
        const int co = wid * 32 + nf * 16 + l15;
        const float bias = b2[co];
#pragma unroll
        for (int m2 = 0; m2 < 2; ++m2)
#pragma unroll
            for (int p = 0; p < 2; ++p) {
                float v = fmaxf(fmaxf(acc[0][m2][nf][2 * p], acc[0][m2][nf][2 * p + 1]),
                                fmaxf(acc[1][m2][nf][2 * p], acc[1][m2][nf][2 * p + 1]));
                const int px = (xh * 2 + m2) * 8 + kgx * 2 + p;
                y2[((size_t)(b * 32 + rp) * 32 + px) * 128 + co] = f2b(fmaxf(v + bias, 0.f));
            }
    }
}

// ---------------- conv3 MFMA: y2 bf16 NHWC -> y3 bf16 NHWC (16,8,8,256)
__global__ __launch_bounds__(256) void k_conv3m(const ushort_t* __restrict__ y2,
                                                const ushort_t* __restrict__ wpk3,
                                                const float* __restrict__ b3,
                                                ushort_t* __restrict__ y3) {
    const int gy = blockIdx.x, gn = blockIdx.y, b = blockIdx.z;
    const int oy0 = gy * 4;
    const int tid = threadIdx.x;
    const int wid = tid >> 6, lane = tid & 63;
    const int l15 = lane & 15, kl8 = (lane >> 4) << 3;
    const int g16 = gn * 4 + wid;
    const int co = g16 * 16 + l15;

    const ushort_t* xb = y2 + (size_t)b * 32 * 32 * 128;
    const f32x4 z4 = {0.f, 0.f, 0.f, 0.f};
    f32x4 acc[4] = {z4, z4, z4, z4};

#pragma unroll 1
    for (int tap = 0; tap < 9; ++tap) {
        const int ky = tap >= 6 ? 2 : (tap >= 3 ? 1 : 0), kx = tap - ky * 3;
        const int iyA = 2 * oy0 - 1 + ky;
        const int c = 2 * l15 - 1 + kx;
        const bool cok = (c >= 0);
#pragma unroll
        for (int h = 0; h < 4; ++h) {
            const int ci0 = h * 32;
            const int kc = tap * 4 + h;
            bf16x8 aF[4];
#pragma unroll
            for (int mf = 0; mf < 4; ++mf) {
                const int iy = iyA + 2 * mf;
                bf16x8 r = {0, 0, 0, 0, 0, 0, 0, 0};
                if (cok && iy >= 0) r = *reinterpret_cast<const bf16x8*>(xb + ((size_t)iy * 32 + c) * 128 + ci0 + kl8);
                aF[mf] = r;
            }
            const bf16x8 bF = *reinterpret_cast<const bf16x8*>(wpk3 + ((size_t)(kc * 16 + g16) * 64 + lane) * 8);
#pragma unroll
            for (int mf = 0; mf < 4; ++mf)
                acc[mf] = __builtin_amdgcn_mfma_f32_16x16x32_bf16(aF[mf], bF, acc[mf], 0, 0, 0);
        }
    }
    const int kg = lane >> 4;
    const float bias = b3[co];
#pragma unroll
    for (int mp = 0; mp < 2; ++mp) {
        const int py = gy * 2 + mp;
#pragma unroll
        for (int p = 0; p < 2; ++p) {
            float v = fmaxf(fmaxf(acc[2 * mp][2 * p], acc[2 * mp][2 * p + 1]),
                            fmaxf(acc[2 * mp + 1][2 * p], acc[2 * mp + 1][2 * p + 1]));
            const int px = kg * 2 + p;
            y3[((size_t)(b * 8 + py) * 8 + px) * 256 + co] = f2b(fmaxf(v + bias, 0.f));
        }
    }
}

// ---------------- im2col for conv4: y3 bf16 NHWC -> A4 [256][2304] bf16, k = tap*256+ci
__global__ __launch_bounds__(256) void k_im2col4(const ushort_t* __restrict__ y3, ushort_t* __restrict__ A4) {
    const int m = blockIdx.x;                             // 256 blocks
    const int b = m >> 4, pix = m & 15;
    const int oy = pix >> 2, ox = pix & 3;
    const ushort_t* xb = y3 + (size_t)b * 16384;
    for (int it = threadIdx.x; it < 288; it += 256) {
        const int tap = it >> 5, ci8 = it & 31;
        const int ky = tap / 3, kx = tap - 3 * (tap / 3);
        const int iy = 2 * oy - 1 + ky, ix = 2 * ox - 1 + kx;
        bf16x8 r = {0, 0, 0, 0, 0, 0, 0, 0};
        if (iy >= 0 && ix >= 0)
            r = *reinterpret_cast<const bf16x8*>(xb + ((iy * 8 + ix) << 8) + ci8 * 8);
        *reinterpret_cast<bf16x8*>(A4 + (size_t)m * 2304 + tap * 256 + ci8 * 8) = r;
    }
}

// ---------------- conv4 GEMM + relu + mean (K-split across 4 waves, 512 blocks)
__global__ __launch_bounds__(256) void k_conv4g(const ushort_t* __restrict__ A4,
                                                const ushort_t* __restrict__ wpk4m,
                                                const float* __restrict__ b4,
                                                float* __restrict__ feats) {
    const int g16 = blockIdx.x, b = blockIdx.y;
    const int tid = threadIdx.x, wid = tid >> 6, lane = tid & 63;
    const int l15 = lane & 15, kg = lane >> 4, kl8 = kg << 3;
    const f32x4 z4 = {0.f, 0.f, 0.f, 0.f};
    f32x4 acc = z4;
    const ushort_t* arow = A4 + (size_t)(b * 16 + l15) * 2304 + kl8;
    const int kc0 = wid * 18;

#pragma unroll 3
    for (int i = 0; i < 18; ++i) {
        const int kc = kc0 + i;
        const bf16x8 aF = *reinterpret_cast<const bf16x8*>(arow + kc * 32);
        const bf16x8 bF = *reinterpret_cast<const bf16x8*>(wpk4m + ((size_t)(kc * 32 + g16) * 64 + lane) * 8);
        acc = __builtin_amdgcn_mfma_f32_16x16x32_bf16(aF, bF, acc, 0, 0, 0);
    }

    __shared__ f32x4 red[4][64];
    red[wid][lane] = acc;
    __syncthreads();
    if (wid == 0) {
        f32x4 t = red[0][lane];
        t = t + red[1][lane];
        t = t + red[2][lane];
        t = t + red[3][lane];
        const int co = g16 * 16 + l15;
        const float bias = b4[co];
        float s = fmaxf(t[0] + bias, 0.f) + fmaxf(t[1] + bias, 0.f)
                + fmaxf(t[2] + bias, 0.f) + fmaxf(t[3] + bias, 0.f);
        s += __shfl_xor(s, 16, 64);
        s += __shfl_xor(s, 32, 64);
        if (kg == 0) feats[b * 512 + co] = s * 0.0625f;
    }
}

// ---------------- head: feats -> logits -> softmax -> VLAD residual v (16, 32768)
__global__ __launch_bounds__(256) void k_head(const float* __restrict__ feats,
                                              const float* __restrict__ wv,
                                              const float* __restrict__ bv,
                                              const float* __restrict__ centroids,
                                              float* __restrict__ v) {
    const int b = blockIdx.x;
    __shared__ float sf[512];
    __shared__ float sl[64];
    __shared__ float sa[64];
    for (int i = threadIdx.x; i < 512; i += 256) sf[i] = feats[b * 512 + i];
    __syncthreads();
    if (threadIdx.x < 64) {
        const int k = threadIdx.x;
        float s = bv[k];
        for (int c = 0; c < 512; ++c) s += sf[c] * wv[(size_t)k * 512 + c];
        sl[k] = s;
    }
    __syncthreads();
    if (threadIdx.x < 64) {
        const int k = threadIdx.x;
        float m = -1e30f;
        for (int i = 0; i < 64; ++i) m = fmaxf(m, sl[i]);
        float sum = 0.f;
        for (int i = 0; i < 64; ++i) sum += __expf(sl[i] - m);
        sa[k] = __expf(sl[k] - m) / sum;
    }
    __syncthreads();
    for (int i4 = threadIdx.x * 4; i4 < 32768; i4 += 1024) {
        const int k = i4 >> 9;
        const float a_ = sa[k];
        const float4 c4 = *(const float4*)(centroids + i4);
        const float4 f4 = *(const float4*)(&sf[i4 & 511]);
        float4 o;
        o.x = a_ * (f4.x - c4.x);
        o.y = a_ * (f4.y - c4.y);
        o.z = a_ * (f4.z - c4.z);
        o.w = a_ * (f4.w - c4.w);
        *(float4*)(v + (size_t)b * 32768 + i4) = o;
    }
}

// ---------------- fc1a: K-split partial GEMV; part[ks][b][d]
__global__ __launch_bounds__(256) void k_fc1a(const float* __restrict__ v,
                                              const float* __restrict__ fw1,
                                              float* __restrict__ part) {
    const int d = blockIdx.x, ks = blockIdx.y;
    const int base = ks * 4096;
    float acc[16];
#pragma unroll
    for (int i = 0; i < 16; ++i) acc[i] = 0.f;
    const float* wrow = fw1 + (size_t)d * 32768 + base;
    const float* vb = v + base;
#pragma unroll
    for (int it = 0; it < 4; ++it) {
        const int j4 = it * 1024 + threadIdx.x * 4;
        const float4 w = *(const float4*)(wrow + j4);
#pragma unroll
        for (int b = 0; b < 16; ++b) {
            const float4 vv = *(const float4*)(vb + (size_t)b * 32768 + j4);
            acc[b] += w.x * vv.x + w.y * vv.y + w.z * vv.z + w.w * vv.w;
        }
    }
#pragma unroll
    for (int b = 0; b < 16; ++b) {
        float s = acc[b];
        for (int off = 32; off >= 1; off >>= 1) s += __shfl_down(s, off, 64);
        acc[b] = s;
    }
    __shared__ float red[4][16];
    const int wid = threadIdx.x >> 6, lane = threadIdx.x & 63;
    if (lane == 0) {
#pragma unroll
        for (int b = 0; b < 16; ++b) red[wid][b] = acc[b];
    }
    __syncthreads();
    if (threadIdx.x < 16) {
        const int b = threadIdx.x;
        part[((size_t)ks * 16 + b) * 256 + d] = red[0][b] + red[1][b] + red[2][b] + red[3][b];
    }
}

// ---------------- fc1r: reduce 8 partials + bias + relu -> d1 (16,256)
__global__ __launch_bounds__(256) void k_fc1r(const float* __restrict__ part,
                                              const float* __restrict__ fb1,
                                              float* __restrict__ d1) {
    const int i = blockIdx.x * 256 + threadIdx.x;         // 16 blocks -> 4096
    const int d = i & 255;
    float s = fb1[d];
#pragma unroll
    for (int ks = 0; ks < 8; ++ks) s += part[(size_t)ks * 4096 + i];
    d1[i] = fmaxf(s, 0.f);
}

// ---------------- fc2 + L2 norm
__global__ __launch_bounds__(256) void k_fc2(const float* __restrict__ d1,
                                             const float* __restrict__ fw2,
                                             const float* __restrict__ fb2,
                                             float* __restrict__ out) {
    const int b = blockIdx.x;
    const int dd = threadIdx.x;
    __shared__ float sd[256];
    __shared__ float sq[256];
    sd[dd] = d1[b * 256 + dd];
    __syncthreads();
    float s = fb2[dd];
    for (int j = 0; j < 256; ++j) s += sd[j] * fw2[(size_t)dd * 256 + j];
    sq[dd] = s * s;
    __syncthreads();
    for (int off = 128; off >= 1; off >>= 1) {
        if (dd < off) sq[dd] += sq[dd + off];
        __syncthreads();
    }
    const float inv = rsqrtf(sq[0]);
    out[b * 256 + dd] = s * inv;
}

extern "C" void kernel_launch(void* const* d_in, const int* in_sizes, int n_in,
                              void* d_out, int out_size, void* d_ws, size_t ws_size,
                              hipStream_t stream) {
    const float* x    = (const float*)d_in[0];
    const float* w1   = (const float*)d_in[1];
    const float* b1   = (const float*)d_in[2];
    const float* w2   = (const float*)d_in[3];
    const float* b2   = (const float*)d_in[4];
    const float* w3   = (const float*)d_in[5];
    const float* b3   = (const float*)d_in[6];
    const float* w4   = (const float*)d_in[7];
    const float* b4   = (const float*)d_in[8];
    const float* wv   = (const float*)d_in[9];
    const float* bv   = (const float*)d_in[10];
    const float* cen  = (const float*)d_in[11];
    const float* fw1  = (const float*)d_in[12];
    const float* fb1  = (const float*)d_in[13];
    const float* fw2  = (const float*)d_in[14];
    const float* fb2  = (const float*)d_in[15];
    float* out = (float*)d_out;

    char* p = (char*)d_ws;
    ushort_t* y1    = (ushort_t*)p; p += 33554432;  // 16*128*128*64 bf16
    ushort_t* wpk2  = (ushort_t*)p; p += 147456;    // 73728 bf16
    ushort_t* wpk3  = (ushort_t*)p; p += 589824;    // 294912 bf16
    ushort_t* wpk4m = (ushort_t*)p; p += 2359296;   // 1179648 bf16
    ushort_t* wpk1  = (ushort_t*)p; p += 4096;      // 2048 bf16
    ushort_t* y2    = (ushort_t*)p; p += 4194304;   // 16*32*32*128 bf16
    ushort_t* y3    = (ushort_t*)p; p += 524288;    // 16*8*8*256 bf16
    float*    feats = (float*)p;    p += 32768;     // 16*512
    float*    vbuf  = (float*)p;    p += 2097152;   // 16*32768
    float*    d1    = (float*)p;    p += 16384;     // 16*256
    ushort_t* A4    = (ushort_t*)p; p += 2359296;   // 256*2304 bf16
    float*    part  = (float*)p;    p += 131072;    // 8*16*256 f32

    k_pack1<<<1, 256, 0, stream>>>(w1, wpk1);
    k_pack2<<<36, 256, 0, stream>>>(w2, wpk2);
    k_pack3<<<144, 256, 0, stream>>>(w3, wpk3);
    k_pack4m<<<512, 256, 0, stream>>>(w4, wpk4m);
    k_conv1f<<<dim3(64, 16), 256, 0, stream>>>(x, wpk1, b1, y1);
    k_conv2s<<<dim3(32, 2, 16), 256, 0, stream>>>(y1, wpk2, b2, y2);
    k_conv3m<<<dim3(4, 4, 16), 256, 0, stream>>>(y2, wpk3, b3, y3);
    k_im2col4<<<256, 256, 0, stream>>>(y3, A4);
    k_conv4g<<<dim3(32, 16), 256, 0, stream>>>(A4, wpk4m, b4, feats);
    k_head<<<16, 256, 0, stream>>>(feats, wv, bv, cen, vbuf);
    k_fc1a<<<dim3(256, 8), 256, 0, stream>>>(vbuf, fw1, part);
    k_fc1r<<<16, 256, 0, stream>>>(part, fb1, d1);
    k_fc2<<<16, 256, 0, stream>>>(d1, fw2, fb2, out);
}

// Round 15
// 148.873 us; speedup vs baseline: 1.4909x; 1.0741x over previous
//
#include <hip/hip_runtime.h>
#include <hip/hip_bf16.h>

typedef unsigned short ushort_t;
typedef short bf16x8 __attribute__((ext_vector_type(8)));
typedef float f32x4 __attribute__((ext_vector_type(4)));

__device__ __forceinline__ ushort_t f2b(float f) {
    __hip_bfloat16 h = __float2bfloat16(f);
    return *reinterpret_cast<ushort_t*>(&h);
}
__device__ __forceinline__ float b2f(short v) {
    union { unsigned int u; float f; } cv;
    cv.u = ((unsigned int)(ushort_t)v) << 16;
    return cv.f;
}

// ---------------- weight repack: w1 (64,3,3,3) -> B-frag order [nf(4)][lane(64)][8], K order k = tap*3+c
__global__ __launch_bounds__(256) void k_pack1(const float* __restrict__ w1, ushort_t* __restrict__ o) {
    const int slot = threadIdx.x;                         // 256 slots
    const int lane = slot & 63, nf = slot >> 6;
    const int co = nf * 16 + (lane & 15);
    const int kg = lane >> 4;
#pragma unroll
    for (int j = 0; j < 8; ++j) {
        const int k = kg * 8 + j;
        float v = 0.f;
        if (k < 27) {
            const int t = k / 3, c = k - 3 * t;
            v = w1[(co * 3 + c) * 9 + t];
        }
        o[slot * 8 + j] = f2b(v);
    }
}

// ---------------- weight repack: w2 (128,64,3,3) -> B-fragment order, bf16
// K order = tap*64 + s, storage channel s -> original ci = 16*(s&3) + (s>>2)
__global__ __launch_bounds__(256) void k_pack2(const float* __restrict__ w2, ushort_t* __restrict__ o) {
    const int slot = blockIdx.x * 256 + threadIdx.x;      // 9216 slots
    const int lane = slot & 63, g = (slot >> 6) & 7, kc = slot >> 9;
    const int k0 = kc * 32 + ((lane >> 4) << 3);
    const int tap = k0 >> 6, sb = k0 & 63;
    const int ky = tap >= 6 ? 2 : (tap >= 3 ? 1 : 0), kx = tap - ky * 3;
    const int co = g * 16 + (lane & 15);
#pragma unroll
    for (int j = 0; j < 8; ++j) {
        const int s = sb + j;
        const int ci = 16 * (s & 3) + (s >> 2);
        o[slot * 8 + j] = f2b(w2[((co * 64 + ci) * 3 + ky) * 3 + kx]);
    }
}

// w3 (256,128,3,3): [kc(36)][g16(16)][lane][8], K order = tap*128+ci
__global__ __launch_bounds__(256) void k_pack3(const float* __restrict__ w3, ushort_t* __restrict__ o) {
    const int slot = blockIdx.x * 256 + threadIdx.x;      // 36864 slots
    const int lane = slot & 63, g = (slot >> 6) & 15, kc = slot >> 10;
    const int k0 = kc * 32 + ((lane >> 4) << 3);
    const int tap = k0 >> 7, cib = k0 & 127;
    const int ky = tap >= 6 ? 2 : (tap >= 3 ? 1 : 0), kx = tap - ky * 3;
    const int co = g * 16 + (lane & 15);
#pragma unroll
    for (int j = 0; j < 8; ++j)
        o[slot * 8 + j] = f2b(w3[((co * 128 + cib + j) * 3 + ky) * 3 + kx]);
}

// w4 (512,256,3,3) -> MFMA B-frag bf16 [kc(72)][g16(32)][lane(64)][8], K order = tap*256+ci
__global__ __launch_bounds__(256) void k_pack4m(const float* __restrict__ w4, ushort_t* __restrict__ o) {
    const int co = blockIdx.x;                            // 512 blocks
    __shared__ float sw[2304];
    for (int i = threadIdx.x; i < 2304; i += 256) sw[i] = w4[(size_t)co * 2304 + i];
    __syncthreads();
    const int g = co >> 4, l15 = co & 15;
    for (int it = threadIdx.x; it < 288; it += 256) {
        const int kc = it >> 2, kg = it & 3;
        const int k0 = kc * 32 + kg * 8;
        const int tap = k0 >> 8, ci0 = k0 & 255;
        const int lane = kg * 16 + l15;
        ushort_t tmp[8];
#pragma unroll
        for (int j = 0; j < 8; ++j)
            tmp[j] = f2b(sw[(ci0 + j) * 9 + tap]);
        *(float4*)(o + ((size_t)(kc * 32 + g) * 64 + lane) * 8) = *(const float4*)tmp;
    }
}

// ---------------- fused conv1 (x-split): x f32 -> LDS stage -> in-LDS im2col gather -> MFMA
// -> pool+bias+relu -> y1 bf16 (permuted ch s=4*l15+nf).
// grid (rp=64, xh=2, b=16) = 2048 blocks. Block = 2 pooled rows x 64 pooled px.
// LDS tile [c(3)][r(9)][colx(257 pad 260)] bf16 = 14040B.
__global__ __launch_bounds__(256) void k_conv1f(const float* __restrict__ x,
                                                const ushort_t* __restrict__ wpk1,
                                                const float* __restrict__ b1,
                                                ushort_t* __restrict__ y1) {
    const int rp = blockIdx.x, xh = blockIdx.y, b = blockIdx.z;
    const int tid = threadIdx.x;
    const int wid = tid >> 6, lane = tid & 63;
    const int l15 = lane & 15, kg = lane >> 4;

    __shared__ __align__(16) ushort_t sX[3 * 9 * 260];    // 14040 B
    const float* xb = x + (size_t)b * 3 * 512 * 512;
    const int iy0 = 8 * rp - 1;
    const int ix0 = 256 * xh - 1;
#pragma unroll
    for (int c = 0; c < 3; ++c)
#pragma unroll
    for (int r = 0; r < 9; ++r) {
        const int iy = iy0 + r;
        const int ix = ix0 + tid;                         // ix <= 510, coalesced
        float v = 0.f;
        if (iy >= 0 && ix >= 0) v = xb[((size_t)c * 512 + iy) * 512 + ix];
        sX[(c * 9 + r) * 260 + tid] = f2b(v);
    }
    if (tid < 27) {                                       // colx = 256 tail
        const int c = tid / 9, r = tid - 9 * c;
        const int iy = iy0 + r, ix = ix0 + 256;
        float v = (iy >= 0) ? xb[((size_t)c * 512 + iy) * 512 + ix] : 0.f;
        sX[(c * 9 + r) * 260 + 256] = f2b(v);
    }
    __syncthreads();

    // per-lane gather offsets for 8 k-values (k = kg*8+j); idx = c*2340 + ky*260 + kx
    const int kbase = kg * 8;
#define OFFJ(J) __extension__ ({ int k_ = kbase + (J); if (k_ > 26) k_ = 26; \
        const int tap_ = k_ / 3; const int c_ = k_ - 3 * tap_; \
        const int ky_ = tap_ / 3; const int kx_ = tap_ - 3 * ky_; \
        c_ * 2340 + ky_ * 260 + kx_; })
    const int o0 = OFFJ(0), o1 = OFFJ(1), o2 = OFFJ(2), o3 = OFFJ(3);
    const int o4 = OFFJ(4), o5 = OFFJ(5), o6 = OFFJ(6), o7 = OFFJ(7);
#undef OFFJ
    const int gq = l15 >> 2;                              // pool-group offset within f
    const int dy = (l15 >> 1) & 1, dx = l15 & 1;

    bf16x8 bF[4];
    float bias[4];
#pragma unroll
    for (int nf = 0; nf < 4; ++nf) {
        bF[nf] = *reinterpret_cast<const bf16x8*>(wpk1 + (size_t)(nf * 64 + lane) * 8);
        bias[nf] = b1[nf * 16 + l15];
    }
    const f32x4 z4 = {0.f, 0.f, 0.f, 0.f};

#pragma unroll 4
    for (int it = 0; it < 8; ++it) {
        const int fl = wid * 8 + it;                      // f_local 0..31
        const int g2 = fl * 4 + gq;                       // A-row pool group 0..127
        const int pyl = g2 >> 6, pxl = g2 & 63;
        const int cr = 2 * pyl + dy;                      // block-local conv row 0..3
        const int oxl = 2 * pxl + dx;                     // block-local conv col 0..127
        const int base = cr * 520 + 2 * oxl;
        bf16x8 aF;
        aF[0] = (short)sX[base + o0];
        aF[1] = (short)sX[base + o1];
        aF[2] = (short)sX[base + o2];
        aF[3] = (short)sX[base + o3];
        aF[4] = (short)sX[base + o4];
        aF[5] = (short)sX[base + o5];
        aF[6] = (short)sX[base + o6];
        aF[7] = (short)sX[base + o7];
        f32x4 acc[4];
#pragma unroll
        for (int nf = 0; nf < 4; ++nf)
            acc[nf] = __builtin_amdgcn_mfma_f32_16x16x32_bf16(aF, bF[nf], z4, 0, 0, 0);
        const int g_out = fl * 4 + kg;                    // output pool group 0..127
        const int pyo = g_out >> 6, pxo = xh * 64 + (g_out & 63);
        union { ushort_t u[4]; uint2 v; } pk;
#pragma unroll
        for (int nf = 0; nf < 4; ++nf) {
            float v = fmaxf(fmaxf(acc[nf][0], acc[nf][1]), fmaxf(acc[nf][2], acc[nf][3]));
            pk.u[nf] = f2b(fmaxf(v + bias[nf], 0.f));
        }
        *(uint2*)(y1 + ((size_t)(b * 128 + 2 * rp + pyo) * 128 + pxo) * 64 + 4 * l15) = pk.v;
    }
}

// ---------------- conv2 LDS-staged MFMA: y1 bf16 (permuted ch) -> y2 bf16 NHWC (16,32,32,128)
__global__ __launch_bounds__(256) void k_conv2s(const ushort_t* __restrict__ y1,
                                                const ushort_t* __restrict__ wpk2,
                                                const float* __restrict__ b2,
                                                ushort_t* __restrict__ y2) {
    const int b = blockIdx.z;
    const int xh = blockIdx.y;               // ox half
    const int rp = blockIdx.x;               // pooled row 0..31
    const int tid = threadIdx.x;
    const int wid = tid >> 6, lane = tid & 63;
    const int l15 = lane & 15, kg = lane >> 4;

    __shared__ __align__(16) ushort_t sY[330 * 72];       // [pc=r*66+cc][ch pad 72], 46.4KB
    bf16x8* sYv = (bf16x8*)sY;                            // pc stride = 9 chunks

    const ushort_t* xb = y1 + (size_t)b * 128 * 128 * 64;
    const int iyb = 4 * rp - 1, ixb = 64 * xh - 1;
    for (int j = tid; j < 2640; j += 256) {
        const int q = j & 7;
        const int pc = j >> 3;
        const int cc = pc % 66, r = pc / 66;
        const int iy = iyb + r, ix = ixb + cc;
        bf16x8 v = {0, 0, 0, 0, 0, 0, 0, 0};
        if (iy >= 0 && ix >= 0 && ix < 128)
            v = *reinterpret_cast<const bf16x8*>(xb + ((size_t)iy * 128 + ix) * 64 + q * 8);
        sYv[pc * 9 + (q ^ ((pc >> 1) & 7))] = v;
    }
    __syncthreads();

    const f32x4 z4 = {0.f, 0.f, 0.f, 0.f};
    f32x4 acc[2][2][2];                      // [oyi][m2][nf]
#pragma unroll
    for (int i = 0; i < 2; ++i)
#pragma unroll
        for (int j = 0; j < 2; ++j) { acc[i][j][0] = z4; acc[i][j][1] = z4; }

#pragma unroll 1
    for (int tap = 0; tap < 9; ++tap) {
        const int ky = tap >= 6 ? 2 : (tap >= 3 ? 1 : 0), kx = tap - ky * 3;
#pragma unroll
        for (int h = 0; h < 2; ++h) {
            const int kc = tap * 2 + h;
            const int c8 = h * 4 + kg;       // channel chunk 0..7
            bf16x8 aF[2][2];
#pragma unroll
            for (int oyi = 0; oyi < 2; ++oyi)
#pragma unroll
            for (int m2 = 0; m2 < 2; ++m2) {
                const int r = 2 * oyi + ky;
                const int cc = 2 * l15 + m2 * 32 + kx;
                const int pc = r * 66 + cc;
                aF[oyi][m2] = sYv[pc * 9 + (c8 ^ ((pc >> 1) & 7))];
            }
            bf16x8 bF[2];
#pragma unroll
            for (int nf = 0; nf < 2; ++nf)
                bF[nf] = *reinterpret_cast<const bf16x8*>(wpk2 + ((size_t)(kc * 8 + wid * 2 + nf) * 64 + lane) * 8);
#pragma unroll
            for (int oyi = 0; oyi < 2; ++oyi)
#pragma unroll
            for (int m2 = 0; m2 < 2; ++m2)
#pragma unroll
            for (int nf = 0; nf < 2; ++nf)
                acc[oyi][m2][nf] = __builtin_amdgcn_mfma_f32_16x16x32_bf16(aF[oyi][m2], bF[nf], acc[oyi][m2][nf], 0, 0, 0);
        }
    }
    const int kgx = lane >> 4;
#pragma unroll
    for (int nf = 0; nf < 2; ++nf) {
        const int co = wid * 32 + nf * 16 + l15;
        const float bias = b2[co];
#pragma unroll
        for (int m2 = 0; m2 < 2; ++m2)
#pragma unroll
            for (int p = 0; p < 2; ++p) {
                float v = fmaxf(fmaxf(acc[0][m2][nf][2 * p], acc[0][m2][nf][2 * p + 1]),
                                fmaxf(acc[1][m2][nf][2 * p], acc[1][m2][nf][2 * p + 1]));
                const int px = (xh * 2 + m2) * 8 + kgx * 2 + p;
                y2[((size_t)(b * 32 + rp) * 32 + px) * 128 + co] = f2b(fmaxf(v + bias, 0.f));
            }
    }
}

// ---------------- conv3 MFMA: y2 bf16 NHWC -> y3 bf16 NHWC (16,8,8,256)
__global__ __launch_bounds__(256) void k_conv3m(const ushort_t* __restrict__ y2,
                                                const ushort_t* __restrict__ wpk3,
                                                const float* __restrict__ b3,
                                                ushort_t* __restrict__ y3) {
    const int gy = blockIdx.x, gn = blockIdx.y, b = blockIdx.z;
    const int oy0 = gy * 4;
    const int tid = threadIdx.x;
    const int wid = tid >> 6, lane = tid & 63;
    const int l15 = lane & 15, kl8 = (lane >> 4) << 3;
    const int g16 = gn * 4 + wid;
    const int co = g16 * 16 + l15;

    const ushort_t* xb = y2 + (size_t)b * 32 * 32 * 128;
    const f32x4 z4 = {0.f, 0.f, 0.f, 0.f};
    f32x4 acc[4] = {z4, z4, z4, z4};

#pragma unroll 1
    for (int tap = 0; tap < 9; ++tap) {
        const int ky = tap >= 6 ? 2 : (tap >= 3 ? 1 : 0), kx = tap - ky * 3;
        const int iyA = 2 * oy0 - 1 + ky;
        const int c = 2 * l15 - 1 + kx;
        const bool cok = (c >= 0);
#pragma unroll
        for (int h = 0; h < 4; ++h) {
            const int ci0 = h * 32;
            const int kc = tap * 4 + h;
            bf16x8 aF[4];
#pragma unroll
            for (int mf = 0; mf < 4; ++mf) {
                const int iy = iyA + 2 * mf;
                bf16x8 r = {0, 0, 0, 0, 0, 0, 0, 0};
                if (cok && iy >= 0) r = *reinterpret_cast<const bf16x8*>(xb + ((size_t)iy * 32 + c) * 128 + ci0 + kl8);
                aF[mf] = r;
            }
            const bf16x8 bF = *reinterpret_cast<const bf16x8*>(wpk3 + ((size_t)(kc * 16 + g16) * 64 + lane) * 8);
#pragma unroll
            for (int mf = 0; mf < 4; ++mf)
                acc[mf] = __builtin_amdgcn_mfma_f32_16x16x32_bf16(aF[mf], bF, acc[mf], 0, 0, 0);
        }
    }
    const int kg = lane >> 4;
    const float bias = b3[co];
#pragma unroll
    for (int mp = 0; mp < 2; ++mp) {
        const int py = gy * 2 + mp;
#pragma unroll
        for (int p = 0; p < 2; ++p) {
            float v = fmaxf(fmaxf(acc[2 * mp][2 * p], acc[2 * mp][2 * p + 1]),
                            fmaxf(acc[2 * mp + 1][2 * p], acc[2 * mp + 1][2 * p + 1]));
            const int px = kg * 2 + p;
            y3[((size_t)(b * 8 + py) * 8 + px) * 256 + co] = f2b(fmaxf(v + bias, 0.f));
        }
    }
}

// ---------------- im2col for conv4: y3 bf16 NHWC -> A4 [256][2304] bf16, k = tap*256+ci
__global__ __launch_bounds__(256) void k_im2col4(const ushort_t* __restrict__ y3, ushort_t* __restrict__ A4) {
    const int m = blockIdx.x;                             // 256 blocks
    const int b = m >> 4, pix = m & 15;
    const int oy = pix >> 2, ox = pix & 3;
    const ushort_t* xb = y3 + (size_t)b * 16384;
    for (int it = threadIdx.x; it < 288; it += 256) {
        const int tap = it >> 5, ci8 = it & 31;
        const int ky = tap / 3, kx = tap - 3 * (tap / 3);
        const int iy = 2 * oy - 1 + ky, ix = 2 * ox - 1 + kx;
        bf16x8 r = {0, 0, 0, 0, 0, 0, 0, 0};
        if (iy >= 0 && ix >= 0)
            r = *reinterpret_cast<const bf16x8*>(xb + ((iy * 8 + ix) << 8) + ci8 * 8);
        *reinterpret_cast<bf16x8*>(A4 + (size_t)m * 2304 + tap * 256 + ci8 * 8) = r;
    }
}

// ---------------- conv4 GEMM + relu + mean (K-split across 4 waves, 512 blocks)
__global__ __launch_bounds__(256) void k_conv4g(const ushort_t* __restrict__ A4,
                                                const ushort_t* __restrict__ wpk4m,
                                                const float* __restrict__ b4,
                                                float* __restrict__ feats) {
    const int g16 = blockIdx.x, b = blockIdx.y;
    const int tid = threadIdx.x, wid = tid >> 6, lane = tid & 63;
    const int l15 = lane & 15, kg = lane >> 4, kl8 = kg << 3;
    const f32x4 z4 = {0.f, 0.f, 0.f, 0.f};
    f32x4 acc = z4;
    const ushort_t* arow = A4 + (size_t)(b * 16 + l15) * 2304 + kl8;
    const int kc0 = wid * 18;

#pragma unroll 3
    for (int i = 0; i < 18; ++i) {
        const int kc = kc0 + i;
        const bf16x8 aF = *reinterpret_cast<const bf16x8*>(arow + kc * 32);
        const bf16x8 bF = *reinterpret_cast<const bf16x8*>(wpk4m + ((size_t)(kc * 32 + g16) * 64 + lane) * 8);
        acc = __builtin_amdgcn_mfma_f32_16x16x32_bf16(aF, bF, acc, 0, 0, 0);
    }

    __shared__ f32x4 red[4][64];
    red[wid][lane] = acc;
    __syncthreads();
    if (wid == 0) {
        f32x4 t = red[0][lane];
        t = t + red[1][lane];
        t = t + red[2][lane];
        t = t + red[3][lane];
        const int co = g16 * 16 + l15;
        const float bias = b4[co];
        float s = fmaxf(t[0] + bias, 0.f) + fmaxf(t[1] + bias, 0.f)
                + fmaxf(t[2] + bias, 0.f) + fmaxf(t[3] + bias, 0.f);
        s += __shfl_xor(s, 16, 64);
        s += __shfl_xor(s, 32, 64);
        if (kg == 0) feats[b * 512 + co] = s * 0.0625f;
    }
}

// ---------------- head: feats -> logits -> softmax -> VLAD residual v (16, 32768)
__global__ __launch_bounds__(256) void k_head(const float* __restrict__ feats,
                                              const float* __restrict__ wv,
                                              const float* __restrict__ bv,
                                              const float* __restrict__ centroids,
                                              float* __restrict__ v) {
    const int b = blockIdx.x;
    __shared__ float sf[512];
    __shared__ float sl[64];
    __shared__ float sa[64];
    for (int i = threadIdx.x; i < 512; i += 256) sf[i] = feats[b * 512 + i];
    __syncthreads();
    if (threadIdx.x < 64) {
        const int k = threadIdx.x;
        float s = bv[k];
        for (int c = 0; c < 512; ++c) s += sf[c] * wv[(size_t)k * 512 + c];
        sl[k] = s;
    }
    __syncthreads();
    if (threadIdx.x < 64) {
        const int k = threadIdx.x;
        float m = -1e30f;
        for (int i = 0; i < 64; ++i) m = fmaxf(m, sl[i]);
        float sum = 0.f;
        for (int i = 0; i < 64; ++i) sum += __expf(sl[i] - m);
        sa[k] = __expf(sl[k] - m) / sum;
    }
    __syncthreads();
    for (int i4 = threadIdx.x * 4; i4 < 32768; i4 += 1024) {
        const int k = i4 >> 9;
        const float a_ = sa[k];
        const float4 c4 = *(const float4*)(centroids + i4);
        const float4 f4 = *(const float4*)(&sf[i4 & 511]);
        float4 o;
        o.x = a_ * (f4.x - c4.x);
        o.y = a_ * (f4.y - c4.y);
        o.z = a_ * (f4.z - c4.z);
        o.w = a_ * (f4.w - c4.w);
        *(float4*)(v + (size_t)b * 32768 + i4) = o;
    }
}

// ---------------- fc1a: K-split partial GEMV; part[ks][b][d]
__global__ __launch_bounds__(256) void k_fc1a(const float* __restrict__ v,
                                              const float* __restrict__ fw1,
                                              float* __restrict__ part) {
    const int d = blockIdx.x, ks = blockIdx.y;
    const int base = ks * 4096;
    float acc[16];
#pragma unroll
    for (int i = 0; i < 16; ++i) acc[i] = 0.f;
    const float* wrow = fw1 + (size_t)d * 32768 + base;
    const float* vb = v + base;
#pragma unroll
    for (int it = 0; it < 4; ++it) {
        const int j4 = it * 1024 + threadIdx.x * 4;
        const float4 w = *(const float4*)(wrow + j4);
#pragma unroll
        for (int b = 0; b < 16; ++b) {
            const float4 vv = *(const float4*)(vb + (size_t)b * 32768 + j4);
            acc[b] += w.x * vv.x + w.y * vv.y + w.z * vv.z + w.w * vv.w;
        }
    }
#pragma unroll
    for (int b = 0; b < 16; ++b) {
        float s = acc[b];
        for (int off = 32; off >= 1; off >>= 1) s += __shfl_down(s, off, 64);
        acc[b] = s;
    }
    __shared__ float red[4][16];
    const int wid = threadIdx.x >> 6, lane = threadIdx.x & 63;
    if (lane == 0) {
#pragma unroll
        for (int b = 0; b < 16; ++b) red[wid][b] = acc[b];
    }
    __syncthreads();
    if (threadIdx.x < 16) {
        const int b = threadIdx.x;
        part[((size_t)ks * 16 + b) * 256 + d] = red[0][b] + red[1][b] + red[2][b] + red[3][b];
    }
}

// ---------------- fc1r: reduce 8 partials + bias + relu -> d1 (16,256)
__global__ __launch_bounds__(256) void k_fc1r(const float* __restrict__ part,
                                              const float* __restrict__ fb1,
                                              float* __restrict__ d1) {
    const int i = blockIdx.x * 256 + threadIdx.x;         // 16 blocks -> 4096
    const int d = i & 255;
    float s = fb1[d];
#pragma unroll
    for (int ks = 0; ks < 8; ++ks) s += part[(size_t)ks * 4096 + i];
    d1[i] = fmaxf(s, 0.f);
}

// ---------------- fc2 + L2 norm
__global__ __launch_bounds__(256) void k_fc2(const float* __restrict__ d1,
                                             const float* __restrict__ fw2,
                                             const float* __restrict__ fb2,
                                             float* __restrict__ out) {
    const int b = blockIdx.x;
    const int dd = threadIdx.x;
    __shared__ float sd[256];
    __shared__ float sq[256];
    sd[dd] = d1[b * 256 + dd];
    __syncthreads();
    float s = fb2[dd];
    for (int j = 0; j < 256; ++j) s += sd[j] * fw2[(size_t)dd * 256 + j];
    sq[dd] = s * s;
    __syncthreads();
    for (int off = 128; off >= 1; off >>= 1) {
        if (dd < off) sq[dd] += sq[dd + off];
        __syncthreads();
    }
    const float inv = rsqrtf(sq[0]);
    out[b * 256 + dd] = s * inv;
}

extern "C" void kernel_launch(void* const* d_in, const int* in_sizes, int n_in,
                              void* d_out, int out_size, void* d_ws, size_t ws_size,
                              hipStream_t stream) {
    const float* x    = (const float*)d_in[0];
    const float* w1   = (const float*)d_in[1];
    const float* b1   = (const float*)d_in[2];
    const float* w2   = (const float*)d_in[3];
    const float* b2   = (const float*)d_in[4];
    const float* w3   = (const float*)d_in[5];
    const float* b3   = (const float*)d_in[6];
    const float* w4   = (const float*)d_in[7];
    const float* b4   = (const float*)d_in[8];
    const float* wv   = (const float*)d_in[9];
    const float* bv   = (const float*)d_in[10];
    const float* cen  = (const float*)d_in[11];
    const float* fw1  = (const float*)d_in[12];
    const float* fb1  = (const float*)d_in[13];
    const float* fw2  = (const float*)d_in[14];
    const float* fb2  = (const float*)d_in[15];
    float* out = (float*)d_out;

    char* p = (char*)d_ws;
    ushort_t* y1    = (ushort_t*)p; p += 33554432;  // 16*128*128*64 bf16
    ushort_t* wpk2  = (ushort_t*)p; p += 147456;    // 73728 bf16
    ushort_t* wpk3  = (ushort_t*)p; p += 589824;    // 294912 bf16
    ushort_t* wpk4m = (ushort_t*)p; p += 2359296;   // 1179648 bf16
    ushort_t* wpk1  = (ushort_t*)p; p += 4096;      // 2048 bf16
    ushort_t* y2    = (ushort_t*)p; p += 4194304;   // 16*32*32*128 bf16
    ushort_t* y3    = (ushort_t*)p; p += 524288;    // 16*8*8*256 bf16
    float*    feats = (float*)p;    p += 32768;     // 16*512
    float*    vbuf  = (float*)p;    p += 2097152;   // 16*32768
    float*    d1    = (float*)p;    p += 16384;     // 16*256
    ushort_t* A4    = (ushort_t*)p; p += 2359296;   // 256*2304 bf16
    float*    part  = (float*)p;    p += 131072;    // 8*16*256 f32

    k_pack1<<<1, 256, 0, stream>>>(w1, wpk1);
    k_pack2<<<36, 256, 0, stream>>>(w2, wpk2);
    k_pack3<<<144, 256, 0, stream>>>(w3, wpk3);
    k_pack4m<<<512, 256, 0, stream>>>(w4, wpk4m);
    k_conv1f<<<dim3(64, 2, 16), 256, 0, stream>>>(x, wpk1, b1, y1);
    k_conv2s<<<dim3(32, 2, 16), 256, 0, stream>>>(y1, wpk2, b2, y2);
    k_conv3m<<<dim3(4, 4, 16), 256, 0, stream>>>(y2, wpk3, b3, y3);
    k_im2col4<<<256, 256, 0, stream>>>(y3, A4);
    k_conv4g<<<dim3(32, 16), 256, 0, stream>>>(A4, wpk4m, b4, feats);
    k_head<<<16, 256, 0, stream>>>(feats, wv, bv, cen, vbuf);
    k_fc1a<<<dim3(256, 8), 256, 0, stream>>>(vbuf, fw1, part);
    k_fc1r<<<16, 256, 0, stream>>>(part, fb1, d1);
    k_fc2<<<16, 256, 0, stream>>>(d1, fw2, fb2, out);
}

// Round 16
// 148.452 us; speedup vs baseline: 1.4951x; 1.0028x over previous
//
#include <hip/hip_runtime.h>
#include <hip/hip_bf16.h>

typedef unsigned short ushort_t;
typedef short bf16x8 __attribute__((ext_vector_type(8)));
typedef float f32x4 __attribute__((ext_vector_type(4)));

__device__ __forceinline__ ushort_t f2b(float f) {
    __hip_bfloat16 h = __float2bfloat16(f);
    return *reinterpret_cast<ushort_t*>(&h);
}
__device__ __forceinline__ float b2f(short v) {
    union { unsigned int u; float f; } cv;
    cv.u = ((unsigned int)(ushort_t)v) << 16;
    return cv.f;
}

// ---------------- all weight repacks in one kernel (693 blocks)
// blocks [0,512): w4 -> wpk4m ; [512,656): w3 -> wpk3 ; [656,692): w2 -> wpk2 ; 692: w1 -> wpk1
__global__ __launch_bounds__(256) void k_packall(const float* __restrict__ w1,
                                                 const float* __restrict__ w2,
                                                 const float* __restrict__ w3,
                                                 const float* __restrict__ w4,
                                                 ushort_t* __restrict__ o1,
                                                 ushort_t* __restrict__ o2,
                                                 ushort_t* __restrict__ o3,
                                                 ushort_t* __restrict__ o4m) {
    const int bx = blockIdx.x;
    if (bx < 512) {
        // w4 (512,256,3,3) -> [kc(72)][g16(32)][lane(64)][8], K order = tap*256+ci
        const int co = bx;
        __shared__ float sw[2304];
        for (int i = threadIdx.x; i < 2304; i += 256) sw[i] = w4[(size_t)co * 2304 + i];
        __syncthreads();
        const int g = co >> 4, l15 = co & 15;
        for (int it = threadIdx.x; it < 288; it += 256) {
            const int kc = it >> 2, kg = it & 3;
            const int k0 = kc * 32 + kg * 8;
            const int tap = k0 >> 8, ci0 = k0 & 255;
            const int lane = kg * 16 + l15;
            ushort_t tmp[8];
#pragma unroll
            for (int j = 0; j < 8; ++j)
                tmp[j] = f2b(sw[(ci0 + j) * 9 + tap]);
            *(float4*)(o4m + ((size_t)(kc * 32 + g) * 64 + lane) * 8) = *(const float4*)tmp;
        }
    } else if (bx < 656) {
        // w3 (256,128,3,3) -> [kc(36)][g16(16)][lane][8], K order = tap*128+ci
        const int slot = (bx - 512) * 256 + threadIdx.x;
        const int lane = slot & 63, g = (slot >> 6) & 15, kc = slot >> 10;
        const int k0 = kc * 32 + ((lane >> 4) << 3);
        const int tap = k0 >> 7, cib = k0 & 127;
        const int ky = tap >= 6 ? 2 : (tap >= 3 ? 1 : 0), kx = tap - ky * 3;
        const int co = g * 16 + (lane & 15);
#pragma unroll
        for (int j = 0; j < 8; ++j)
            o3[slot * 8 + j] = f2b(w3[((co * 128 + cib + j) * 3 + ky) * 3 + kx]);
    } else if (bx < 692) {
        // w2 (128,64,3,3) -> K order = tap*64 + s, s -> ci = 16*(s&3)+(s>>2)
        const int slot = (bx - 656) * 256 + threadIdx.x;
        const int lane = slot & 63, g = (slot >> 6) & 7, kc = slot >> 9;
        const int k0 = kc * 32 + ((lane >> 4) << 3);
        const int tap = k0 >> 6, sb = k0 & 63;
        const int ky = tap >= 6 ? 2 : (tap >= 3 ? 1 : 0), kx = tap - ky * 3;
        const int co = g * 16 + (lane & 15);
#pragma unroll
        for (int j = 0; j < 8; ++j) {
            const int s = sb + j;
            const int ci = 16 * (s & 3) + (s >> 2);
            o2[slot * 8 + j] = f2b(w2[((co * 64 + ci) * 3 + ky) * 3 + kx]);
        }
    } else {
        // w1 (64,3,3,3) -> [nf(4)][lane(64)][8], K order k = tap*3+c
        const int slot = threadIdx.x;
        const int lane = slot & 63, nf = slot >> 6;
        const int co = nf * 16 + (lane & 15);
        const int kg = lane >> 4;
#pragma unroll
        for (int j = 0; j < 8; ++j) {
            const int k = kg * 8 + j;
            float v = 0.f;
            if (k < 27) {
                const int t = k / 3, c = k - 3 * t;
                v = w1[(co * 3 + c) * 9 + t];
            }
            o1[slot * 8 + j] = f2b(v);
        }
    }
}

// ---------------- fused conv1 (x-split): x f32 -> LDS stage -> in-LDS im2col gather -> MFMA
// -> pool+bias+relu -> y1 bf16 (permuted ch s=4*l15+nf). grid (rp=64, xh=2, b=16).
__global__ __launch_bounds__(256) void k_conv1f(const float* __restrict__ x,
                                                const ushort_t* __restrict__ wpk1,
                                                const float* __restrict__ b1,
                                                ushort_t* __restrict__ y1) {
    const int rp = blockIdx.x, xh = blockIdx.y, b = blockIdx.z;
    const int tid = threadIdx.x;
    const int wid = tid >> 6, lane = tid & 63;
    const int l15 = lane & 15, kg = lane >> 4;

    __shared__ __align__(16) ushort_t sX[3 * 9 * 260];    // 14040 B
    const float* xb = x + (size_t)b * 3 * 512 * 512;
    const int iy0 = 8 * rp - 1;
    const int ix0 = 256 * xh - 1;
#pragma unroll
    for (int c = 0; c < 3; ++c)
#pragma unroll
    for (int r = 0; r < 9; ++r) {
        const int iy = iy0 + r;
        const int ix = ix0 + tid;
        float v = 0.f;
        if (iy >= 0 && ix >= 0) v = xb[((size_t)c * 512 + iy) * 512 + ix];
        sX[(c * 9 + r) * 260 + tid] = f2b(v);
    }
    if (tid < 27) {
        const int c = tid / 9, r = tid - 9 * c;
        const int iy = iy0 + r, ix = ix0 + 256;
        float v = (iy >= 0) ? xb[((size_t)c * 512 + iy) * 512 + ix] : 0.f;
        sX[(c * 9 + r) * 260 + 256] = f2b(v);
    }
    __syncthreads();

    const int kbase = kg * 8;
#define OFFJ(J) __extension__ ({ int k_ = kbase + (J); if (k_ > 26) k_ = 26; \
        const int tap_ = k_ / 3; const int c_ = k_ - 3 * tap_; \
        const int ky_ = tap_ / 3; const int kx_ = tap_ - 3 * ky_; \
        c_ * 2340 + ky_ * 260 + kx_; })
    const int o0 = OFFJ(0), o1 = OFFJ(1), o2 = OFFJ(2), o3 = OFFJ(3);
    const int o4 = OFFJ(4), o5 = OFFJ(5), o6 = OFFJ(6), o7 = OFFJ(7);
#undef OFFJ
    const int gq = l15 >> 2;
    const int dy = (l15 >> 1) & 1, dx = l15 & 1;

    bf16x8 bF[4];
    float bias[4];
#pragma unroll
    for (int nf = 0; nf < 4; ++nf) {
        bF[nf] = *reinterpret_cast<const bf16x8*>(wpk1 + (size_t)(nf * 64 + lane) * 8);
        bias[nf] = b1[nf * 16 + l15];
    }
    const f32x4 z4 = {0.f, 0.f, 0.f, 0.f};

#pragma unroll 4
    for (int it = 0; it < 8; ++it) {
        const int fl = wid * 8 + it;
        const int g2 = fl * 4 + gq;
        const int pyl = g2 >> 6, pxl = g2 & 63;
        const int cr = 2 * pyl + dy;
        const int oxl = 2 * pxl + dx;
        const int base = cr * 520 + 2 * oxl;
        bf16x8 aF;
        aF[0] = (short)sX[base + o0];
        aF[1] = (short)sX[base + o1];
        aF[2] = (short)sX[base + o2];
        aF[3] = (short)sX[base + o3];
        aF[4] = (short)sX[base + o4];
        aF[5] = (short)sX[base + o5];
        aF[6] = (short)sX[base + o6];
        aF[7] = (short)sX[base + o7];
        f32x4 acc[4];
#pragma unroll
        for (int nf = 0; nf < 4; ++nf)
            acc[nf] = __builtin_amdgcn_mfma_f32_16x16x32_bf16(aF, bF[nf], z4, 0, 0, 0);
        const int g_out = fl * 4 + kg;
        const int pyo = g_out >> 6, pxo = xh * 64 + (g_out & 63);
        union { ushort_t u[4]; uint2 v; } pk;
#pragma unroll
        for (int nf = 0; nf < 4; ++nf) {
            float v = fmaxf(fmaxf(acc[nf][0], acc[nf][1]), fmaxf(acc[nf][2], acc[nf][3]));
            pk.u[nf] = f2b(fmaxf(v + bias[nf], 0.f));
        }
        *(uint2*)(y1 + ((size_t)(b * 128 + 2 * rp + pyo) * 128 + pxo) * 64 + 4 * l15) = pk.v;
    }
}

// ---------------- conv2 LDS-staged MFMA: y1 bf16 (permuted ch) -> y2 bf16 NHWC (16,32,32,128)
__global__ __launch_bounds__(256) void k_conv2s(const ushort_t* __restrict__ y1,
                                                const ushort_t* __restrict__ wpk2,
                                                const float* __restrict__ b2,
                                                ushort_t* __restrict__ y2) {
    const int b = blockIdx.z;
    const int xh = blockIdx.y;
    const int rp = blockIdx.x;
    const int tid = threadIdx.x;
    const int wid = tid >> 6, lane = tid & 63;
    const int l15 = lane & 15, kg = lane >> 4;

    __shared__ __align__(16) ushort_t sY[330 * 72];
    bf16x8* sYv = (bf16x8*)sY;

    const ushort_t* xb = y1 + (size_t)b * 128 * 128 * 64;
    const int iyb = 4 * rp - 1, ixb = 64 * xh - 1;
    for (int j = tid; j < 2640; j += 256) {
        const int q = j & 7;
        const int pc = j >> 3;
        const int cc = pc % 66, r = pc / 66;
        const int iy = iyb + r, ix = ixb + cc;
        bf16x8 v = {0, 0, 0, 0, 0, 0, 0, 0};
        if (iy >= 0 && ix >= 0 && ix < 128)
            v = *reinterpret_cast<const bf16x8*>(xb + ((size_t)iy * 128 + ix) * 64 + q * 8);
        sYv[pc * 9 + (q ^ ((pc >> 1) & 7))] = v;
    }
    __syncthreads();

    const f32x4 z4 = {0.f, 0.f, 0.f, 0.f};
    f32x4 acc[2][2][2];
#pragma unroll
    for (int i = 0; i < 2; ++i)
#pragma unroll
        for (int j = 0; j < 2; ++j) { acc[i][j][0] = z4; acc[i][j][1] = z4; }

#pragma unroll 1
    for (int tap = 0; tap < 9; ++tap) {
        const int ky = tap >= 6 ? 2 : (tap >= 3 ? 1 : 0), kx = tap - ky * 3;
#pragma unroll
        for (int h = 0; h < 2; ++h) {
            const int kc = tap * 2 + h;
            const int c8 = h * 4 + kg;
            bf16x8 aF[2][2];
#pragma unroll
            for (int oyi = 0; oyi < 2; ++oyi)
#pragma unroll
            for (int m2 = 0; m2 < 2; ++m2) {
                const int r = 2 * oyi + ky;
                const int cc = 2 * l15 + m2 * 32 + kx;
                const int pc = r * 66 + cc;
                aF[oyi][m2] = sYv[pc * 9 + (c8 ^ ((pc >> 1) & 7))];
            }
            bf16x8 bF[2];
#pragma unroll
            for (int nf = 0; nf < 2; ++nf)
                bF[nf] = *reinterpret_cast<const bf16x8*>(wpk2 + ((size_t)(kc * 8 + wid * 2 + nf) * 64 + lane) * 8);
#pragma unroll
            for (int oyi = 0; oyi < 2; ++oyi)
#pragma unroll
            for (int m2 = 0; m2 < 2; ++m2)
#pragma unroll
            for (int nf = 0; nf < 2; ++nf)
                acc[oyi][m2][nf] = __builtin_amdgcn_mfma_f32_16x16x32_bf16(aF[oyi][m2], bF[nf], acc[oyi][m2][nf], 0, 0, 0);
        }
    }
    const int kgx = lane >> 4;
#pragma unroll
    for (int nf = 0; nf < 2; ++nf) {
        const int co = wid * 32 + nf * 16 + l15;
        const float bias = b2[co];
#pragma unroll
        for (int m2 = 0; m2 < 2; ++m2)
#pragma unroll
            for (int p = 0; p < 2; ++p) {
                float v = fmaxf(fmaxf(acc[0][m2][nf][2 * p], acc[0][m2][nf][2 * p + 1]),
                                fmaxf(acc[1][m2][nf][2 * p], acc[1][m2][nf][2 * p + 1]));
                const int px = (xh * 2 + m2) * 8 + kgx * 2 + p;
                y2[((size_t)(b * 32 + rp) * 32 + px) * 128 + co] = f2b(fmaxf(v + bias, 0.f));
            }
    }
}

// ---------------- conv3 MFMA: y2 bf16 NHWC -> y3 bf16 NHWC (16,8,8,256)
__global__ __launch_bounds__(256) void k_conv3m(const ushort_t* __restrict__ y2,
                                                const ushort_t* __restrict__ wpk3,
                                                const float* __restrict__ b3,
                                                ushort_t* __restrict__ y3) {
    const int gy = blockIdx.x, gn = blockIdx.y, b = blockIdx.z;
    const int oy0 = gy * 4;
    const int tid = threadIdx.x;
    const int wid = tid >> 6, lane = tid & 63;
    const int l15 = lane & 15, kl8 = (lane >> 4) << 3;
    const int g16 = gn * 4 + wid;
    const int co = g16 * 16 + l15;

    const ushort_t* xb = y2 + (size_t)b * 32 * 32 * 128;
    const f32x4 z4 = {0.f, 0.f, 0.f, 0.f};
    f32x4 acc[4] = {z4, z4, z4, z4};

#pragma unroll 1
    for (int tap = 0; tap < 9; ++tap) {
        const int ky = tap >= 6 ? 2 : (tap >= 3 ? 1 : 0), kx = tap - ky * 3;
        const int iyA = 2 * oy0 - 1 + ky;
        const int c = 2 * l15 - 1 + kx;
        const bool cok = (c >= 0);
#pragma unroll
        for (int h = 0; h < 4; ++h) {
            const int ci0 = h * 32;
            const int kc = tap * 4 + h;
            bf16x8 aF[4];
#pragma unroll
            for (int mf = 0; mf < 4; ++mf) {
                const int iy = iyA + 2 * mf;
                bf16x8 r = {0, 0, 0, 0, 0, 0, 0, 0};
                if (cok && iy >= 0) r = *reinterpret_cast<const bf16x8*>(xb + ((size_t)iy * 32 + c) * 128 + ci0 + kl8);
                aF[mf] = r;
            }
            const bf16x8 bF = *reinterpret_cast<const bf16x8*>(wpk3 + ((size_t)(kc * 16 + g16) * 64 + lane) * 8);
#pragma unroll
            for (int mf = 0; mf < 4; ++mf)
                acc[mf] = __builtin_amdgcn_mfma_f32_16x16x32_bf16(aF[mf], bF, acc[mf], 0, 0, 0);
        }
    }
    const int kg = lane >> 4;
    const float bias = b3[co];
#pragma unroll
    for (int mp = 0; mp < 2; ++mp) {
        const int py = gy * 2 + mp;
#pragma unroll
        for (int p = 0; p < 2; ++p) {
            float v = fmaxf(fmaxf(acc[2 * mp][2 * p], acc[2 * mp][2 * p + 1]),
                            fmaxf(acc[2 * mp + 1][2 * p], acc[2 * mp + 1][2 * p + 1]));
            const int px = kg * 2 + p;
            y3[((size_t)(b * 8 + py) * 8 + px) * 256 + co] = f2b(fmaxf(v + bias, 0.f));
        }
    }
}

// ---------------- conv4 GEMM + relu + mean, fused im2col gather from y3 (K-split 4 waves)
__global__ __launch_bounds__(256) void k_conv4g(const ushort_t* __restrict__ y3,
                                                const ushort_t* __restrict__ wpk4m,
                                                const float* __restrict__ b4,
                                                float* __restrict__ feats) {
    const int g16 = blockIdx.x, b = blockIdx.y;
    const int tid = threadIdx.x, wid = tid >> 6, lane = tid & 63;
    const int l15 = lane & 15, kg = lane >> 4, kl8 = kg << 3;
    const int oy = l15 >> 2, ox = l15 & 3;
    const f32x4 z4 = {0.f, 0.f, 0.f, 0.f};
    f32x4 acc = z4;
    const ushort_t* yb = y3 + (size_t)b * 16384;
    const int kc0 = wid * 18;

#pragma unroll 3
    for (int i = 0; i < 18; ++i) {
        const int kc = kc0 + i;
        const int k0 = kc * 32 + kl8;
        const int tap = k0 >> 8, ci0 = k0 & 255;
        const int ky = tap / 3, kx = tap - 3 * (tap / 3);
        const int iy = 2 * oy - 1 + ky, ix = 2 * ox - 1 + kx;   // max 7, only lower bound can fail
        bf16x8 aF = {0, 0, 0, 0, 0, 0, 0, 0};
        if (iy >= 0 && ix >= 0)
            aF = *reinterpret_cast<const bf16x8*>(yb + ((iy * 8 + ix) << 8) + ci0);
        const bf16x8 bF = *reinterpret_cast<const bf16x8*>(wpk4m + ((size_t)(kc * 32 + g16) * 64 + lane) * 8);
        acc = __builtin_amdgcn_mfma_f32_16x16x32_bf16(aF, bF, acc, 0, 0, 0);
    }

    __shared__ f32x4 red[4][64];
    red[wid][lane] = acc;
    __syncthreads();
    if (wid == 0) {
        f32x4 t = red[0][lane];
        t = t + red[1][lane];
        t = t + red[2][lane];
        t = t + red[3][lane];
        const int co = g16 * 16 + l15;
        const float bias = b4[co];
        float s = fmaxf(t[0] + bias, 0.f) + fmaxf(t[1] + bias, 0.f)
                + fmaxf(t[2] + bias, 0.f) + fmaxf(t[3] + bias, 0.f);
        s += __shfl_xor(s, 16, 64);
        s += __shfl_xor(s, 32, 64);
        if (kg == 0) feats[b * 512 + co] = s * 0.0625f;
    }
}

// ---------------- head (split writes): grid (b=16, slice=8); redundant logits+softmax per block
__global__ __launch_bounds__(256) void k_head(const float* __restrict__ feats,
                                              const float* __restrict__ wv,
                                              const float* __restrict__ bv,
                                              const float* __restrict__ centroids,
                                              float* __restrict__ v) {
    const int b = blockIdx.x, sl8 = blockIdx.y;
    __shared__ float sf[512];
    __shared__ float sl[64];
    __shared__ float sa[64];
    for (int i = threadIdx.x; i < 512; i += 256) sf[i] = feats[b * 512 + i];
    __syncthreads();
    if (threadIdx.x < 64) {
        const int k = threadIdx.x;
        float s = bv[k];
        for (int c = 0; c < 512; ++c) s += sf[c] * wv[(size_t)k * 512 + c];
        sl[k] = s;
    }
    __syncthreads();
    if (threadIdx.x < 64) {
        const int k = threadIdx.x;
        float m = -1e30f;
        for (int i = 0; i < 64; ++i) m = fmaxf(m, sl[i]);
        float sum = 0.f;
        for (int i = 0; i < 64; ++i) sum += __expf(sl[i] - m);
        sa[k] = __expf(sl[k] - m) / sum;
    }
    __syncthreads();
    const int i4end = (sl8 + 1) * 4096;
    for (int i4 = sl8 * 4096 + threadIdx.x * 4; i4 < i4end; i4 += 1024) {
        const int k = i4 >> 9;
        const float a_ = sa[k];
        const float4 c4 = *(const float4*)(centroids + i4);
        const float4 f4 = *(const float4*)(&sf[i4 & 511]);
        float4 o;
        o.x = a_ * (f4.x - c4.x);
        o.y = a_ * (f4.y - c4.y);
        o.z = a_ * (f4.z - c4.z);
        o.w = a_ * (f4.w - c4.w);
        *(float4*)(v + (size_t)b * 32768 + i4) = o;
    }
}

// ---------------- fc1a: grid (dquad=64, ks=8); block = 4 d-rows, wave = K-quarter of all 4
__global__ __launch_bounds__(256) void k_fc1a(const float* __restrict__ v,
                                              const float* __restrict__ fw1,
                                              float* __restrict__ part) {
    const int d0 = blockIdx.x * 4, ks = blockIdx.y;
    const int tid = threadIdx.x, wid = tid >> 6, lane = tid & 63;
    const int base = ks * 4096 + wid * 1024;
    float acc[4][16];
#pragma unroll
    for (int dq = 0; dq < 4; ++dq)
#pragma unroll
        for (int bb = 0; bb < 16; ++bb) acc[dq][bb] = 0.f;
    const float* vb = v + base;
#pragma unroll
    for (int it = 0; it < 4; ++it) {
        const int j4 = it * 256 + lane * 4;
        float4 w[4];
#pragma unroll
        for (int dq = 0; dq < 4; ++dq)
            w[dq] = *(const float4*)(fw1 + (size_t)(d0 + dq) * 32768 + base + j4);
#pragma unroll
        for (int bb = 0; bb < 16; ++bb) {
            const float4 vv = *(const float4*)(vb + (size_t)bb * 32768 + j4);
#pragma unroll
            for (int dq = 0; dq < 4; ++dq)
                acc[dq][bb] += w[dq].x * vv.x + w[dq].y * vv.y + w[dq].z * vv.z + w[dq].w * vv.w;
        }
    }
    __shared__ float red[4][4][16];
#pragma unroll
    for (int dq = 0; dq < 4; ++dq)
#pragma unroll
        for (int bb = 0; bb < 16; ++bb) {
            float s = acc[dq][bb];
            for (int off = 32; off >= 1; off >>= 1) s += __shfl_down(s, off, 64);
            if (lane == 0) red[wid][dq][bb] = s;
        }
    __syncthreads();
    if (tid < 64) {
        const int dq = tid >> 4, bb = tid & 15;
        part[((size_t)ks * 16 + bb) * 256 + d0 + dq] =
            red[0][dq][bb] + red[1][dq][bb] + red[2][dq][bb] + red[3][dq][bb];
    }
}

// ---------------- fc2 (+fc1 reduce/bias/relu) + L2 norm
__global__ __launch_bounds__(256) void k_fc2(const float* __restrict__ part,
                                             const float* __restrict__ fb1,
                                             const float* __restrict__ fw2,
                                             const float* __restrict__ fb2,
                                             float* __restrict__ out) {
    const int b = blockIdx.x;
    const int dd = threadIdx.x;
    __shared__ float sd[256];
    __shared__ float sq[256];
    float t = fb1[dd];
#pragma unroll
    for (int ks = 0; ks < 8; ++ks) t += part[((size_t)ks * 16 + b) * 256 + dd];
    sd[dd] = fmaxf(t, 0.f);
    __syncthreads();
    float s = fb2[dd];
    for (int j = 0; j < 256; ++j) s += sd[j] * fw2[(size_t)dd * 256 + j];
    sq[dd] = s * s;
    __syncthreads();
    for (int off = 128; off >= 1; off >>= 1) {
        if (dd < off) sq[dd] += sq[dd + off];
        __syncthreads();
    }
    const float inv = rsqrtf(sq[0]);
    out[b * 256 + dd] = s * inv;
}

extern "C" void kernel_launch(void* const* d_in, const int* in_sizes, int n_in,
                              void* d_out, int out_size, void* d_ws, size_t ws_size,
                              hipStream_t stream) {
    const float* x    = (const float*)d_in[0];
    const float* w1   = (const float*)d_in[1];
    const float* b1   = (const float*)d_in[2];
    const float* w2   = (const float*)d_in[3];
    const float* b2   = (const float*)d_in[4];
    const float* w3   = (const float*)d_in[5];
    const float* b3   = (const float*)d_in[6];
    const float* w4   = (const float*)d_in[7];
    const float* b4   = (const float*)d_in[8];
    const float* wv   = (const float*)d_in[9];
    const float* bv   = (const float*)d_in[10];
    const float* cen  = (const float*)d_in[11];
    const float* fw1  = (const float*)d_in[12];
    const float* fb1  = (const float*)d_in[13];
    const float* fw2  = (const float*)d_in[14];
    const float* fb2  = (const float*)d_in[15];
    float* out = (float*)d_out;

    char* p = (char*)d_ws;
    ushort_t* y1    = (ushort_t*)p; p += 33554432;  // 16*128*128*64 bf16
    ushort_t* wpk2  = (ushort_t*)p; p += 147456;    // 73728 bf16
    ushort_t* wpk3  = (ushort_t*)p; p += 589824;    // 294912 bf16
    ushort_t* wpk4m = (ushort_t*)p; p += 2359296;   // 1179648 bf16
    ushort_t* wpk1  = (ushort_t*)p; p += 4096;      // 2048 bf16
    ushort_t* y2    = (ushort_t*)p; p += 4194304;   // 16*32*32*128 bf16
    ushort_t* y3    = (ushort_t*)p; p += 524288;    // 16*8*8*256 bf16
    float*    feats = (float*)p;    p += 32768;     // 16*512
    float*    vbuf  = (float*)p;    p += 2097152;   // 16*32768
    float*    part  = (float*)p;    p += 131072;    // 8*16*256 f32

    k_packall<<<693, 256, 0, stream>>>(w1, w2, w3, w4, wpk1, wpk2, wpk3, wpk4m);
    k_conv1f<<<dim3(64, 2, 16), 256, 0, stream>>>(x, wpk1, b1, y1);
    k_conv2s<<<dim3(32, 2, 16), 256, 0, stream>>>(y1, wpk2, b2, y2);
    k_conv3m<<<dim3(4, 4, 16), 256, 0, stream>>>(y2, wpk3, b3, y3);
    k_conv4g<<<dim3(32, 16), 256, 0, stream>>>(y3, wpk4m, b4, feats);
    k_head<<<dim3(16, 8), 256, 0, stream>>>(feats, wv, bv, cen, vbuf);
    k_fc1a<<<dim3(64, 8), 256, 0, stream>>>(vbuf, fw1, part);
    k_fc2<<<16, 256, 0, stream>>>(part, fb1, fw2, fb2, out);
}

// Round 17
// 115.382 us; speedup vs baseline: 1.9236x; 1.2866x over previous
//
#include <hip/hip_runtime.h>
#include <hip/hip_bf16.h>

typedef unsigned short ushort_t;
typedef short bf16x8 __attribute__((ext_vector_type(8)));
typedef float f32x4 __attribute__((ext_vector_type(4)));

__device__ __forceinline__ ushort_t f2b(float f) {
    __hip_bfloat16 h = __float2bfloat16(f);
    return *reinterpret_cast<ushort_t*>(&h);
}
__device__ __forceinline__ float b2f(short v) {
    union { unsigned int u; float f; } cv;
    cv.u = ((unsigned int)(ushort_t)v) << 16;
    return cv.f;
}

// ---------------- all weight repacks in one kernel (693 blocks)
__global__ __launch_bounds__(256) void k_packall(const float* __restrict__ w1,
                                                 const float* __restrict__ w2,
                                                 const float* __restrict__ w3,
                                                 const float* __restrict__ w4,
                                                 ushort_t* __restrict__ o1,
                                                 ushort_t* __restrict__ o2,
                                                 ushort_t* __restrict__ o3,
                                                 ushort_t* __restrict__ o4m) {
    const int bx = blockIdx.x;
    if (bx < 512) {
        const int co = bx;
        __shared__ float sw[2304];
        for (int i = threadIdx.x; i < 2304; i += 256) sw[i] = w4[(size_t)co * 2304 + i];
        __syncthreads();
        const int g = co >> 4, l15 = co & 15;
        for (int it = threadIdx.x; it < 288; it += 256) {
            const int kc = it >> 2, kg = it & 3;
            const int k0 = kc * 32 + kg * 8;
            const int tap = k0 >> 8, ci0 = k0 & 255;
            const int lane = kg * 16 + l15;
            ushort_t tmp[8];
#pragma unroll
            for (int j = 0; j < 8; ++j)
                tmp[j] = f2b(sw[(ci0 + j) * 9 + tap]);
            *(float4*)(o4m + ((size_t)(kc * 32 + g) * 64 + lane) * 8) = *(const float4*)tmp;
        }
    } else if (bx < 656) {
        const int slot = (bx - 512) * 256 + threadIdx.x;
        const int lane = slot & 63, g = (slot >> 6) & 15, kc = slot >> 10;
        const int k0 = kc * 32 + ((lane >> 4) << 3);
        const int tap = k0 >> 7, cib = k0 & 127;
        const int ky = tap >= 6 ? 2 : (tap >= 3 ? 1 : 0), kx = tap - ky * 3;
        const int co = g * 16 + (lane & 15);
#pragma unroll
        for (int j = 0; j < 8; ++j)
            o3[slot * 8 + j] = f2b(w3[((co * 128 + cib + j) * 3 + ky) * 3 + kx]);
    } else if (bx < 692) {
        const int slot = (bx - 656) * 256 + threadIdx.x;
        const int lane = slot & 63, g = (slot >> 6) & 7, kc = slot >> 9;
        const int k0 = kc * 32 + ((lane >> 4) << 3);
        const int tap = k0 >> 6, sb = k0 & 63;
        const int ky = tap >= 6 ? 2 : (tap >= 3 ? 1 : 0), kx = tap - ky * 3;
        const int co = g * 16 + (lane & 15);
#pragma unroll
        for (int j = 0; j < 8; ++j) {
            const int s = sb + j;
            const int ci = 16 * (s & 3) + (s >> 2);
            o2[slot * 8 + j] = f2b(w2[((co * 64 + ci) * 3 + ky) * 3 + kx]);
        }
    } else {
        const int slot = threadIdx.x;
        const int lane = slot & 63, nf = slot >> 6;
        const int co = nf * 16 + (lane & 15);
        const int kg = lane >> 4;
#pragma unroll
        for (int j = 0; j < 8; ++j) {
            const int k = kg * 8 + j;
            float v = 0.f;
            if (k < 27) {
                const int t = k / 3, c = k - 3 * t;
                v = w1[(co * 3 + c) * 9 + t];
            }
            o1[slot * 8 + j] = f2b(v);
        }
    }
}

// ---------------- fused conv1 (x-split)
__global__ __launch_bounds__(256) void k_conv1f(const float* __restrict__ x,
                                                const ushort_t* __restrict__ wpk1,
                                                const float* __restrict__ b1,
                                                ushort_t* __restrict__ y1) {
    const int rp = blockIdx.x, xh = blockIdx.y, b = blockIdx.z;
    const int tid = threadIdx.x;
    const int wid = tid >> 6, lane = tid & 63;
    const int l15 = lane & 15, kg = lane >> 4;

    __shared__ __align__(16) ushort_t sX[3 * 9 * 260];    // 14040 B
    const float* xb = x + (size_t)b * 3 * 512 * 512;
    const int iy0 = 8 * rp - 1;
    const int ix0 = 256 * xh - 1;
#pragma unroll
    for (int c = 0; c < 3; ++c)
#pragma unroll
    for (int r = 0; r < 9; ++r) {
        const int iy = iy0 + r;
        const int ix = ix0 + tid;
        float v = 0.f;
        if (iy >= 0 && ix >= 0) v = xb[((size_t)c * 512 + iy) * 512 + ix];
        sX[(c * 9 + r) * 260 + tid] = f2b(v);
    }
    if (tid < 27) {
        const int c = tid / 9, r = tid - 9 * c;
        const int iy = iy0 + r, ix = ix0 + 256;
        float v = (iy >= 0) ? xb[((size_t)c * 512 + iy) * 512 + ix] : 0.f;
        sX[(c * 9 + r) * 260 + 256] = f2b(v);
    }
    __syncthreads();

    const int kbase = kg * 8;
#define OFFJ(J) __extension__ ({ int k_ = kbase + (J); if (k_ > 26) k_ = 26; \
        const int tap_ = k_ / 3; const int c_ = k_ - 3 * tap_; \
        const int ky_ = tap_ / 3; const int kx_ = tap_ - 3 * ky_; \
        c_ * 2340 + ky_ * 260 + kx_; })
    const int o0 = OFFJ(0), o1 = OFFJ(1), o2 = OFFJ(2), o3 = OFFJ(3);
    const int o4 = OFFJ(4), o5 = OFFJ(5), o6 = OFFJ(6), o7 = OFFJ(7);
#undef OFFJ
    const int gq = l15 >> 2;
    const int dy = (l15 >> 1) & 1, dx = l15 & 1;

    bf16x8 bF[4];
    float bias[4];
#pragma unroll
    for (int nf = 0; nf < 4; ++nf) {
        bF[nf] = *reinterpret_cast<const bf16x8*>(wpk1 + (size_t)(nf * 64 + lane) * 8);
        bias[nf] = b1[nf * 16 + l15];
    }
    const f32x4 z4 = {0.f, 0.f, 0.f, 0.f};

#pragma unroll 4
    for (int it = 0; it < 8; ++it) {
        const int fl = wid * 8 + it;
        const int g2 = fl * 4 + gq;
        const int pyl = g2 >> 6, pxl = g2 & 63;
        const int cr = 2 * pyl + dy;
        const int oxl = 2 * pxl + dx;
        const int base = cr * 520 + 2 * oxl;
        bf16x8 aF;
        aF[0] = (short)sX[base + o0];
        aF[1] = (short)sX[base + o1];
        aF[2] = (short)sX[base + o2];
        aF[3] = (short)sX[base + o3];
        aF[4] = (short)sX[base + o4];
        aF[5] = (short)sX[base + o5];
        aF[6] = (short)sX[base + o6];
        aF[7] = (short)sX[base + o7];
        f32x4 acc[4];
#pragma unroll
        for (int nf = 0; nf < 4; ++nf)
            acc[nf] = __builtin_amdgcn_mfma_f32_16x16x32_bf16(aF, bF[nf], z4, 0, 0, 0);
        const int g_out = fl * 4 + kg;
        const int pyo = g_out >> 6, pxo = xh * 64 + (g_out & 63);
        union { ushort_t u[4]; uint2 v; } pk;
#pragma unroll
        for (int nf = 0; nf < 4; ++nf) {
            float v = fmaxf(fmaxf(acc[nf][0], acc[nf][1]), fmaxf(acc[nf][2], acc[nf][3]));
            pk.u[nf] = f2b(fmaxf(v + bias[nf], 0.f));
        }
        *(uint2*)(y1 + ((size_t)(b * 128 + 2 * rp + pyo) * 128 + pxo) * 64 + 4 * l15) = pk.v;
    }
}

// ---------------- conv2 LDS-staged MFMA
__global__ __launch_bounds__(256) void k_conv2s(const ushort_t* __restrict__ y1,
                                                const ushort_t* __restrict__ wpk2,
                                                const float* __restrict__ b2,
                                                ushort_t* __restrict__ y2) {
    const int b = blockIdx.z;
    const int xh = blockIdx.y;
    const int rp = blockIdx.x;
    const int tid = threadIdx.x;
    const int wid = tid >> 6, lane = tid & 63;
    const int l15 = lane & 15, kg = lane >> 4;

    __shared__ __align__(16) ushort_t sY[330 * 72];
    bf16x8* sYv = (bf16x8*)sY;

    const ushort_t* xb = y1 + (size_t)b * 128 * 128 * 64;
    const int iyb = 4 * rp - 1, ixb = 64 * xh - 1;
    for (int j = tid; j < 2640; j += 256) {
        const int q = j & 7;
        const int pc = j >> 3;
        const int cc = pc % 66, r = pc / 66;
        const int iy = iyb + r, ix = ixb + cc;
        bf16x8 v = {0, 0, 0, 0, 0, 0, 0, 0};
        if (iy >= 0 && ix >= 0 && ix < 128)
            v = *reinterpret_cast<const bf16x8*>(xb + ((size_t)iy * 128 + ix) * 64 + q * 8);
        sYv[pc * 9 + (q ^ ((pc >> 1) & 7))] = v;
    }
    __syncthreads();

    const f32x4 z4 = {0.f, 0.f, 0.f, 0.f};
    f32x4 acc[2][2][2];
#pragma unroll
    for (int i = 0; i < 2; ++i)
#pragma unroll
        for (int j = 0; j < 2; ++j) { acc[i][j][0] = z4; acc[i][j][1] = z4; }

#pragma unroll 1
    for (int tap = 0; tap < 9; ++tap) {
        const int ky = tap >= 6 ? 2 : (tap >= 3 ? 1 : 0), kx = tap - ky * 3;
#pragma unroll
        for (int h = 0; h < 2; ++h) {
            const int kc = tap * 2 + h;
            const int c8 = h * 4 + kg;
            bf16x8 aF[2][2];
#pragma unroll
            for (int oyi = 0; oyi < 2; ++oyi)
#pragma unroll
            for (int m2 = 0; m2 < 2; ++m2) {
                const int r = 2 * oyi + ky;
                const int cc = 2 * l15 + m2 * 32 + kx;
                const int pc = r * 66 + cc;
                aF[oyi][m2] = sYv[pc * 9 + (c8 ^ ((pc >> 1) & 7))];
            }
            bf16x8 bF[2];
#pragma unroll
            for (int nf = 0; nf < 2; ++nf)
                bF[nf] = *reinterpret_cast<const bf16x8*>(wpk2 + ((size_t)(kc * 8 + wid * 2 + nf) * 64 + lane) * 8);
#pragma unroll
            for (int oyi = 0; oyi < 2; ++oyi)
#pragma unroll
            for (int m2 = 0; m2 < 2; ++m2)
#pragma unroll
            for (int nf = 0; nf < 2; ++nf)
                acc[oyi][m2][nf] = __builtin_amdgcn_mfma_f32_16x16x32_bf16(aF[oyi][m2], bF[nf], acc[oyi][m2][nf], 0, 0, 0);
        }
    }
    const int kgx = lane >> 4;
#pragma unroll
    for (int nf = 0; nf < 2; ++nf) {
        const int co = wid * 32 + nf * 16 + l15;
        const float bias = b2[co];
#pragma unroll
        for (int m2 = 0; m2 < 2; ++m2)
#pragma unroll
            for (int p = 0; p < 2; ++p) {
                float v = fmaxf(fmaxf(acc[0][m2][nf][2 * p], acc[0][m2][nf][2 * p + 1]),
                                fmaxf(acc[1][m2][nf][2 * p], acc[1][m2][nf][2 * p + 1]));
                const int px = (xh * 2 + m2) * 8 + kgx * 2 + p;
                y2[((size_t)(b * 32 + rp) * 32 + px) * 128 + co] = f2b(fmaxf(v + bias, 0.f));
            }
    }
}

// ---------------- conv3 MFMA
__global__ __launch_bounds__(256) void k_conv3m(const ushort_t* __restrict__ y2,
                                                const ushort_t* __restrict__ wpk3,
                                                const float* __restrict__ b3,
                                                ushort_t* __restrict__ y3) {
    const int gy = blockIdx.x, gn = blockIdx.y, b = blockIdx.z;
    const int oy0 = gy * 4;
    const int tid = threadIdx.x;
    const int wid = tid >> 6, lane = tid & 63;
    const int l15 = lane & 15, kl8 = (lane >> 4) << 3;
    const int g16 = gn * 4 + wid;
    const int co = g16 * 16 + l15;

    const ushort_t* xb = y2 + (size_t)b * 32 * 32 * 128;
    const f32x4 z4 = {0.f, 0.f, 0.f, 0.f};
    f32x4 acc[4] = {z4, z4, z4, z4};

#pragma unroll 1
    for (int tap = 0; tap < 9; ++tap) {
        const int ky = tap >= 6 ? 2 : (tap >= 3 ? 1 : 0), kx = tap - ky * 3;
        const int iyA = 2 * oy0 - 1 + ky;
        const int c = 2 * l15 - 1 + kx;
        const bool cok = (c >= 0);
#pragma unroll
        for (int h = 0; h < 4; ++h) {
            const int ci0 = h * 32;
            const int kc = tap * 4 + h;
            bf16x8 aF[4];
#pragma unroll
            for (int mf = 0; mf < 4; ++mf) {
                const int iy = iyA + 2 * mf;
                bf16x8 r = {0, 0, 0, 0, 0, 0, 0, 0};
                if (cok && iy >= 0) r = *reinterpret_cast<const bf16x8*>(xb + ((size_t)iy * 32 + c) * 128 + ci0 + kl8);
                aF[mf] = r;
            }
            const bf16x8 bF = *reinterpret_cast<const bf16x8*>(wpk3 + ((size_t)(kc * 16 + g16) * 64 + lane) * 8);
#pragma unroll
            for (int mf = 0; mf < 4; ++mf)
                acc[mf] = __builtin_amdgcn_mfma_f32_16x16x32_bf16(aF[mf], bF, acc[mf], 0, 0, 0);
        }
    }
    const int kg = lane >> 4;
    const float bias = b3[co];
#pragma unroll
    for (int mp = 0; mp < 2; ++mp) {
        const int py = gy * 2 + mp;
#pragma unroll
        for (int p = 0; p < 2; ++p) {
            float v = fmaxf(fmaxf(acc[2 * mp][2 * p], acc[2 * mp][2 * p + 1]),
                            fmaxf(acc[2 * mp + 1][2 * p], acc[2 * mp + 1][2 * p + 1]));
            const int px = kg * 2 + p;
            y3[((size_t)(b * 8 + py) * 8 + px) * 256 + co] = f2b(fmaxf(v + bias, 0.f));
        }
    }
}

// ---------------- conv4 GEMM + relu + mean, fused im2col gather from y3 (K-split 4 waves)
__global__ __launch_bounds__(256) void k_conv4g(const ushort_t* __restrict__ y3,
                                                const ushort_t* __restrict__ wpk4m,
                                                const float* __restrict__ b4,
                                                float* __restrict__ feats) {
    const int g16 = blockIdx.x, b = blockIdx.y;
    const int tid = threadIdx.x, wid = tid >> 6, lane = tid & 63;
    const int l15 = lane & 15, kg = lane >> 4, kl8 = kg << 3;
    const int oy = l15 >> 2, ox = l15 & 3;
    const f32x4 z4 = {0.f, 0.f, 0.f, 0.f};
    f32x4 acc = z4;
    const ushort_t* yb = y3 + (size_t)b * 16384;
    const int kc0 = wid * 18;

#pragma unroll 3
    for (int i = 0; i < 18; ++i) {
        const int kc = kc0 + i;
        const int k0 = kc * 32 + kl8;
        const int tap = k0 >> 8, ci0 = k0 & 255;
        const int ky = tap / 3, kx = tap - 3 * (tap / 3);
        const int iy = 2 * oy - 1 + ky, ix = 2 * ox - 1 + kx;
        bf16x8 aF = {0, 0, 0, 0, 0, 0, 0, 0};
        if (iy >= 0 && ix >= 0)
            aF = *reinterpret_cast<const bf16x8*>(yb + ((iy * 8 + ix) << 8) + ci0);
        const bf16x8 bF = *reinterpret_cast<const bf16x8*>(wpk4m + ((size_t)(kc * 32 + g16) * 64 + lane) * 8);
        acc = __builtin_amdgcn_mfma_f32_16x16x32_bf16(aF, bF, acc, 0, 0, 0);
    }

    __shared__ f32x4 red[4][64];
    red[wid][lane] = acc;
    __syncthreads();
    if (wid == 0) {
        f32x4 t = red[0][lane];
        t = t + red[1][lane];
        t = t + red[2][lane];
        t = t + red[3][lane];
        const int co = g16 * 16 + l15;
        const float bias = b4[co];
        float s = fmaxf(t[0] + bias, 0.f) + fmaxf(t[1] + bias, 0.f)
                + fmaxf(t[2] + bias, 0.f) + fmaxf(t[3] + bias, 0.f);
        s += __shfl_xor(s, 16, 64);
        s += __shfl_xor(s, 32, 64);
        if (kg == 0) feats[b * 512 + co] = s * 0.0625f;
    }
}

// ---------------- head (split writes): grid (b=16, slice=8)
__global__ __launch_bounds__(256) void k_head(const float* __restrict__ feats,
                                              const float* __restrict__ wv,
                                              const float* __restrict__ bv,
                                              const float* __restrict__ centroids,
                                              float* __restrict__ v) {
    const int b = blockIdx.x, sl8 = blockIdx.y;
    __shared__ float sf[512];
    __shared__ float sl[64];
    __shared__ float sa[64];
    for (int i = threadIdx.x; i < 512; i += 256) sf[i] = feats[b * 512 + i];
    __syncthreads();
    if (threadIdx.x < 64) {
        const int k = threadIdx.x;
        float s = bv[k];
        for (int c = 0; c < 512; ++c) s += sf[c] * wv[(size_t)k * 512 + c];
        sl[k] = s;
    }
    __syncthreads();
    if (threadIdx.x < 64) {
        const int k = threadIdx.x;
        float m = -1e30f;
        for (int i = 0; i < 64; ++i) m = fmaxf(m, sl[i]);
        float sum = 0.f;
        for (int i = 0; i < 64; ++i) sum += __expf(sl[i] - m);
        sa[k] = __expf(sl[k] - m) / sum;
    }
    __syncthreads();
    const int i4end = (sl8 + 1) * 4096;
    for (int i4 = sl8 * 4096 + threadIdx.x * 4; i4 < i4end; i4 += 1024) {
        const int k = i4 >> 9;
        const float a_ = sa[k];
        const float4 c4 = *(const float4*)(centroids + i4);
        const float4 f4 = *(const float4*)(&sf[i4 & 511]);
        float4 o;
        o.x = a_ * (f4.x - c4.x);
        o.y = a_ * (f4.y - c4.y);
        o.z = a_ * (f4.z - c4.z);
        o.w = a_ * (f4.w - c4.w);
        *(float4*)(v + (size_t)b * 32768 + i4) = o;
    }
}

// ---------------- fc1 MFMA: d1_part = v[16 x 32768] @ fw1^T[32768 x 256], K-split
// grid (g16=16, by=64); block covers 16 kc steps (4 waves x 4); inline fp32->bf16 cvt
__global__ __launch_bounds__(256) void k_fc1m(const float* __restrict__ v,
                                              const float* __restrict__ fw1,
                                              float* __restrict__ part) {
    const int g16 = blockIdx.x, by = blockIdx.y;
    const int tid = threadIdx.x, wid = tid >> 6, lane = tid & 63;
    const int l15 = lane & 15, kg = lane >> 4;
    const f32x4 z4 = {0.f, 0.f, 0.f, 0.f};
    f32x4 acc = z4;
    const float* vrow = v + (size_t)l15 * 32768;                   // batch = l15
    const float* wrow = fw1 + (size_t)(g16 * 16 + l15) * 32768;    // d = g16*16+l15
    const int kc0 = by * 16 + wid * 4;

#pragma unroll
    for (int i = 0; i < 4; ++i) {
        const int j0 = (kc0 + i) * 32 + kg * 8;
        const float4 va = *(const float4*)(vrow + j0);
        const float4 vb = *(const float4*)(vrow + j0 + 4);
        const float4 wa = *(const float4*)(wrow + j0);
        const float4 wb = *(const float4*)(wrow + j0 + 4);
        bf16x8 aF, bF;
        aF[0] = (short)f2b(va.x); aF[1] = (short)f2b(va.y);
        aF[2] = (short)f2b(va.z); aF[3] = (short)f2b(va.w);
        aF[4] = (short)f2b(vb.x); aF[5] = (short)f2b(vb.y);
        aF[6] = (short)f2b(vb.z); aF[7] = (short)f2b(vb.w);
        bF[0] = (short)f2b(wa.x); bF[1] = (short)f2b(wa.y);
        bF[2] = (short)f2b(wa.z); bF[3] = (short)f2b(wa.w);
        bF[4] = (short)f2b(wb.x); bF[5] = (short)f2b(wb.y);
        bF[6] = (short)f2b(wb.z); bF[7] = (short)f2b(wb.w);
        acc = __builtin_amdgcn_mfma_f32_16x16x32_bf16(aF, bF, acc, 0, 0, 0);
    }

    __shared__ f32x4 red[4][64];
    red[wid][lane] = acc;
    __syncthreads();
    if (wid == 0) {
        f32x4 t = red[0][lane];
        t = t + red[1][lane];
        t = t + red[2][lane];
        t = t + red[3][lane];
        // C layout: col = l15 (d-local), row = kg*4 + r (batch)
#pragma unroll
        for (int r = 0; r < 4; ++r)
            part[((size_t)by * 16 + (kg * 4 + r)) * 256 + g16 * 16 + l15] = t[r];
    }
}

// ---------------- fc2 (+fc1 reduce/bias/relu) + L2 norm; 64 K-partials
__global__ __launch_bounds__(256) void k_fc2(const float* __restrict__ part,
                                             const float* __restrict__ fb1,
                                             const float* __restrict__ fw2,
                                             const float* __restrict__ fb2,
                                             float* __restrict__ out) {
    const int b = blockIdx.x;
    const int dd = threadIdx.x;
    __shared__ float sd[256];
    __shared__ float sq[256];
    float t = fb1[dd];
#pragma unroll 8
    for (int ks = 0; ks < 64; ++ks) t += part[((size_t)ks * 16 + b) * 256 + dd];
    sd[dd] = fmaxf(t, 0.f);
    __syncthreads();
    float s = fb2[dd];
    for (int j = 0; j < 256; ++j) s += sd[j] * fw2[(size_t)dd * 256 + j];
    sq[dd] = s * s;
    __syncthreads();
    for (int off = 128; off >= 1; off >>= 1) {
        if (dd < off) sq[dd] += sq[dd + off];
        __syncthreads();
    }
    const float inv = rsqrtf(sq[0]);
    out[b * 256 + dd] = s * inv;
}

extern "C" void kernel_launch(void* const* d_in, const int* in_sizes, int n_in,
                              void* d_out, int out_size, void* d_ws, size_t ws_size,
                              hipStream_t stream) {
    const float* x    = (const float*)d_in[0];
    const float* w1   = (const float*)d_in[1];
    const float* b1   = (const float*)d_in[2];
    const float* w2   = (const float*)d_in[3];
    const float* b2   = (const float*)d_in[4];
    const float* w3   = (const float*)d_in[5];
    const float* b3   = (const float*)d_in[6];
    const float* w4   = (const float*)d_in[7];
    const float* b4   = (const float*)d_in[8];
    const float* wv   = (const float*)d_in[9];
    const float* bv   = (const float*)d_in[10];
    const float* cen  = (const float*)d_in[11];
    const float* fw1  = (const float*)d_in[12];
    const float* fb1  = (const float*)d_in[13];
    const float* fw2  = (const float*)d_in[14];
    const float* fb2  = (const float*)d_in[15];
    float* out = (float*)d_out;

    char* p = (char*)d_ws;
    ushort_t* y1    = (ushort_t*)p; p += 33554432;  // 16*128*128*64 bf16
    ushort_t* wpk2  = (ushort_t*)p; p += 147456;    // 73728 bf16
    ushort_t* wpk3  = (ushort_t*)p; p += 589824;    // 294912 bf16
    ushort_t* wpk4m = (ushort_t*)p; p += 2359296;   // 1179648 bf16
    ushort_t* wpk1  = (ushort_t*)p; p += 4096;      // 2048 bf16
    ushort_t* y2    = (ushort_t*)p; p += 4194304;   // 16*32*32*128 bf16
    ushort_t* y3    = (ushort_t*)p; p += 524288;    // 16*8*8*256 bf16
    float*    feats = (float*)p;    p += 32768;     // 16*512
    float*    vbuf  = (float*)p;    p += 2097152;   // 16*32768
    float*    part  = (float*)p;    p += 1048576;   // 64*16*256 f32

    k_packall<<<693, 256, 0, stream>>>(w1, w2, w3, w4, wpk1, wpk2, wpk3, wpk4m);
    k_conv1f<<<dim3(64, 2, 16), 256, 0, stream>>>(x, wpk1, b1, y1);
    k_conv2s<<<dim3(32, 2, 16), 256, 0, stream>>>(y1, wpk2, b2, y2);
    k_conv3m<<<dim3(4, 4, 16), 256, 0, stream>>>(y2, wpk3, b3, y3);
    k_conv4g<<<dim3(32, 16), 256, 0, stream>>>(y3, wpk4m, b4, feats);
    k_head<<<dim3(16, 8), 256, 0, stream>>>(feats, wv, bv, cen, vbuf);
    k_fc1m<<<dim3(16, 64), 256, 0, stream>>>(vbuf, fw1, part);
    k_fc2<<<16, 256, 0, stream>>>(part, fb1, fw2, fb2, out);
}

// Round 18
// 111.839 us; speedup vs baseline: 1.9845x; 1.0317x over previous
//
#include <hip/hip_runtime.h>
#include <hip/hip_bf16.h>

typedef unsigned short ushort_t;
typedef short bf16x8 __attribute__((ext_vector_type(8)));
typedef float f32x4 __attribute__((ext_vector_type(4)));

__device__ __forceinline__ ushort_t f2b(float f) {
    __hip_bfloat16 h = __float2bfloat16(f);
    return *reinterpret_cast<ushort_t*>(&h);
}
__device__ __forceinline__ float b2f(short v) {
    union { unsigned int u; float f; } cv;
    cv.u = ((unsigned int)(ushort_t)v) << 16;
    return cv.f;
}

// ---------------- all weight repacks in one kernel (693 blocks)
// w1 k-order (conv1): k<24: ky=k>>3, q=k&7, kx=q/3, c=q%3 ; k=24..26: (ky=k-24, kx=2, c=2); k>=27: 0
__global__ __launch_bounds__(256) void k_packall(const float* __restrict__ w1,
                                                 const float* __restrict__ w2,
                                                 const float* __restrict__ w3,
                                                 const float* __restrict__ w4,
                                                 ushort_t* __restrict__ o1,
                                                 ushort_t* __restrict__ o2,
                                                 ushort_t* __restrict__ o3,
                                                 ushort_t* __restrict__ o4m) {
    const int bx = blockIdx.x;
    if (bx < 512) {
        const int co = bx;
        __shared__ float sw[2304];
        for (int i = threadIdx.x; i < 2304; i += 256) sw[i] = w4[(size_t)co * 2304 + i];
        __syncthreads();
        const int g = co >> 4, l15 = co & 15;
        for (int it = threadIdx.x; it < 288; it += 256) {
            const int kc = it >> 2, kg = it & 3;
            const int k0 = kc * 32 + kg * 8;
            const int tap = k0 >> 8, ci0 = k0 & 255;
            const int lane = kg * 16 + l15;
            ushort_t tmp[8];
#pragma unroll
            for (int j = 0; j < 8; ++j)
                tmp[j] = f2b(sw[(ci0 + j) * 9 + tap]);
            *(float4*)(o4m + ((size_t)(kc * 32 + g) * 64 + lane) * 8) = *(const float4*)tmp;
        }
    } else if (bx < 656) {
        const int slot = (bx - 512) * 256 + threadIdx.x;
        const int lane = slot & 63, g = (slot >> 6) & 15, kc = slot >> 10;
        const int k0 = kc * 32 + ((lane >> 4) << 3);
        const int tap = k0 >> 7, cib = k0 & 127;
        const int ky = tap >= 6 ? 2 : (tap >= 3 ? 1 : 0), kx = tap - ky * 3;
        const int co = g * 16 + (lane & 15);
#pragma unroll
        for (int j = 0; j < 8; ++j)
            o3[slot * 8 + j] = f2b(w3[((co * 128 + cib + j) * 3 + ky) * 3 + kx]);
    } else if (bx < 692) {
        const int slot = (bx - 656) * 256 + threadIdx.x;
        const int lane = slot & 63, g = (slot >> 6) & 7, kc = slot >> 9;
        const int k0 = kc * 32 + ((lane >> 4) << 3);
        const int tap = k0 >> 6, sb = k0 & 63;
        const int ky = tap >= 6 ? 2 : (tap >= 3 ? 1 : 0), kx = tap - ky * 3;
        const int co = g * 16 + (lane & 15);
#pragma unroll
        for (int j = 0; j < 8; ++j) {
            const int s = sb + j;
            const int ci = 16 * (s & 3) + (s >> 2);
            o2[slot * 8 + j] = f2b(w2[((co * 64 + ci) * 3 + ky) * 3 + kx]);
        }
    } else {
        const int slot = threadIdx.x;
        const int lane = slot & 63, nf = slot >> 6;
        const int co = nf * 16 + (lane & 15);
        const int kg = lane >> 4;
#pragma unroll
        for (int j = 0; j < 8; ++j) {
            const int k = kg * 8 + j;
            float v = 0.f;
            if (k < 24) {
                const int ky = k >> 3, q = k & 7;
                const int kx = q / 3, c = q - 3 * kx;
                v = w1[(co * 3 + c) * 9 + ky * 3 + kx];
            } else if (k < 27) {
                const int ky = k - 24;
                v = w1[(co * 3 + 2) * 9 + ky * 3 + 2];
            }
            o1[slot * 8 + j] = f2b(v);
        }
    }
}

// ---------------- fused conv1 (x-split, contiguous-gather LDS layout)
// LDS tile: [r(9)][ix'(258)][c(3)] shorts, row stride 776 (13968 B).
// Lane kg<3 A-frag = 8 contiguous shorts at (2*cr+kg)*776 + 6*oxl; kg3 = 3 u16 at +8.
__global__ __launch_bounds__(256) void k_conv1f(const float* __restrict__ x,
                                                const ushort_t* __restrict__ wpk1,
                                                const float* __restrict__ b1,
                                                ushort_t* __restrict__ y1) {
    const int rp = blockIdx.x, xh = blockIdx.y, b = blockIdx.z;
    const int tid = threadIdx.x;
    const int wid = tid >> 6, lane = tid & 63;
    const int l15 = lane & 15, kg = lane >> 4;

    __shared__ __align__(16) ushort_t sX[9 * 776];        // 13968 B
    const float* xb = x + (size_t)b * 3 * 512 * 512;
    const int iy0 = 8 * rp - 1;
    const int ix0 = 256 * xh - 1;
#pragma unroll
    for (int c = 0; c < 3; ++c)
#pragma unroll
    for (int r = 0; r < 9; ++r) {
        const int iy = iy0 + r;
        const int ix = ix0 + tid;
        float v = 0.f;
        if (iy >= 0 && ix >= 0) v = xb[((size_t)c * 512 + iy) * 512 + ix];
        sX[r * 776 + tid * 3 + c] = f2b(v);
    }
    if (tid < 27) {                                       // ix' = 256 tail
        const int c = tid / 9, r = tid - 9 * c;
        const int iy = iy0 + r, ix = ix0 + 256;
        float v = (iy >= 0) ? xb[((size_t)c * 512 + iy) * 512 + ix] : 0.f;
        sX[r * 776 + 256 * 3 + c] = f2b(v);
    }
    __syncthreads();

    const int gq = l15 >> 2;
    const int dy = (l15 >> 1) & 1, dx = l15 & 1;

    bf16x8 bF[4];
    float bias[4];
#pragma unroll
    for (int nf = 0; nf < 4; ++nf) {
        bF[nf] = *reinterpret_cast<const bf16x8*>(wpk1 + (size_t)(nf * 64 + lane) * 8);
        bias[nf] = b1[nf * 16 + l15];
    }
    const f32x4 z4 = {0.f, 0.f, 0.f, 0.f};

#pragma unroll 4
    for (int it = 0; it < 8; ++it) {
        const int fl = wid * 8 + it;
        const int g2 = fl * 4 + gq;
        const int pyl = g2 >> 6, pxl = g2 & 63;
        const int cr = 2 * pyl + dy;
        const int oxl = 2 * pxl + dx;
        bf16x8 aF;
        if (kg < 3) {
            const int ba = (2 * cr + kg) * 776 + 6 * oxl; // even -> 4B-aligned bytes
            const unsigned int* pu = (const unsigned int*)(sX + ba);
            union { unsigned int u[4]; bf16x8 v; } cvt;
            cvt.u[0] = pu[0]; cvt.u[1] = pu[1]; cvt.u[2] = pu[2]; cvt.u[3] = pu[3];
            aF = cvt.v;
        } else {
            const int b0 = 2 * cr * 776 + 6 * oxl + 8;
            aF = (bf16x8){0, 0, 0, 0, 0, 0, 0, 0};
            aF[0] = (short)sX[b0];
            aF[1] = (short)sX[b0 + 776];
            aF[2] = (short)sX[b0 + 1552];
        }
        f32x4 acc[4];
#pragma unroll
        for (int nf = 0; nf < 4; ++nf)
            acc[nf] = __builtin_amdgcn_mfma_f32_16x16x32_bf16(aF, bF[nf], z4, 0, 0, 0);
        const int g_out = fl * 4 + kg;
        const int pyo = g_out >> 6, pxo = xh * 64 + (g_out & 63);
        union { ushort_t u[4]; uint2 v; } pk;
#pragma unroll
        for (int nf = 0; nf < 4; ++nf) {
            float v = fmaxf(fmaxf(acc[nf][0], acc[nf][1]), fmaxf(acc[nf][2], acc[nf][3]));
            pk.u[nf] = f2b(fmaxf(v + bias[nf], 0.f));
        }
        *(uint2*)(y1 + ((size_t)(b * 128 + 2 * rp + pyo) * 128 + pxo) * 64 + 4 * l15) = pk.v;
    }
}

// ---------------- conv2 LDS-staged MFMA
__global__ __launch_bounds__(256) void k_conv2s(const ushort_t* __restrict__ y1,
                                                const ushort_t* __restrict__ wpk2,
                                                const float* __restrict__ b2,
                                                ushort_t* __restrict__ y2) {
    const int b = blockIdx.z;
    const int xh = blockIdx.y;
    const int rp = blockIdx.x;
    const int tid = threadIdx.x;
    const int wid = tid >> 6, lane = tid & 63;
    const int l15 = lane & 15, kg = lane >> 4;

    __shared__ __align__(16) ushort_t sY[330 * 72];
    bf16x8* sYv = (bf16x8*)sY;

    const ushort_t* xb = y1 + (size_t)b * 128 * 128 * 64;
    const int iyb = 4 * rp - 1, ixb = 64 * xh - 1;
    for (int j = tid; j < 2640; j += 256) {
        const int q = j & 7;
        const int pc = j >> 3;
        const int cc = pc % 66, r = pc / 66;
        const int iy = iyb + r, ix = ixb + cc;
        bf16x8 v = {0, 0, 0, 0, 0, 0, 0, 0};
        if (iy >= 0 && ix >= 0 && ix < 128)
            v = *reinterpret_cast<const bf16x8*>(xb + ((size_t)iy * 128 + ix) * 64 + q * 8);
        sYv[pc * 9 + (q ^ ((pc >> 1) & 7))] = v;
    }
    __syncthreads();

    const f32x4 z4 = {0.f, 0.f, 0.f, 0.f};
    f32x4 acc[2][2][2];
#pragma unroll
    for (int i = 0; i < 2; ++i)
#pragma unroll
        for (int j = 0; j < 2; ++j) { acc[i][j][0] = z4; acc[i][j][1] = z4; }

#pragma unroll 1
    for (int tap = 0; tap < 9; ++tap) {
        const int ky = tap >= 6 ? 2 : (tap >= 3 ? 1 : 0), kx = tap - ky * 3;
#pragma unroll
        for (int h = 0; h < 2; ++h) {
            const int kc = tap * 2 + h;
            const int c8 = h * 4 + kg;
            bf16x8 aF[2][2];
#pragma unroll
            for (int oyi = 0; oyi < 2; ++oyi)
#pragma unroll
            for (int m2 = 0; m2 < 2; ++m2) {
                const int r = 2 * oyi + ky;
                const int cc = 2 * l15 + m2 * 32 + kx;
                const int pc = r * 66 + cc;
                aF[oyi][m2] = sYv[pc * 9 + (c8 ^ ((pc >> 1) & 7))];
            }
            bf16x8 bF[2];
#pragma unroll
            for (int nf = 0; nf < 2; ++nf)
                bF[nf] = *reinterpret_cast<const bf16x8*>(wpk2 + ((size_t)(kc * 8 + wid * 2 + nf) * 64 + lane) * 8);
#pragma unroll
            for (int oyi = 0; oyi < 2; ++oyi)
#pragma unroll
            for (int m2 = 0; m2 < 2; ++m2)
#pragma unroll
            for (int nf = 0; nf < 2; ++nf)
                acc[oyi][m2][nf] = __builtin_amdgcn_mfma_f32_16x16x32_bf16(aF[oyi][m2], bF[nf], acc[oyi][m2][nf], 0, 0, 0);
        }
    }
    const int kgx = lane >> 4;
#pragma unroll
    for (int nf = 0; nf < 2; ++nf) {
        const int co = wid * 32 + nf * 16 + l15;
        const float bias = b2[co];
#pragma unroll
        for (int m2 = 0; m2 < 2; ++m2)
#pragma unroll
            for (int p = 0; p < 2; ++p) {
                float v = fmaxf(fmaxf(acc[0][m2][nf][2 * p], acc[0][m2][nf][2 * p + 1]),
                                fmaxf(acc[1][m2][nf][2 * p], acc[1][m2][nf][2 * p + 1]));
                const int px = (xh * 2 + m2) * 8 + kgx * 2 + p;
                y2[((size_t)(b * 32 + rp) * 32 + px) * 128 + co] = f2b(fmaxf(v + bias, 0.f));
            }
    }
}

// ---------------- conv3 MFMA
__global__ __launch_bounds__(256) void k_conv3m(const ushort_t* __restrict__ y2,
                                                const ushort_t* __restrict__ wpk3,
                                                const float* __restrict__ b3,
                                                ushort_t* __restrict__ y3) {
    const int gy = blockIdx.x, gn = blockIdx.y, b = blockIdx.z;
    const int oy0 = gy * 4;
    const int tid = threadIdx.x;
    const int wid = tid >> 6, lane = tid & 63;
    const int l15 = lane & 15, kl8 = (lane >> 4) << 3;
    const int g16 = gn * 4 + wid;
    const int co = g16 * 16 + l15;

    const ushort_t* xb = y2 + (size_t)b * 32 * 32 * 128;
    const f32x4 z4 = {0.f, 0.f, 0.f, 0.f};
    f32x4 acc[4] = {z4, z4, z4, z4};

#pragma unroll 1
    for (int tap = 0; tap < 9; ++tap) {
        const int ky = tap >= 6 ? 2 : (tap >= 3 ? 1 : 0), kx = tap - ky * 3;
        const int iyA = 2 * oy0 - 1 + ky;
        const int c = 2 * l15 - 1 + kx;
        const bool cok = (c >= 0);
#pragma unroll
        for (int h = 0; h < 4; ++h) {
            const int ci0 = h * 32;
            const int kc = tap * 4 + h;
            bf16x8 aF[4];
#pragma unroll
            for (int mf = 0; mf < 4; ++mf) {
                const int iy = iyA + 2 * mf;
                bf16x8 r = {0, 0, 0, 0, 0, 0, 0, 0};
                if (cok && iy >= 0) r = *reinterpret_cast<const bf16x8*>(xb + ((size_t)iy * 32 + c) * 128 + ci0 + kl8);
                aF[mf] = r;
            }
            const bf16x8 bF = *reinterpret_cast<const bf16x8*>(wpk3 + ((size_t)(kc * 16 + g16) * 64 + lane) * 8);
#pragma unroll
            for (int mf = 0; mf < 4; ++mf)
                acc[mf] = __builtin_amdgcn_mfma_f32_16x16x32_bf16(aF[mf], bF, acc[mf], 0, 0, 0);
        }
    }
    const int kg = lane >> 4;
    const float bias = b3[co];
#pragma unroll
    for (int mp = 0; mp < 2; ++mp) {
        const int py = gy * 2 + mp;
#pragma unroll
        for (int p = 0; p < 2; ++p) {
            float v = fmaxf(fmaxf(acc[2 * mp][2 * p], acc[2 * mp][2 * p + 1]),
                            fmaxf(acc[2 * mp + 1][2 * p], acc[2 * mp + 1][2 * p + 1]));
            const int px = kg * 2 + p;
            y3[((size_t)(b * 8 + py) * 8 + px) * 256 + co] = f2b(fmaxf(v + bias, 0.f));
        }
    }
}

// ---------------- conv4 GEMM + relu + mean, fused im2col gather from y3 (K-split 4 waves)
__global__ __launch_bounds__(256) void k_conv4g(const ushort_t* __restrict__ y3,
                                                const ushort_t* __restrict__ wpk4m,
                                                const float* __restrict__ b4,
                                                float* __restrict__ feats) {
    const int g16 = blockIdx.x, b = blockIdx.y;
    const int tid = threadIdx.x, wid = tid >> 6, lane = tid & 63;
    const int l15 = lane & 15, kg = lane >> 4, kl8 = kg << 3;
    const int oy = l15 >> 2, ox = l15 & 3;
    const f32x4 z4 = {0.f, 0.f, 0.f, 0.f};
    f32x4 acc = z4;
    const ushort_t* yb = y3 + (size_t)b * 16384;
    const int kc0 = wid * 18;

#pragma unroll 3
    for (int i = 0; i < 18; ++i) {
        const int kc = kc0 + i;
        const int k0 = kc * 32 + kl8;
        const int tap = k0 >> 8, ci0 = k0 & 255;
        const int ky = tap / 3, kx = tap - 3 * (tap / 3);
        const int iy = 2 * oy - 1 + ky, ix = 2 * ox - 1 + kx;
        bf16x8 aF = {0, 0, 0, 0, 0, 0, 0, 0};
        if (iy >= 0 && ix >= 0)
            aF = *reinterpret_cast<const bf16x8*>(yb + ((iy * 8 + ix) << 8) + ci0);
        const bf16x8 bF = *reinterpret_cast<const bf16x8*>(wpk4m + ((size_t)(kc * 32 + g16) * 64 + lane) * 8);
        acc = __builtin_amdgcn_mfma_f32_16x16x32_bf16(aF, bF, acc, 0, 0, 0);
    }

    __shared__ f32x4 red[4][64];
    red[wid][lane] = acc;
    __syncthreads();
    if (wid == 0) {
        f32x4 t = red[0][lane];
        t = t + red[1][lane];
        t = t + red[2][lane];
        t = t + red[3][lane];
        const int co = g16 * 16 + l15;
        const float bias = b4[co];
        float s = fmaxf(t[0] + bias, 0.f) + fmaxf(t[1] + bias, 0.f)
                + fmaxf(t[2] + bias, 0.f) + fmaxf(t[3] + bias, 0.f);
        s += __shfl_xor(s, 16, 64);
        s += __shfl_xor(s, 32, 64);
        if (kg == 0) feats[b * 512 + co] = s * 0.0625f;
    }
}

// ---------------- head (split writes, bf16 vlad output): grid (b=16, slice=8)
__global__ __launch_bounds__(256) void k_head(const float* __restrict__ feats,
                                              const float* __restrict__ wv,
                                              const float* __restrict__ bv,
                                              const float* __restrict__ centroids,
                                              ushort_t* __restrict__ v) {
    const int b = blockIdx.x, sl8 = blockIdx.y;
    __shared__ float sf[512];
    __shared__ float sl[64];
    __shared__ float sa[64];
    for (int i = threadIdx.x; i < 512; i += 256) sf[i] = feats[b * 512 + i];
    __syncthreads();
    if (threadIdx.x < 64) {
        const int k = threadIdx.x;
        float s = bv[k];
        for (int c = 0; c < 512; ++c) s += sf[c] * wv[(size_t)k * 512 + c];
        sl[k] = s;
    }
    __syncthreads();
    if (threadIdx.x < 64) {
        const int k = threadIdx.x;
        float m = -1e30f;
        for (int i = 0; i < 64; ++i) m = fmaxf(m, sl[i]);
        float sum = 0.f;
        for (int i = 0; i < 64; ++i) sum += __expf(sl[i] - m);
        sa[k] = __expf(sl[k] - m) / sum;
    }
    __syncthreads();
    const int i4end = (sl8 + 1) * 4096;
    for (int i4 = sl8 * 4096 + threadIdx.x * 4; i4 < i4end; i4 += 1024) {
        const int k = i4 >> 9;
        const float a_ = sa[k];
        const float4 c4 = *(const float4*)(centroids + i4);
        const float4 f4 = *(const float4*)(&sf[i4 & 511]);
        union { ushort_t u[4]; uint2 w; } pk;
        pk.u[0] = f2b(a_ * (f4.x - c4.x));
        pk.u[1] = f2b(a_ * (f4.y - c4.y));
        pk.u[2] = f2b(a_ * (f4.z - c4.z));
        pk.u[3] = f2b(a_ * (f4.w - c4.w));
        *(uint2*)(v + (size_t)b * 32768 + i4) = pk.w;
    }
}

// ---------------- fc1 MFMA: part = v_bf16[16 x 32768] @ fw1^T, K-split
// grid (g16=16, by=64); A direct bf16 load, B inline fp32->bf16 cvt
__global__ __launch_bounds__(256) void k_fc1m(const ushort_t* __restrict__ v,
                                              const float* __restrict__ fw1,
                                              float* __restrict__ part) {
    const int g16 = blockIdx.x, by = blockIdx.y;
    const int tid = threadIdx.x, wid = tid >> 6, lane = tid & 63;
    const int l15 = lane & 15, kg = lane >> 4;
    const f32x4 z4 = {0.f, 0.f, 0.f, 0.f};
    f32x4 acc = z4;
    const ushort_t* vrow = v + (size_t)l15 * 32768;                // batch = l15
    const float* wrow = fw1 + (size_t)(g16 * 16 + l15) * 32768;    // d = g16*16+l15
    const int kc0 = by * 16 + wid * 4;

#pragma unroll
    for (int i = 0; i < 4; ++i) {
        const int j0 = (kc0 + i) * 32 + kg * 8;
        const bf16x8 aF = *reinterpret_cast<const bf16x8*>(vrow + j0);
        const float4 wa = *(const float4*)(wrow + j0);
        const float4 wb = *(const float4*)(wrow + j0 + 4);
        bf16x8 bF;
        bF[0] = (short)f2b(wa.x); bF[1] = (short)f2b(wa.y);
        bF[2] = (short)f2b(wa.z); bF[3] = (short)f2b(wa.w);
        bF[4] = (short)f2b(wb.x); bF[5] = (short)f2b(wb.y);
        bF[6] = (short)f2b(wb.z); bF[7] = (short)f2b(wb.w);
        acc = __builtin_amdgcn_mfma_f32_16x16x32_bf16(aF, bF, acc, 0, 0, 0);
    }

    __shared__ f32x4 red[4][64];
    red[wid][lane] = acc;
    __syncthreads();
    if (wid == 0) {
        f32x4 t = red[0][lane];
        t = t + red[1][lane];
        t = t + red[2][lane];
        t = t + red[3][lane];
#pragma unroll
        for (int r = 0; r < 4; ++r)
            part[((size_t)by * 16 + (kg * 4 + r)) * 256 + g16 * 16 + l15] = t[r];
    }
}

// ---------------- fc2 (+fc1 reduce/bias/relu) + L2 norm; 64 K-partials
__global__ __launch_bounds__(256) void k_fc2(const float* __restrict__ part,
                                             const float* __restrict__ fb1,
                                             const float* __restrict__ fw2,
                                             const float* __restrict__ fb2,
                                             float* __restrict__ out) {
    const int b = blockIdx.x;
    const int dd = threadIdx.x;
    __shared__ float sd[256];
    __shared__ float sq[256];
    float t = fb1[dd];
#pragma unroll 8
    for (int ks = 0; ks < 64; ++ks) t += part[((size_t)ks * 16 + b) * 256 + dd];
    sd[dd] = fmaxf(t, 0.f);
    __syncthreads();
    float s = fb2[dd];
    for (int j = 0; j < 256; ++j) s += sd[j] * fw2[(size_t)dd * 256 + j];
    sq[dd] = s * s;
    __syncthreads();
    for (int off = 128; off >= 1; off >>= 1) {
        if (dd < off) sq[dd] += sq[dd + off];
        __syncthreads();
    }
    const float inv = rsqrtf(sq[0]);
    out[b * 256 + dd] = s * inv;
}

extern "C" void kernel_launch(void* const* d_in, const int* in_sizes, int n_in,
                              void* d_out, int out_size, void* d_ws, size_t ws_size,
                              hipStream_t stream) {
    const float* x    = (const float*)d_in[0];
    const float* w1   = (const float*)d_in[1];
    const float* b1   = (const float*)d_in[2];
    const float* w2   = (const float*)d_in[3];
    const float* b2   = (const float*)d_in[4];
    const float* w3   = (const float*)d_in[5];
    const float* b3   = (const float*)d_in[6];
    const float* w4   = (const float*)d_in[7];
    const float* b4   = (const float*)d_in[8];
    const float* wv   = (const float*)d_in[9];
    const float* bv   = (const float*)d_in[10];
    const float* cen  = (const float*)d_in[11];
    const float* fw1  = (const float*)d_in[12];
    const float* fb1  = (const float*)d_in[13];
    const float* fw2  = (const float*)d_in[14];
    const float* fb2  = (const float*)d_in[15];
    float* out = (float*)d_out;

    char* p = (char*)d_ws;
    ushort_t* y1    = (ushort_t*)p; p += 33554432;  // 16*128*128*64 bf16
    ushort_t* wpk2  = (ushort_t*)p; p += 147456;    // 73728 bf16
    ushort_t* wpk3  = (ushort_t*)p; p += 589824;    // 294912 bf16
    ushort_t* wpk4m = (ushort_t*)p; p += 2359296;   // 1179648 bf16
    ushort_t* wpk1  = (ushort_t*)p; p += 4096;      // 2048 bf16
    ushort_t* y2    = (ushort_t*)p; p += 4194304;   // 16*32*32*128 bf16
    ushort_t* y3    = (ushort_t*)p; p += 524288;    // 16*8*8*256 bf16
    float*    feats = (float*)p;    p += 32768;     // 16*512
    ushort_t* vbuf  = (ushort_t*)p; p += 1048576;   // 16*32768 bf16
    float*    part  = (float*)p;    p += 1048576;   // 64*16*256 f32

    k_packall<<<693, 256, 0, stream>>>(w1, w2, w3, w4, wpk1, wpk2, wpk3, wpk4m);
    k_conv1f<<<dim3(64, 2, 16), 256, 0, stream>>>(x, wpk1, b1, y1);
    k_conv2s<<<dim3(32, 2, 16), 256, 0, stream>>>(y1, wpk2, b2, y2);
    k_conv3m<<<dim3(4, 4, 16), 256, 0, stream>>>(y2, wpk3, b3, y3);
    k_conv4g<<<dim3(32, 16), 256, 0, stream>>>(y3, wpk4m, b4, feats);
    k_head<<<dim3(16, 8), 256, 0, stream>>>(feats, wv, bv, cen, vbuf);
    k_fc1m<<<dim3(16, 64), 256, 0, stream>>>(vbuf, fw1, part);
    k_fc2<<<16, 256, 0, stream>>>(part, fb1, fw2, fb2, out);
}